// Round 9
// baseline (472.989 us; speedup 1.0000x reference)
//
#include <hip/hip_runtime.h>
#include <cstdint>
#include <cstddef>

#define NEG_SLOPE 0.2f

typedef _Float16 f16x8 __attribute__((ext_vector_type(8)));
typedef _Float16 f16x2 __attribute__((ext_vector_type(2)));
typedef float    f32x4 __attribute__((ext_vector_type(4)));

__device__ __forceinline__ float leaky(float x){ return x > 0.f ? x : NEG_SLOPE * x; }
__device__ __forceinline__ float elu(float x){ return x > 0.f ? x : __expf(x) - 1.f; }

// ============ split f32 -> fp16 hi + fp16 lo ============
__global__ void k_wcvt(const float* __restrict__ src, _Float16* __restrict__ hi,
                       _Float16* __restrict__ lo, int n)
{
    int i = blockIdx.x * 256 + threadIdx.x;
    if (i >= n) return;
    float v = src[i];
    _Float16 h = (_Float16)v;
    hi[i] = h;
    lo[i] = (_Float16)(v - (float)h);
}

// ============ fold attention vectors: w_s[h,k] = sum_c att_src[h,c] * W1[h*128+c, k] ============
__global__ __launch_bounds__(128) void k_wvec(const float* __restrict__ W1,
                                              const float* __restrict__ as1,
                                              const float* __restrict__ ad1,
                                              float* __restrict__ w_s,
                                              float* __restrict__ w_d)
{
    int h = blockIdx.x, k = threadIdx.x;
    float s = 0.f, d = 0.f;
    for (int c = 0; c < 128; ++c) {
        float w = W1[((size_t)(h * 128 + c)) * 128 + k];
        s += as1[h * 128 + c] * w;
        d += ad1[h * 128 + c] * w;
    }
    w_s[h * 128 + k] = s;
    w_d[h * 128 + k] = d;
}

// ============ layer-1 attention logits from raw x; also emit x as fp16 ============
__global__ __launch_bounds__(256) void k_attn_x(const float* __restrict__ x,
                                                const float* __restrict__ w_s,
                                                const float* __restrict__ w_d,
                                                float* __restrict__ a_s,
                                                float* __restrict__ a_d,
                                                _Float16* __restrict__ xh, int N)
{
    int n = blockIdx.x * 4 + (threadIdx.x >> 6);
    if (n >= N) return;
    int lane = threadIdx.x & 63;
    float2 xv = *(const float2*)(x + (size_t)n * 128 + lane * 2);
    f16x2 hv = { (_Float16)xv.x, (_Float16)xv.y };
    *(f16x2*)(xh + (size_t)n * 128 + lane * 2) = hv;
    float ps[4], pd[4];
    #pragma unroll
    for (int h = 0; h < 4; ++h) {
        float2 sv = *(const float2*)(w_s + h * 128 + lane * 2);
        float2 dv = *(const float2*)(w_d + h * 128 + lane * 2);
        ps[h] = xv.x * sv.x + xv.y * sv.y;
        pd[h] = xv.x * dv.x + xv.y * dv.y;
    }
    #pragma unroll
    for (int h = 0; h < 4; ++h)
        for (int off = 32; off; off >>= 1) {
            ps[h] += __shfl_xor(ps[h], off);
            pd[h] += __shfl_xor(pd[h], off);
        }
    if (lane == 0) {
        *(float4*)(a_s + (size_t)n * 4) = make_float4(ps[0], ps[1], ps[2], ps[3]);
        *(float4*)(a_d + (size_t)n * 4) = make_float4(pd[0], pd[1], pd[2], pd[3]);
    }
}

// ============ CSR construction ============
__global__ void k_count(const int* __restrict__ ei, int* __restrict__ deg, int E, int Ep)
{
    int e = blockIdx.x * blockDim.x + threadIdx.x;
    if (e >= Ep) return;
    int dst = (e < E) ? ei[E + e] : (e - E);
    atomicAdd(&deg[dst], 1);
}

__global__ __launch_bounds__(1024) void k_scanA(const int* __restrict__ deg,
                                                int* __restrict__ start,
                                                int* __restrict__ sums, int Ntot, int N)
{
    __shared__ int sm[1024];
    int tid = threadIdx.x;
    int i = blockIdx.x * 1024 + tid;
    int v = (i < N) ? deg[i] : 0;
    sm[tid] = v; __syncthreads();
    for (int off = 1; off < 1024; off <<= 1) {
        int t = (tid >= off) ? sm[tid - off] : 0;
        __syncthreads();
        sm[tid] += t;
        __syncthreads();
    }
    if (i < Ntot) start[i] = sm[tid] - v;
    if (tid == 1023) sums[blockIdx.x] = sm[1023];
}

__global__ void k_scanB(int* sums, int nb)
{
    int l = threadIdx.x;
    int v = (l < nb) ? sums[l] : 0;
    int orig = v;
    for (int off = 1; off < 64; off <<= 1) { int t = __shfl_up(v, off); if (l >= off) v += t; }
    if (l < nb) sums[l] = v - orig;
}

__global__ __launch_bounds__(1024) void k_scanC(int* __restrict__ start,
                                                const int* __restrict__ sums, int Ntot)
{
    int i = blockIdx.x * 1024 + threadIdx.x;
    if (i < Ntot) start[i] += sums[blockIdx.x];
}

__global__ void k_fill(const int* __restrict__ ei, const int* __restrict__ start,
                       int* __restrict__ cursor, int* __restrict__ csr_src, int E, int Ep)
{
    int e = blockIdx.x * blockDim.x + threadIdx.x;
    if (e >= Ep) return;
    int src, dst;
    if (e < E) { src = ei[e]; dst = ei[E + e]; } else { src = dst = e - E; }
    int pos = atomicAdd(&cursor[dst], 1);
    csr_src[start[dst] + pos] = src;
}

// ============ layer-1 gather: one WAVE per dst, zero barriers/LDS ============
__global__ __launch_bounds__(256) void k_gat1(const int* __restrict__ start,
                                              const int* __restrict__ csr,
                                              const float* __restrict__ a_s,
                                              const float* __restrict__ a_d,
                                              const _Float16* __restrict__ x,
                                              _Float16* __restrict__ agg, int N)
{
    int d = blockIdx.x * 4 + (threadIdx.x >> 6);
    if (d >= N) return;
    int lane = threadIdx.x & 63;
    int beg = start[d], end = start[d + 1];
    float4 ad4 = *(const float4*)(a_d + (size_t)d * 4);

    float sum0 = 0.f, sum1 = 0.f, sum2 = 0.f, sum3 = 0.f;
    float a00 = 0.f, a01 = 0.f, a10 = 0.f, a11 = 0.f;
    float a20 = 0.f, a21 = 0.f, a30 = 0.f, a31 = 0.f;
    const _Float16* xb = x + 2 * lane;

    for (int chunk = beg; chunk < end; chunk += 64) {
        int nchunk = end - chunk; if (nchunk > 64) nchunk = 64;
        int s = 0;
        float e0 = 0.f, e1 = 0.f, e2 = 0.f, e3 = 0.f;
        if (lane < nchunk) {
            s = csr[chunk + lane];
            float4 as4 = *(const float4*)(a_s + (size_t)s * 4);
            e0 = __expf(leaky(as4.x + ad4.x));
            e1 = __expf(leaky(as4.y + ad4.y));
            e2 = __expf(leaky(as4.z + ad4.z));
            e3 = __expf(leaky(as4.w + ad4.w));
            sum0 += e0; sum1 += e1; sum2 += e2; sum3 += e3;
        }
        for (int i = 0; i < nchunk; ++i) {
            int   si = __shfl(s,  i);
            float w0 = __shfl(e0, i);
            float w1 = __shfl(e1, i);
            float w2 = __shfl(e2, i);
            float w3 = __shfl(e3, i);
            f16x2 hv = *(const f16x2*)(xb + (size_t)si * 128);
            float vx = (float)hv.x, vy = (float)hv.y;
            a00 += w0 * vx; a01 += w0 * vy;
            a10 += w1 * vx; a11 += w1 * vy;
            a20 += w2 * vx; a21 += w2 * vy;
            a30 += w3 * vx; a31 += w3 * vy;
        }
    }
    #pragma unroll
    for (int o = 32; o; o >>= 1) {
        sum0 += __shfl_xor(sum0, o); sum1 += __shfl_xor(sum1, o);
        sum2 += __shfl_xor(sum2, o); sum3 += __shfl_xor(sum3, o);
    }
    float i0 = 1.f / (sum0 + 1e-16f), i1 = 1.f / (sum1 + 1e-16f);
    float i2 = 1.f / (sum2 + 1e-16f), i3 = 1.f / (sum3 + 1e-16f);
    _Float16* o = agg + (size_t)d * 512 + 2 * lane;
    f16x2 o0 = {(_Float16)(a00 * i0), (_Float16)(a01 * i0)};
    f16x2 o1 = {(_Float16)(a10 * i1), (_Float16)(a11 * i1)};
    f16x2 o2 = {(_Float16)(a20 * i2), (_Float16)(a21 * i2)};
    f16x2 o3 = {(_Float16)(a30 * i3), (_Float16)(a31 * i3)};
    *(f16x2*)(o)       = o0;
    *(f16x2*)(o + 128) = o1;
    *(f16x2*)(o + 256) = o2;
    *(f16x2*)(o + 384) = o3;
}

// ============ FUSED MLP: h1 = elu(agg @ W1^T + b1) [LDS-only]; xh2 = h1 @ W2^T;
//              + layer-2 attention logits fused into the epilogue ============
// Block 256 thr (4 waves), M-tile 64. Wave w owns COLUMN slice c0=w*32 (j=0..1)
// for ALL 64 rows (r2=0..3) -> every W fragment loaded by exactly one wave.
#define HP 520   // padded LDS row (halfs)
__global__ __launch_bounds__(256, 2) void k_mlp(
    const _Float16* __restrict__ agg,                                   // [N,512]
    const _Float16* __restrict__ W1h, const _Float16* __restrict__ W1l, // [512,128]
    const float* __restrict__ b1,
    const _Float16* __restrict__ W2h, const _Float16* __restrict__ W2l, // [128,512]
    const float* __restrict__ as2, const float* __restrict__ ad2,       // [128]
    _Float16* __restrict__ xh2, float* __restrict__ As2,
    float* __restrict__ Ad2, int N)
{
    __shared__ __align__(16) _Float16 s_h1[64 * HP];
    __shared__ float s_ss[4][64];
    __shared__ float s_sd[4][64];
    const int tid = threadIdx.x;
    const int wave = tid >> 6, lane = tid & 63;
    const int quad = lane >> 4, l16 = lane & 15;
    const int m0 = blockIdx.x * 64;
    const int c0 = wave * 32;           // column slice within 128

    // ---------- GEMM1 per head (+bias+elu) -> s_h1 ----------
    #pragma unroll
    for (int h = 0; h < 4; ++h) {
        f16x8 af[4][4];                 // [row subtile r2][k slice kk]
        #pragma unroll
        for (int r2 = 0; r2 < 4; ++r2) {
            int mrow = m0 + r2 * 16 + l16;
            #pragma unroll
            for (int kk = 0; kk < 4; ++kk) {
                f16x8 v = {};
                if (mrow < N) v = *(const f16x8*)(agg + (size_t)mrow * 512 + h * 128 + kk * 32 + quad * 8);
                af[r2][kk] = v;
            }
        }
        f32x4 acc[4][2] = {};
        #pragma unroll
        for (int kk = 0; kk < 4; ++kk) {
            f16x8 bh[2], bl[2];
            #pragma unroll
            for (int j = 0; j < 2; ++j) {
                size_t wo = (size_t)(h * 128 + c0 + j * 16 + l16) * 128 + kk * 32 + quad * 8;
                bh[j] = *(const f16x8*)(W1h + wo);
                bl[j] = *(const f16x8*)(W1l + wo);
            }
            #pragma unroll
            for (int r2 = 0; r2 < 4; ++r2) {
                acc[r2][0] = __builtin_amdgcn_mfma_f32_16x16x32_f16(af[r2][kk], bh[0], acc[r2][0], 0, 0, 0);
                acc[r2][0] = __builtin_amdgcn_mfma_f32_16x16x32_f16(af[r2][kk], bl[0], acc[r2][0], 0, 0, 0);
                acc[r2][1] = __builtin_amdgcn_mfma_f32_16x16x32_f16(af[r2][kk], bh[1], acc[r2][1], 0, 0, 0);
                acc[r2][1] = __builtin_amdgcn_mfma_f32_16x16x32_f16(af[r2][kk], bl[1], acc[r2][1], 0, 0, 0);
            }
        }
        #pragma unroll
        for (int j = 0; j < 2; ++j) {
            int n = c0 + j * 16 + l16;
            float bb = b1[h * 128 + n];
            #pragma unroll
            for (int r2 = 0; r2 < 4; ++r2)
                #pragma unroll
                for (int r = 0; r < 4; ++r)
                    s_h1[(r2 * 16 + quad * 4 + r) * HP + h * 128 + n] = (_Float16)elu(acc[r2][j][r] + bb);
        }
    }
    __syncthreads();

    // ---------- GEMM2 (K=512) from LDS -> xh2 fp16 + attn2 logit partials ----------
    f32x4 acc2[4][2] = {};
    #pragma unroll
    for (int kk = 0; kk < 16; ++kk) {
        f16x8 bh[2], bl[2];
        #pragma unroll
        for (int j = 0; j < 2; ++j) {
            size_t wo = (size_t)(c0 + j * 16 + l16) * 512 + kk * 32 + quad * 8;
            bh[j] = *(const f16x8*)(W2h + wo);
            bl[j] = *(const f16x8*)(W2l + wo);
        }
        #pragma unroll
        for (int r2 = 0; r2 < 4; ++r2) {
            f16x8 a = *(const f16x8*)&s_h1[(r2 * 16 + l16) * HP + kk * 32 + quad * 8];
            acc2[r2][0] = __builtin_amdgcn_mfma_f32_16x16x32_f16(a, bh[0], acc2[r2][0], 0, 0, 0);
            acc2[r2][0] = __builtin_amdgcn_mfma_f32_16x16x32_f16(a, bl[0], acc2[r2][0], 0, 0, 0);
            acc2[r2][1] = __builtin_amdgcn_mfma_f32_16x16x32_f16(a, bh[1], acc2[r2][1], 0, 0, 0);
            acc2[r2][1] = __builtin_amdgcn_mfma_f32_16x16x32_f16(a, bl[1], acc2[r2][1], 0, 0, 0);
        }
    }
    float ss[4][4] = {}, sd[4][4] = {};
    #pragma unroll
    for (int j = 0; j < 2; ++j) {
        int n = c0 + j * 16 + l16;
        float av = as2[n], dv = ad2[n];
        #pragma unroll
        for (int r2 = 0; r2 < 4; ++r2)
            #pragma unroll
            for (int r = 0; r < 4; ++r) {
                float v = acc2[r2][j][r];
                int d = m0 + r2 * 16 + quad * 4 + r;
                if (d < N) xh2[(size_t)d * 128 + n] = (_Float16)v;
                ss[r2][r] += v * av;
                sd[r2][r] += v * dv;
            }
    }
    #pragma unroll
    for (int o = 1; o < 16; o <<= 1)
        #pragma unroll
        for (int r2 = 0; r2 < 4; ++r2)
            #pragma unroll
            for (int r = 0; r < 4; ++r) {
                ss[r2][r] += __shfl_xor(ss[r2][r], o);
                sd[r2][r] += __shfl_xor(sd[r2][r], o);
            }
    if (l16 == 0) {
        #pragma unroll
        for (int r2 = 0; r2 < 4; ++r2)
            #pragma unroll
            for (int r = 0; r < 4; ++r) {
                int row = r2 * 16 + quad * 4 + r;
                s_ss[wave][row] = ss[r2][r];
                s_sd[wave][row] = sd[r2][r];
            }
    }
    __syncthreads();
    if (tid < 64) {
        int d = m0 + tid;
        if (d < N) {
            As2[d] = s_ss[0][tid] + s_ss[1][tid] + s_ss[2][tid] + s_ss[3][tid];
            Ad2[d] = s_sd[0][tid] + s_sd[1][tid] + s_sd[2][tid] + s_sd[3][tid];
        }
    }
}

// ============ layer-2 gather (1 head) + bias + ELU -> h2 f32, wave per dst ============
__global__ __launch_bounds__(256) void k_gat2(const int* __restrict__ start,
                                              const int* __restrict__ csr,
                                              const float* __restrict__ a_s,
                                              const float* __restrict__ a_d,
                                              const _Float16* __restrict__ xh2,
                                              const float* __restrict__ b2,
                                              float* __restrict__ h2, int N)
{
    int d = blockIdx.x * 4 + (threadIdx.x >> 6);
    if (d >= N) return;
    int lane = threadIdx.x & 63;
    int beg = start[d], end = start[d + 1];
    float ad = a_d[d];

    float sum = 0.f, ax = 0.f, ay = 0.f;
    const _Float16* xb = xh2 + 2 * lane;

    for (int chunk = beg; chunk < end; chunk += 64) {
        int nchunk = end - chunk; if (nchunk > 64) nchunk = 64;
        int s = 0; float e = 0.f;
        if (lane < nchunk) {
            s = csr[chunk + lane];
            e = __expf(leaky(a_s[s] + ad));
            sum += e;
        }
        for (int i = 0; i < nchunk; ++i) {
            int   si = __shfl(s, i);
            float w  = __shfl(e, i);
            f16x2 hv = *(const f16x2*)(xb + (size_t)si * 128);
            ax += w * (float)hv.x;
            ay += w * (float)hv.y;
        }
    }
    #pragma unroll
    for (int o = 32; o; o >>= 1) sum += __shfl_xor(sum, o);
    float inv = 1.f / (sum + 1e-16f);
    float2 bb = *(const float2*)(b2 + 2 * lane);
    float2 ov = make_float2(elu(ax * inv + bb.x), elu(ay * inv + bb.y));
    *(float2*)(h2 + (size_t)d * 128 + 2 * lane) = ov;
}

// ============ graph boundaries from SORTED batch ============
__global__ void k_gbound(const int* __restrict__ batch, int* __restrict__ gstart, int N, int G)
{
    int n = blockIdx.x * blockDim.x + threadIdx.x;
    if (n >= N) return;
    int b = batch[n];
    int prev = (n == 0) ? -1 : batch[n - 1];
    for (int g = prev + 1; g <= b; ++g) gstart[g] = n;
    if (n == N - 1)
        for (int g = b + 1; g <= G; ++g) gstart[g] = N;
}

// ============ pooling stage A: chunked partial sums ============
#define PCH 64
__global__ __launch_bounds__(128) void k_poolA(const float* __restrict__ h2,
                                               const int* __restrict__ batch,
                                               float* __restrict__ pooled, int N)
{
    int c = threadIdx.x;
    int n0 = blockIdx.x * PCH;
    int n1 = n0 + PCH < N ? n0 + PCH : N;
    if (n0 >= N) return;
    int g = batch[n0];
    float acc = 0.f;
    for (int n = n0; n < n1; ++n) {
        int bg = batch[n];
        if (bg != g) { atomicAdd(&pooled[(size_t)g * 128 + c], acc); acc = 0.f; g = bg; }
        acc += h2[(size_t)n * 128 + c];
    }
    atomicAdd(&pooled[(size_t)g * 128 + c], acc);
}

// ============ head: mean + relu(pooled@Wh1^T+bh1) @ Wh2^T + bh2 ============
__global__ __launch_bounds__(128) void k_head(const float* __restrict__ pooled,
                                              const int* __restrict__ gstart,
                                              const float* __restrict__ Wh1,
                                              const float* __restrict__ bh1,
                                              const float* __restrict__ Wh2,
                                              const float* __restrict__ bh2,
                                              float* __restrict__ out)
{
    int g = blockIdx.x, c = threadIdx.x;
    __shared__ float p[128];
    __shared__ float red[128];
    float cf = (float)(gstart[g + 1] - gstart[g]); cf = cf > 1.f ? cf : 1.f;
    p[c] = pooled[(size_t)g * 128 + c] / cf;
    __syncthreads();
    float z = bh1[c];
    for (int k = 0; k < 128; ++k) z += p[k] * Wh1[c * 128 + k];
    z = z > 0.f ? z : 0.f;
    red[c] = z * Wh2[c];
    __syncthreads();
    for (int st = 64; st > 0; st >>= 1) { if (c < st) red[c] += red[c + st]; __syncthreads(); }
    if (c == 0) out[g] = red[0] + bh2[0];
}

// ============ launch ============
extern "C" void kernel_launch(void* const* d_in, const int* in_sizes, int n_in,
                              void* d_out, int out_size, void* d_ws, size_t ws_size,
                              hipStream_t stream)
{
    const float* x   = (const float*)d_in[0];
    const int*   ei  = (const int*)d_in[1];
    const int*   bat = (const int*)d_in[2];
    const float* W1  = (const float*)d_in[3];
    const float* as1 = (const float*)d_in[4];
    const float* ad1 = (const float*)d_in[5];
    const float* b1  = (const float*)d_in[6];
    const float* W2  = (const float*)d_in[7];
    const float* as2 = (const float*)d_in[8];
    const float* ad2 = (const float*)d_in[9];
    const float* b2  = (const float*)d_in[10];
    const float* Wh1 = (const float*)d_in[11];
    const float* bh1 = (const float*)d_in[12];
    const float* Wh2 = (const float*)d_in[13];
    const float* bh2 = (const float*)d_in[14];
    float* out = (float*)d_out;

    const int N  = in_sizes[0] / 128;
    const int E  = in_sizes[1] / 2;
    const int Ep = E + N;
    const int G  = 128;

    char* w = (char*)d_ws;
    size_t off = 0;
    auto alloc = [&](size_t bytes) -> char* {
        char* p = w + off; off += (bytes + 511) & ~(size_t)511; return p;
    };
    _Float16* x_h  = (_Float16*)alloc((size_t)N * 128 * 2);
    _Float16* agg  = (_Float16*)alloc((size_t)N * 512 * 2);
    _Float16* xh2h = (_Float16*)alloc((size_t)N * 128 * 2);
    float*    h2   = (float*)alloc((size_t)N * 128 * 4);
    float*    As1  = (float*)alloc((size_t)N * 4 * 4);
    float*    Ad1  = (float*)alloc((size_t)N * 4 * 4);
    float*    As2  = (float*)alloc((size_t)N * 4);
    float*    Ad2  = (float*)alloc((size_t)N * 4);
    float*    w_s1 = (float*)alloc(512 * 4);
    float*    w_d1 = (float*)alloc(512 * 4);
    _Float16* W1hi = (_Float16*)alloc(65536 * 2);
    _Float16* W1lo = (_Float16*)alloc(65536 * 2);
    _Float16* W2hi = (_Float16*)alloc(65536 * 2);
    _Float16* W2lo = (_Float16*)alloc(65536 * 2);
    int* startb = (int*)alloc((size_t)(N + 1) * 4);
    int* csr    = (int*)alloc((size_t)Ep * 4);
    int* sums   = (int*)alloc(4096);
    int* gstart = (int*)alloc((size_t)(G + 1) * 4);
    char* zbase = w + off;                                // zero-init group
    int*   deg    = (int*)alloc((size_t)N * 4);
    int*   cursor = (int*)alloc((size_t)N * 4);
    float* pooled = (float*)alloc((size_t)G * 128 * 4);
    size_t zbytes = (size_t)((w + off) - zbase);

    hipMemsetAsync(zbase, 0, zbytes, stream);

    // 1) fold attention vectors; logits + fp16 x
    k_wvec<<<4, 128, 0, stream>>>(W1, as1, ad1, w_s1, w_d1);
    k_attn_x<<<(N + 3) / 4, 256, 0, stream>>>(x, w_s1, w_d1, As1, Ad1, x_h, N);
    // 2) weights -> split fp16
    k_wcvt<<<256, 256, 0, stream>>>(W1, W1hi, W1lo, 65536);
    k_wcvt<<<256, 256, 0, stream>>>(W2, W2hi, W2lo, 65536);
    // 3) CSR by destination (self-loops appended)
    k_count<<<(Ep + 255) / 256, 256, 0, stream>>>(ei, deg, E, Ep);
    int nb = (N + 1 + 1023) / 1024;
    k_scanA<<<nb, 1024, 0, stream>>>(deg, startb, sums, N + 1, N);
    k_scanB<<<1, 64, 0, stream>>>(sums, nb);
    k_scanC<<<nb, 1024, 0, stream>>>(startb, sums, N + 1);
    k_fill<<<(Ep + 255) / 256, 256, 0, stream>>>(ei, startb, cursor, csr, E, Ep);
    // 4) graph boundaries
    k_gbound<<<(N + 255) / 256, 256, 0, stream>>>(bat, gstart, N, G);
    // 5) layer-1 gather (wave per dst) -> agg fp16 [N, 4*128]
    k_gat1<<<(N + 3) / 4, 256, 0, stream>>>(startb, csr, As1, Ad1, x_h, agg, N);
    // 6) fused MLP: GEMM1(+bias+elu, LDS) -> GEMM2 -> xh2 fp16 + attn2 logits
    k_mlp<<<(N + 63) / 64, 256, 0, stream>>>(
        agg, W1hi, W1lo, b1, W2hi, W2lo, as2, ad2, xh2h, As2, Ad2, N);
    // 7) layer-2 gather + bias + ELU -> h2 f32 (wave per dst)
    k_gat2<<<(N + 3) / 4, 256, 0, stream>>>(startb, csr, As2, Ad2, xh2h, b2, h2, N);
    // 8) two-stage pooling + MLP head
    k_poolA<<<(N + PCH - 1) / PCH, 128, 0, stream>>>(h2, bat, pooled, N);
    k_head<<<G, 128, 0, stream>>>(pooled, gstart, Wh1, bh1, Wh2, bh2, out);
}

// Round 10
// 469.541 us; speedup vs baseline: 1.0073x; 1.0073x over previous
//
#include <hip/hip_runtime.h>
#include <cstdint>
#include <cstddef>

#define NEG_SLOPE 0.2f

typedef _Float16 f16x8 __attribute__((ext_vector_type(8)));
typedef _Float16 f16x2 __attribute__((ext_vector_type(2)));
typedef float    f32x4 __attribute__((ext_vector_type(4)));

__device__ __forceinline__ float leaky(float x){ return x > 0.f ? x : NEG_SLOPE * x; }
__device__ __forceinline__ float elu(float x){ return x > 0.f ? x : __expf(x) - 1.f; }

// ============ split f32 -> fp16 hi + fp16 lo ============
__global__ void k_wcvt(const float* __restrict__ src, _Float16* __restrict__ hi,
                       _Float16* __restrict__ lo, int n)
{
    int i = blockIdx.x * 256 + threadIdx.x;
    if (i >= n) return;
    float v = src[i];
    _Float16 h = (_Float16)v;
    hi[i] = h;
    lo[i] = (_Float16)(v - (float)h);
}

// ============ fold attention vectors: w_s[h,k] = sum_c att_src[h,c] * W1[h*128+c, k] ============
__global__ __launch_bounds__(128) void k_wvec(const float* __restrict__ W1,
                                              const float* __restrict__ as1,
                                              const float* __restrict__ ad1,
                                              float* __restrict__ w_s,
                                              float* __restrict__ w_d)
{
    int h = blockIdx.x, k = threadIdx.x;
    float s = 0.f, d = 0.f;
    for (int c = 0; c < 128; ++c) {
        float w = W1[((size_t)(h * 128 + c)) * 128 + k];
        s += as1[h * 128 + c] * w;
        d += ad1[h * 128 + c] * w;
    }
    w_s[h * 128 + k] = s;
    w_d[h * 128 + k] = d;
}

// ============ layer-1 attention logits from raw x; also emit x as fp16 ============
__global__ __launch_bounds__(256) void k_attn_x(const float* __restrict__ x,
                                                const float* __restrict__ w_s,
                                                const float* __restrict__ w_d,
                                                float* __restrict__ a_s,
                                                float* __restrict__ a_d,
                                                _Float16* __restrict__ xh, int N)
{
    int n = blockIdx.x * 4 + (threadIdx.x >> 6);
    if (n >= N) return;
    int lane = threadIdx.x & 63;
    float2 xv = *(const float2*)(x + (size_t)n * 128 + lane * 2);
    f16x2 hv = { (_Float16)xv.x, (_Float16)xv.y };
    *(f16x2*)(xh + (size_t)n * 128 + lane * 2) = hv;
    float ps[4], pd[4];
    #pragma unroll
    for (int h = 0; h < 4; ++h) {
        float2 sv = *(const float2*)(w_s + h * 128 + lane * 2);
        float2 dv = *(const float2*)(w_d + h * 128 + lane * 2);
        ps[h] = xv.x * sv.x + xv.y * sv.y;
        pd[h] = xv.x * dv.x + xv.y * dv.y;
    }
    #pragma unroll
    for (int h = 0; h < 4; ++h)
        for (int off = 32; off; off >>= 1) {
            ps[h] += __shfl_xor(ps[h], off);
            pd[h] += __shfl_xor(pd[h], off);
        }
    if (lane == 0) {
        *(float4*)(a_s + (size_t)n * 4) = make_float4(ps[0], ps[1], ps[2], ps[3]);
        *(float4*)(a_d + (size_t)n * 4) = make_float4(pd[0], pd[1], pd[2], pd[3]);
    }
}

// ============ CSR construction ============
__global__ void k_count(const int* __restrict__ ei, int* __restrict__ deg, int E, int Ep)
{
    int e = blockIdx.x * blockDim.x + threadIdx.x;
    if (e >= Ep) return;
    int dst = (e < E) ? ei[E + e] : (e - E);
    atomicAdd(&deg[dst], 1);
}

__global__ __launch_bounds__(1024) void k_scanA(const int* __restrict__ deg,
                                                int* __restrict__ start,
                                                int* __restrict__ sums, int Ntot, int N)
{
    __shared__ int sm[1024];
    int tid = threadIdx.x;
    int i = blockIdx.x * 1024 + tid;
    int v = (i < N) ? deg[i] : 0;
    sm[tid] = v; __syncthreads();
    for (int off = 1; off < 1024; off <<= 1) {
        int t = (tid >= off) ? sm[tid - off] : 0;
        __syncthreads();
        sm[tid] += t;
        __syncthreads();
    }
    if (i < Ntot) start[i] = sm[tid] - v;
    if (tid == 1023) sums[blockIdx.x] = sm[1023];
}

__global__ void k_scanB(int* sums, int nb)
{
    int l = threadIdx.x;
    int v = (l < nb) ? sums[l] : 0;
    int orig = v;
    for (int off = 1; off < 64; off <<= 1) { int t = __shfl_up(v, off); if (l >= off) v += t; }
    if (l < nb) sums[l] = v - orig;
}

__global__ __launch_bounds__(1024) void k_scanC(int* __restrict__ start,
                                                const int* __restrict__ sums, int Ntot)
{
    int i = blockIdx.x * 1024 + threadIdx.x;
    if (i < Ntot) start[i] += sums[blockIdx.x];
}

__global__ void k_fill(const int* __restrict__ ei, const int* __restrict__ start,
                       int* __restrict__ cursor, int* __restrict__ csr_src, int E, int Ep)
{
    int e = blockIdx.x * blockDim.x + threadIdx.x;
    if (e >= Ep) return;
    int src, dst;
    if (e < E) { src = ei[e]; dst = ei[E + e]; } else { src = dst = e - E; }
    int pos = atomicAdd(&cursor[dst], 1);
    csr_src[start[dst] + pos] = src;
}

// ============ layer-1 gather: one WAVE per dst, 4-edge unrolled broadcast loop ============
__global__ __launch_bounds__(256) void k_gat1(const int* __restrict__ start,
                                              const int* __restrict__ csr,
                                              const float* __restrict__ a_s,
                                              const float* __restrict__ a_d,
                                              const _Float16* __restrict__ x,
                                              _Float16* __restrict__ agg, int N)
{
    int d = blockIdx.x * 4 + (threadIdx.x >> 6);
    if (d >= N) return;
    int lane = threadIdx.x & 63;
    int beg = start[d], end = start[d + 1];
    float4 ad4 = *(const float4*)(a_d + (size_t)d * 4);

    float sum0 = 0.f, sum1 = 0.f, sum2 = 0.f, sum3 = 0.f;
    float a00 = 0.f, a01 = 0.f, a10 = 0.f, a11 = 0.f;
    float a20 = 0.f, a21 = 0.f, a30 = 0.f, a31 = 0.f;
    const _Float16* xb = x + 2 * lane;

    for (int chunk = beg; chunk < end; chunk += 64) {
        int nchunk = end - chunk; if (nchunk > 64) nchunk = 64;
        int s = 0;
        float e0 = 0.f, e1 = 0.f, e2 = 0.f, e3 = 0.f;
        if (lane < nchunk) {
            s = csr[chunk + lane];
            float4 as4 = *(const float4*)(a_s + (size_t)s * 4);
            e0 = __expf(leaky(as4.x + ad4.x));
            e1 = __expf(leaky(as4.y + ad4.y));
            e2 = __expf(leaky(as4.z + ad4.z));
            e3 = __expf(leaky(as4.w + ad4.w));
            sum0 += e0; sum1 += e1; sum2 += e2; sum3 += e3;
        }
        int i = 0;
        for (; i + 4 <= nchunk; i += 4) {
            // batch src shuffles, fire 4 independent gathers, then weight shuffles
            int sA = __shfl(s, i),     sB = __shfl(s, i + 1);
            int sC = __shfl(s, i + 2), sD = __shfl(s, i + 3);
            f16x2 hA = *(const f16x2*)(xb + (size_t)sA * 128);
            f16x2 hB = *(const f16x2*)(xb + (size_t)sB * 128);
            f16x2 hC = *(const f16x2*)(xb + (size_t)sC * 128);
            f16x2 hD = *(const f16x2*)(xb + (size_t)sD * 128);
            float w0A = __shfl(e0, i),     w1A = __shfl(e1, i),     w2A = __shfl(e2, i),     w3A = __shfl(e3, i);
            float w0B = __shfl(e0, i + 1), w1B = __shfl(e1, i + 1), w2B = __shfl(e2, i + 1), w3B = __shfl(e3, i + 1);
            float w0C = __shfl(e0, i + 2), w1C = __shfl(e1, i + 2), w2C = __shfl(e2, i + 2), w3C = __shfl(e3, i + 2);
            float w0D = __shfl(e0, i + 3), w1D = __shfl(e1, i + 3), w2D = __shfl(e2, i + 3), w3D = __shfl(e3, i + 3);
            float vxA = (float)hA.x, vyA = (float)hA.y;
            float vxB = (float)hB.x, vyB = (float)hB.y;
            float vxC = (float)hC.x, vyC = (float)hC.y;
            float vxD = (float)hD.x, vyD = (float)hD.y;
            a00 += w0A * vxA + w0B * vxB + w0C * vxC + w0D * vxD;
            a01 += w0A * vyA + w0B * vyB + w0C * vyC + w0D * vyD;
            a10 += w1A * vxA + w1B * vxB + w1C * vxC + w1D * vxD;
            a11 += w1A * vyA + w1B * vyB + w1C * vyC + w1D * vyD;
            a20 += w2A * vxA + w2B * vxB + w2C * vxC + w2D * vxD;
            a21 += w2A * vyA + w2B * vyB + w2C * vyC + w2D * vyD;
            a30 += w3A * vxA + w3B * vxB + w3C * vxC + w3D * vxD;
            a31 += w3A * vyA + w3B * vyB + w3C * vyC + w3D * vyD;
        }
        for (; i < nchunk; ++i) {
            int   si = __shfl(s,  i);
            float w0 = __shfl(e0, i);
            float w1 = __shfl(e1, i);
            float w2 = __shfl(e2, i);
            float w3 = __shfl(e3, i);
            f16x2 hv = *(const f16x2*)(xb + (size_t)si * 128);
            float vx = (float)hv.x, vy = (float)hv.y;
            a00 += w0 * vx; a01 += w0 * vy;
            a10 += w1 * vx; a11 += w1 * vy;
            a20 += w2 * vx; a21 += w2 * vy;
            a30 += w3 * vx; a31 += w3 * vy;
        }
    }
    #pragma unroll
    for (int o = 32; o; o >>= 1) {
        sum0 += __shfl_xor(sum0, o); sum1 += __shfl_xor(sum1, o);
        sum2 += __shfl_xor(sum2, o); sum3 += __shfl_xor(sum3, o);
    }
    float i0 = 1.f / (sum0 + 1e-16f), i1 = 1.f / (sum1 + 1e-16f);
    float i2 = 1.f / (sum2 + 1e-16f), i3 = 1.f / (sum3 + 1e-16f);
    _Float16* o = agg + (size_t)d * 512 + 2 * lane;
    f16x2 o0 = {(_Float16)(a00 * i0), (_Float16)(a01 * i0)};
    f16x2 o1 = {(_Float16)(a10 * i1), (_Float16)(a11 * i1)};
    f16x2 o2 = {(_Float16)(a20 * i2), (_Float16)(a21 * i2)};
    f16x2 o3 = {(_Float16)(a30 * i3), (_Float16)(a31 * i3)};
    *(f16x2*)(o)       = o0;
    *(f16x2*)(o + 128) = o1;
    *(f16x2*)(o + 256) = o2;
    *(f16x2*)(o + 384) = o3;
}

// ============ FUSED MLP (M-tile 32, 4 blocks/CU): h1 in LDS; xh2 + attn2 logits ============
#define MT2 32
#define HP 520   // padded LDS row (halfs)
__global__ __launch_bounds__(256, 4) void k_mlp(
    const _Float16* __restrict__ agg,                                   // [N,512]
    const _Float16* __restrict__ W1h, const _Float16* __restrict__ W1l, // [512,128]
    const float* __restrict__ b1,
    const _Float16* __restrict__ W2h, const _Float16* __restrict__ W2l, // [128,512]
    const float* __restrict__ as2, const float* __restrict__ ad2,       // [128]
    _Float16* __restrict__ xh2, float* __restrict__ As2,
    float* __restrict__ Ad2, int N)
{
    __shared__ __align__(16) _Float16 s_h1[MT2 * HP];
    __shared__ float s_ss[4][MT2];
    __shared__ float s_sd[4][MT2];
    const int tid = threadIdx.x;
    const int wave = tid >> 6, lane = tid & 63;
    const int quad = lane >> 4, l16 = lane & 15;
    const int m0 = blockIdx.x * MT2;
    const int c0 = wave * 32;           // column slice within 128

    // ---------- GEMM1 per head (+bias+elu) -> s_h1 ----------
    #pragma unroll
    for (int h = 0; h < 4; ++h) {
        f16x8 af[2][4];
        #pragma unroll
        for (int r2 = 0; r2 < 2; ++r2) {
            int mrow = m0 + r2 * 16 + l16;
            #pragma unroll
            for (int kk = 0; kk < 4; ++kk) {
                f16x8 v = {};
                if (mrow < N) v = *(const f16x8*)(agg + (size_t)mrow * 512 + h * 128 + kk * 32 + quad * 8);
                af[r2][kk] = v;
            }
        }
        f32x4 acc[2][2] = {};
        #pragma unroll
        for (int kk = 0; kk < 4; ++kk) {
            f16x8 bh[2], bl[2];
            #pragma unroll
            for (int j = 0; j < 2; ++j) {
                size_t wo = (size_t)(h * 128 + c0 + j * 16 + l16) * 128 + kk * 32 + quad * 8;
                bh[j] = *(const f16x8*)(W1h + wo);
                bl[j] = *(const f16x8*)(W1l + wo);
            }
            #pragma unroll
            for (int r2 = 0; r2 < 2; ++r2) {
                acc[r2][0] = __builtin_amdgcn_mfma_f32_16x16x32_f16(af[r2][kk], bh[0], acc[r2][0], 0, 0, 0);
                acc[r2][0] = __builtin_amdgcn_mfma_f32_16x16x32_f16(af[r2][kk], bl[0], acc[r2][0], 0, 0, 0);
                acc[r2][1] = __builtin_amdgcn_mfma_f32_16x16x32_f16(af[r2][kk], bh[1], acc[r2][1], 0, 0, 0);
                acc[r2][1] = __builtin_amdgcn_mfma_f32_16x16x32_f16(af[r2][kk], bl[1], acc[r2][1], 0, 0, 0);
            }
        }
        #pragma unroll
        for (int j = 0; j < 2; ++j) {
            int n = c0 + j * 16 + l16;
            float bb = b1[h * 128 + n];
            #pragma unroll
            for (int r2 = 0; r2 < 2; ++r2)
                #pragma unroll
                for (int r = 0; r < 4; ++r)
                    s_h1[(r2 * 16 + quad * 4 + r) * HP + h * 128 + n] = (_Float16)elu(acc[r2][j][r] + bb);
        }
    }
    __syncthreads();

    // ---------- GEMM2 (K=512) from LDS -> xh2 fp16 + attn2 logit partials ----------
    f32x4 acc2[2][2] = {};
    #pragma unroll
    for (int kk = 0; kk < 16; ++kk) {
        f16x8 bh[2], bl[2];
        #pragma unroll
        for (int j = 0; j < 2; ++j) {
            size_t wo = (size_t)(c0 + j * 16 + l16) * 512 + kk * 32 + quad * 8;
            bh[j] = *(const f16x8*)(W2h + wo);
            bl[j] = *(const f16x8*)(W2l + wo);
        }
        #pragma unroll
        for (int r2 = 0; r2 < 2; ++r2) {
            f16x8 a = *(const f16x8*)&s_h1[(r2 * 16 + l16) * HP + kk * 32 + quad * 8];
            acc2[r2][0] = __builtin_amdgcn_mfma_f32_16x16x32_f16(a, bh[0], acc2[r2][0], 0, 0, 0);
            acc2[r2][0] = __builtin_amdgcn_mfma_f32_16x16x32_f16(a, bl[0], acc2[r2][0], 0, 0, 0);
            acc2[r2][1] = __builtin_amdgcn_mfma_f32_16x16x32_f16(a, bh[1], acc2[r2][1], 0, 0, 0);
            acc2[r2][1] = __builtin_amdgcn_mfma_f32_16x16x32_f16(a, bl[1], acc2[r2][1], 0, 0, 0);
        }
    }
    float ss[2][4] = {}, sd[2][4] = {};
    #pragma unroll
    for (int j = 0; j < 2; ++j) {
        int n = c0 + j * 16 + l16;
        float av = as2[n], dv = ad2[n];
        #pragma unroll
        for (int r2 = 0; r2 < 2; ++r2)
            #pragma unroll
            for (int r = 0; r < 4; ++r) {
                float v = acc2[r2][j][r];
                int d = m0 + r2 * 16 + quad * 4 + r;
                if (d < N) xh2[(size_t)d * 128 + n] = (_Float16)v;
                ss[r2][r] += v * av;
                sd[r2][r] += v * dv;
            }
    }
    #pragma unroll
    for (int o = 1; o < 16; o <<= 1)
        #pragma unroll
        for (int r2 = 0; r2 < 2; ++r2)
            #pragma unroll
            for (int r = 0; r < 4; ++r) {
                ss[r2][r] += __shfl_xor(ss[r2][r], o);
                sd[r2][r] += __shfl_xor(sd[r2][r], o);
            }
    if (l16 == 0) {
        #pragma unroll
        for (int r2 = 0; r2 < 2; ++r2)
            #pragma unroll
            for (int r = 0; r < 4; ++r) {
                int row = r2 * 16 + quad * 4 + r;
                s_ss[wave][row] = ss[r2][r];
                s_sd[wave][row] = sd[r2][r];
            }
    }
    __syncthreads();
    if (tid < MT2) {
        int d = m0 + tid;
        if (d < N) {
            As2[d] = s_ss[0][tid] + s_ss[1][tid] + s_ss[2][tid] + s_ss[3][tid];
            Ad2[d] = s_sd[0][tid] + s_sd[1][tid] + s_sd[2][tid] + s_sd[3][tid];
        }
    }
}

// ============ layer-2 gather (1 head) + bias + ELU -> h2 f32, 4-edge unrolled ============
__global__ __launch_bounds__(256) void k_gat2(const int* __restrict__ start,
                                              const int* __restrict__ csr,
                                              const float* __restrict__ a_s,
                                              const float* __restrict__ a_d,
                                              const _Float16* __restrict__ xh2,
                                              const float* __restrict__ b2,
                                              float* __restrict__ h2, int N)
{
    int d = blockIdx.x * 4 + (threadIdx.x >> 6);
    if (d >= N) return;
    int lane = threadIdx.x & 63;
    int beg = start[d], end = start[d + 1];
    float ad = a_d[d];

    float sum = 0.f, ax = 0.f, ay = 0.f;
    const _Float16* xb = xh2 + 2 * lane;

    for (int chunk = beg; chunk < end; chunk += 64) {
        int nchunk = end - chunk; if (nchunk > 64) nchunk = 64;
        int s = 0; float e = 0.f;
        if (lane < nchunk) {
            s = csr[chunk + lane];
            e = __expf(leaky(a_s[s] + ad));
            sum += e;
        }
        int i = 0;
        for (; i + 4 <= nchunk; i += 4) {
            int sA = __shfl(s, i),     sB = __shfl(s, i + 1);
            int sC = __shfl(s, i + 2), sD = __shfl(s, i + 3);
            f16x2 hA = *(const f16x2*)(xb + (size_t)sA * 128);
            f16x2 hB = *(const f16x2*)(xb + (size_t)sB * 128);
            f16x2 hC = *(const f16x2*)(xb + (size_t)sC * 128);
            f16x2 hD = *(const f16x2*)(xb + (size_t)sD * 128);
            float wA = __shfl(e, i),     wB = __shfl(e, i + 1);
            float wC = __shfl(e, i + 2), wD = __shfl(e, i + 3);
            ax += wA * (float)hA.x + wB * (float)hB.x + wC * (float)hC.x + wD * (float)hD.x;
            ay += wA * (float)hA.y + wB * (float)hB.y + wC * (float)hC.y + wD * (float)hD.y;
        }
        for (; i < nchunk; ++i) {
            int   si = __shfl(s, i);
            float w  = __shfl(e, i);
            f16x2 hv = *(const f16x2*)(xb + (size_t)si * 128);
            ax += w * (float)hv.x;
            ay += w * (float)hv.y;
        }
    }
    #pragma unroll
    for (int o = 32; o; o >>= 1) sum += __shfl_xor(sum, o);
    float inv = 1.f / (sum + 1e-16f);
    float2 bb = *(const float2*)(b2 + 2 * lane);
    float2 ov = make_float2(elu(ax * inv + bb.x), elu(ay * inv + bb.y));
    *(float2*)(h2 + (size_t)d * 128 + 2 * lane) = ov;
}

// ============ graph boundaries from SORTED batch ============
__global__ void k_gbound(const int* __restrict__ batch, int* __restrict__ gstart, int N, int G)
{
    int n = blockIdx.x * blockDim.x + threadIdx.x;
    if (n >= N) return;
    int b = batch[n];
    int prev = (n == 0) ? -1 : batch[n - 1];
    for (int g = prev + 1; g <= b; ++g) gstart[g] = n;
    if (n == N - 1)
        for (int g = b + 1; g <= G; ++g) gstart[g] = N;
}

// ============ pooling stage A: chunked partial sums ============
#define PCH 64
__global__ __launch_bounds__(128) void k_poolA(const float* __restrict__ h2,
                                               const int* __restrict__ batch,
                                               float* __restrict__ pooled, int N)
{
    int c = threadIdx.x;
    int n0 = blockIdx.x * PCH;
    int n1 = n0 + PCH < N ? n0 + PCH : N;
    if (n0 >= N) return;
    int g = batch[n0];
    float acc = 0.f;
    for (int n = n0; n < n1; ++n) {
        int bg = batch[n];
        if (bg != g) { atomicAdd(&pooled[(size_t)g * 128 + c], acc); acc = 0.f; g = bg; }
        acc += h2[(size_t)n * 128 + c];
    }
    atomicAdd(&pooled[(size_t)g * 128 + c], acc);
}

// ============ head: mean + relu(pooled@Wh1^T+bh1) @ Wh2^T + bh2 ============
__global__ __launch_bounds__(128) void k_head(const float* __restrict__ pooled,
                                              const int* __restrict__ gstart,
                                              const float* __restrict__ Wh1,
                                              const float* __restrict__ bh1,
                                              const float* __restrict__ Wh2,
                                              const float* __restrict__ bh2,
                                              float* __restrict__ out)
{
    int g = blockIdx.x, c = threadIdx.x;
    __shared__ float p[128];
    __shared__ float red[128];
    float cf = (float)(gstart[g + 1] - gstart[g]); cf = cf > 1.f ? cf : 1.f;
    p[c] = pooled[(size_t)g * 128 + c] / cf;
    __syncthreads();
    float z = bh1[c];
    for (int k = 0; k < 128; ++k) z += p[k] * Wh1[c * 128 + k];
    z = z > 0.f ? z : 0.f;
    red[c] = z * Wh2[c];
    __syncthreads();
    for (int st = 64; st > 0; st >>= 1) { if (c < st) red[c] += red[c + st]; __syncthreads(); }
    if (c == 0) out[g] = red[0] + bh2[0];
}

// ============ launch ============
extern "C" void kernel_launch(void* const* d_in, const int* in_sizes, int n_in,
                              void* d_out, int out_size, void* d_ws, size_t ws_size,
                              hipStream_t stream)
{
    const float* x   = (const float*)d_in[0];
    const int*   ei  = (const int*)d_in[1];
    const int*   bat = (const int*)d_in[2];
    const float* W1  = (const float*)d_in[3];
    const float* as1 = (const float*)d_in[4];
    const float* ad1 = (const float*)d_in[5];
    const float* b1  = (const float*)d_in[6];
    const float* W2  = (const float*)d_in[7];
    const float* as2 = (const float*)d_in[8];
    const float* ad2 = (const float*)d_in[9];
    const float* b2  = (const float*)d_in[10];
    const float* Wh1 = (const float*)d_in[11];
    const float* bh1 = (const float*)d_in[12];
    const float* Wh2 = (const float*)d_in[13];
    const float* bh2 = (const float*)d_in[14];
    float* out = (float*)d_out;

    const int N  = in_sizes[0] / 128;
    const int E  = in_sizes[1] / 2;
    const int Ep = E + N;
    const int G  = 128;

    char* w = (char*)d_ws;
    size_t off = 0;
    auto alloc = [&](size_t bytes) -> char* {
        char* p = w + off; off += (bytes + 511) & ~(size_t)511; return p;
    };
    _Float16* x_h  = (_Float16*)alloc((size_t)N * 128 * 2);
    _Float16* agg  = (_Float16*)alloc((size_t)N * 512 * 2);
    _Float16* xh2h = (_Float16*)alloc((size_t)N * 128 * 2);
    float*    h2   = (float*)alloc((size_t)N * 128 * 4);
    float*    As1  = (float*)alloc((size_t)N * 4 * 4);
    float*    Ad1  = (float*)alloc((size_t)N * 4 * 4);
    float*    As2  = (float*)alloc((size_t)N * 4);
    float*    Ad2  = (float*)alloc((size_t)N * 4);
    float*    w_s1 = (float*)alloc(512 * 4);
    float*    w_d1 = (float*)alloc(512 * 4);
    _Float16* W1hi = (_Float16*)alloc(65536 * 2);
    _Float16* W1lo = (_Float16*)alloc(65536 * 2);
    _Float16* W2hi = (_Float16*)alloc(65536 * 2);
    _Float16* W2lo = (_Float16*)alloc(65536 * 2);
    int* startb = (int*)alloc((size_t)(N + 1) * 4);
    int* csr    = (int*)alloc((size_t)Ep * 4);
    int* sums   = (int*)alloc(4096);
    int* gstart = (int*)alloc((size_t)(G + 1) * 4);
    char* zbase = w + off;                                // zero-init group
    int*   deg    = (int*)alloc((size_t)N * 4);
    int*   cursor = (int*)alloc((size_t)N * 4);
    float* pooled = (float*)alloc((size_t)G * 128 * 4);
    size_t zbytes = (size_t)((w + off) - zbase);

    hipMemsetAsync(zbase, 0, zbytes, stream);

    // 1) fold attention vectors; logits + fp16 x
    k_wvec<<<4, 128, 0, stream>>>(W1, as1, ad1, w_s1, w_d1);
    k_attn_x<<<(N + 3) / 4, 256, 0, stream>>>(x, w_s1, w_d1, As1, Ad1, x_h, N);
    // 2) weights -> split fp16
    k_wcvt<<<256, 256, 0, stream>>>(W1, W1hi, W1lo, 65536);
    k_wcvt<<<256, 256, 0, stream>>>(W2, W2hi, W2lo, 65536);
    // 3) CSR by destination (self-loops appended)
    k_count<<<(Ep + 255) / 256, 256, 0, stream>>>(ei, deg, E, Ep);
    int nb = (N + 1 + 1023) / 1024;
    k_scanA<<<nb, 1024, 0, stream>>>(deg, startb, sums, N + 1, N);
    k_scanB<<<1, 64, 0, stream>>>(sums, nb);
    k_scanC<<<nb, 1024, 0, stream>>>(startb, sums, N + 1);
    k_fill<<<(Ep + 255) / 256, 256, 0, stream>>>(ei, startb, cursor, csr, E, Ep);
    // 4) graph boundaries
    k_gbound<<<(N + 255) / 256, 256, 0, stream>>>(bat, gstart, N, G);
    // 5) layer-1 gather (wave per dst, unrolled) -> agg fp16 [N, 4*128]
    k_gat1<<<(N + 3) / 4, 256, 0, stream>>>(startb, csr, As1, Ad1, x_h, agg, N);
    // 6) fused MLP (M=32): GEMM1(+bias+elu, LDS) -> GEMM2 -> xh2 fp16 + attn2 logits
    k_mlp<<<(N + MT2 - 1) / MT2, 256, 0, stream>>>(
        agg, W1hi, W1lo, b1, W2hi, W2lo, as2, ad2, xh2h, As2, Ad2, N);
    // 7) layer-2 gather + bias + ELU -> h2 f32 (wave per dst, unrolled)
    k_gat2<<<(N + 3) / 4, 256, 0, stream>>>(startb, csr, As2, Ad2, xh2h, b2, h2, N);
    // 8) two-stage pooling + MLP head
    k_poolA<<<(N + PCH - 1) / PCH, 128, 0, stream>>>(h2, bat, pooled, N);
    k_head<<<G, 128, 0, stream>>>(pooled, gstart, Wh1, bh1, Wh2, bh2, out);
}

// Round 11
// 436.578 us; speedup vs baseline: 1.0834x; 1.0755x over previous
//
#include <hip/hip_runtime.h>
#include <cstdint>
#include <cstddef>

#define NEG_SLOPE 0.2f

typedef _Float16 f16x8 __attribute__((ext_vector_type(8)));
typedef _Float16 f16x2 __attribute__((ext_vector_type(2)));
typedef float    f32x4 __attribute__((ext_vector_type(4)));

__device__ __forceinline__ float leaky(float x){ return x > 0.f ? x : NEG_SLOPE * x; }
__device__ __forceinline__ float elu(float x){ return x > 0.f ? x : __expf(x) - 1.f; }

// ============ split f32 -> fp16 hi + fp16 lo ============
__global__ void k_wcvt(const float* __restrict__ src, _Float16* __restrict__ hi,
                       _Float16* __restrict__ lo, int n)
{
    int i = blockIdx.x * 256 + threadIdx.x;
    if (i >= n) return;
    float v = src[i];
    _Float16 h = (_Float16)v;
    hi[i] = h;
    lo[i] = (_Float16)(v - (float)h);
}

// ============ fp16-A x split-fp16-B MFMA GEMM (tile 128x128, BK=32, z = heads) ============
// Proven r7 structure: LDS-staged A and B, 4 waves 2x2, ~88 VGPR, 2 blocks/CU.
template<bool FUSE_BIAS_ELU>
__global__ __launch_bounds__(256, 2) void k_gemm_h(
    const _Float16* __restrict__ A, const _Float16* __restrict__ Bh,
    const _Float16* __restrict__ Bl, const float* __restrict__ bias,
    _Float16* __restrict__ C,
    int M, int K, int lda, int ldb, int ldc,
    long aZ, long bZ, long cZ, long biasZ)
{
    constexpr int LS = 40;   // halfs per LDS row (32 + 8 pad)
    __shared__ __align__(16) _Float16 As [128 * LS];
    __shared__ __align__(16) _Float16 Bhs[128 * LS];
    __shared__ __align__(16) _Float16 Bls[128 * LS];

    const _Float16* Ab  = A  + (size_t)blockIdx.z * aZ;
    const _Float16* Bhb = Bh + (size_t)blockIdx.z * bZ;
    const _Float16* Blb = Bl + (size_t)blockIdx.z * bZ;
    _Float16* Cb = C + (size_t)blockIdx.z * cZ;

    const int tid = threadIdx.x;
    const int wave = tid >> 6, lane = tid & 63;
    const int wm = wave >> 1, wn = wave & 1;
    const int quad = lane >> 4, l16 = lane & 15;
    const int m0 = blockIdx.x * 128;

    f32x4 acc[4][4] = {};

    for (int k0 = 0; k0 < K; k0 += 32) {
        #pragma unroll
        for (int q = 0; q < 2; ++q) {
            int idx = tid + q * 256;            // 0..511: row 0..127, kq 0..3
            int row = idx >> 2, kq = idx & 3;
            int rg = m0 + row;
            f16x8 va = {};
            if (rg < M) va = *(const f16x8*)(Ab + (size_t)rg * lda + k0 + kq * 8);
            *(f16x8*)&As[row * LS + kq * 8] = va;
            *(f16x8*)&Bhs[row * LS + kq * 8] = *(const f16x8*)(Bhb + (size_t)row * ldb + k0 + kq * 8);
            *(f16x8*)&Bls[row * LS + kq * 8] = *(const f16x8*)(Blb + (size_t)row * ldb + k0 + kq * 8);
        }
        __syncthreads();

        f16x8 af[4], bhf[4], blf[4];
        #pragma unroll
        for (int i = 0; i < 4; ++i) {
            int mr = wm * 64 + i * 16 + l16;
            af[i] = *(const f16x8*)&As[mr * LS + quad * 8];
            int nr = wn * 64 + i * 16 + l16;
            bhf[i] = *(const f16x8*)&Bhs[nr * LS + quad * 8];
            blf[i] = *(const f16x8*)&Bls[nr * LS + quad * 8];
        }
        #pragma unroll
        for (int i = 0; i < 4; ++i)
            #pragma unroll
            for (int j = 0; j < 4; ++j) {
                acc[i][j] = __builtin_amdgcn_mfma_f32_16x16x32_f16(af[i], bhf[j], acc[i][j], 0, 0, 0);
                acc[i][j] = __builtin_amdgcn_mfma_f32_16x16x32_f16(af[i], blf[j], acc[i][j], 0, 0, 0);
            }
        __syncthreads();
    }

    #pragma unroll
    for (int j = 0; j < 4; ++j) {
        int n = wn * 64 + j * 16 + l16;
        float bb = 0.f;
        if (FUSE_BIAS_ELU) bb = bias[blockIdx.z * biasZ + n];
        #pragma unroll
        for (int i = 0; i < 4; ++i)
            #pragma unroll
            for (int r = 0; r < 4; ++r) {
                int m = m0 + wm * 64 + i * 16 + quad * 4 + r;
                if (m < M) {
                    float v = acc[i][j][r];
                    if (FUSE_BIAS_ELU) v = elu(v + bb);
                    Cb[(size_t)m * ldc + n] = (_Float16)v;
                }
            }
    }
}

// ============ fold attention vectors: w_s[h,k] = sum_c att_src[h,c] * W1[h*128+c, k] ============
__global__ __launch_bounds__(128) void k_wvec(const float* __restrict__ W1,
                                              const float* __restrict__ as1,
                                              const float* __restrict__ ad1,
                                              float* __restrict__ w_s,
                                              float* __restrict__ w_d)
{
    int h = blockIdx.x, k = threadIdx.x;
    float s = 0.f, d = 0.f;
    for (int c = 0; c < 128; ++c) {
        float w = W1[((size_t)(h * 128 + c)) * 128 + k];
        s += as1[h * 128 + c] * w;
        d += ad1[h * 128 + c] * w;
    }
    w_s[h * 128 + k] = s;
    w_d[h * 128 + k] = d;
}

// ============ layer-1 attention logits from raw x; also emit x as fp16 ============
__global__ __launch_bounds__(256) void k_attn_x(const float* __restrict__ x,
                                                const float* __restrict__ w_s,
                                                const float* __restrict__ w_d,
                                                float* __restrict__ a_s,
                                                float* __restrict__ a_d,
                                                _Float16* __restrict__ xh, int N)
{
    int n = blockIdx.x * 4 + (threadIdx.x >> 6);
    if (n >= N) return;
    int lane = threadIdx.x & 63;
    float2 xv = *(const float2*)(x + (size_t)n * 128 + lane * 2);
    f16x2 hv = { (_Float16)xv.x, (_Float16)xv.y };
    *(f16x2*)(xh + (size_t)n * 128 + lane * 2) = hv;
    float ps[4], pd[4];
    #pragma unroll
    for (int h = 0; h < 4; ++h) {
        float2 sv = *(const float2*)(w_s + h * 128 + lane * 2);
        float2 dv = *(const float2*)(w_d + h * 128 + lane * 2);
        ps[h] = xv.x * sv.x + xv.y * sv.y;
        pd[h] = xv.x * dv.x + xv.y * dv.y;
    }
    #pragma unroll
    for (int h = 0; h < 4; ++h)
        for (int off = 32; off; off >>= 1) {
            ps[h] += __shfl_xor(ps[h], off);
            pd[h] += __shfl_xor(pd[h], off);
        }
    if (lane == 0) {
        *(float4*)(a_s + (size_t)n * 4) = make_float4(ps[0], ps[1], ps[2], ps[3]);
        *(float4*)(a_d + (size_t)n * 4) = make_float4(pd[0], pd[1], pd[2], pd[3]);
    }
}

// ============ layer-2 attention logits from fp16 xh2 ============
__global__ __launch_bounds__(256) void k_attn2(const _Float16* __restrict__ xh,
                                               const float* __restrict__ as2,
                                               const float* __restrict__ ad2,
                                               float* __restrict__ a_s,
                                               float* __restrict__ a_d, int N)
{
    int n = blockIdx.x * 4 + (threadIdx.x >> 6);
    if (n >= N) return;
    int lane = threadIdx.x & 63;
    f16x2 xv = *(const f16x2*)(xh + (size_t)n * 128 + lane * 2);
    float vx = (float)xv.x, vy = (float)xv.y;
    float2 sv = *(const float2*)(as2 + lane * 2);
    float2 dv = *(const float2*)(ad2 + lane * 2);
    float ps = vx * sv.x + vy * sv.y;
    float pd = vx * dv.x + vy * dv.y;
    for (int off = 32; off; off >>= 1) { ps += __shfl_xor(ps, off); pd += __shfl_xor(pd, off); }
    if (lane == 0) { a_s[n] = ps; a_d[n] = pd; }
}

// ============ CSR construction ============
__global__ void k_count(const int* __restrict__ ei, int* __restrict__ deg, int E, int Ep)
{
    int e = blockIdx.x * blockDim.x + threadIdx.x;
    if (e >= Ep) return;
    int dst = (e < E) ? ei[E + e] : (e - E);
    atomicAdd(&deg[dst], 1);
}

__global__ __launch_bounds__(1024) void k_scanA(const int* __restrict__ deg,
                                                int* __restrict__ start,
                                                int* __restrict__ sums, int Ntot, int N)
{
    __shared__ int sm[1024];
    int tid = threadIdx.x;
    int i = blockIdx.x * 1024 + tid;
    int v = (i < N) ? deg[i] : 0;
    sm[tid] = v; __syncthreads();
    for (int off = 1; off < 1024; off <<= 1) {
        int t = (tid >= off) ? sm[tid - off] : 0;
        __syncthreads();
        sm[tid] += t;
        __syncthreads();
    }
    if (i < Ntot) start[i] = sm[tid] - v;
    if (tid == 1023) sums[blockIdx.x] = sm[1023];
}

__global__ void k_scanB(int* sums, int nb)
{
    int l = threadIdx.x;
    int v = (l < nb) ? sums[l] : 0;
    int orig = v;
    for (int off = 1; off < 64; off <<= 1) { int t = __shfl_up(v, off); if (l >= off) v += t; }
    if (l < nb) sums[l] = v - orig;
}

__global__ __launch_bounds__(1024) void k_scanC(int* __restrict__ start,
                                                const int* __restrict__ sums, int Ntot)
{
    int i = blockIdx.x * 1024 + threadIdx.x;
    if (i < Ntot) start[i] += sums[blockIdx.x];
}

__global__ void k_fill(const int* __restrict__ ei, const int* __restrict__ start,
                       int* __restrict__ cursor, int* __restrict__ csr_src, int E, int Ep)
{
    int e = blockIdx.x * blockDim.x + threadIdx.x;
    if (e >= Ep) return;
    int src, dst;
    if (e < E) { src = ei[e]; dst = ei[E + e]; } else { src = dst = e - E; }
    int pos = atomicAdd(&cursor[dst], 1);
    csr_src[start[dst] + pos] = src;
}

// ============ layer-1 gather: one WAVE per dst, 4-edge unrolled broadcast loop ============
__global__ __launch_bounds__(256) void k_gat1(const int* __restrict__ start,
                                              const int* __restrict__ csr,
                                              const float* __restrict__ a_s,
                                              const float* __restrict__ a_d,
                                              const _Float16* __restrict__ x,
                                              _Float16* __restrict__ agg, int N)
{
    int d = blockIdx.x * 4 + (threadIdx.x >> 6);
    if (d >= N) return;
    int lane = threadIdx.x & 63;
    int beg = start[d], end = start[d + 1];
    float4 ad4 = *(const float4*)(a_d + (size_t)d * 4);

    float sum0 = 0.f, sum1 = 0.f, sum2 = 0.f, sum3 = 0.f;
    float a00 = 0.f, a01 = 0.f, a10 = 0.f, a11 = 0.f;
    float a20 = 0.f, a21 = 0.f, a30 = 0.f, a31 = 0.f;
    const _Float16* xb = x + 2 * lane;

    for (int chunk = beg; chunk < end; chunk += 64) {
        int nchunk = end - chunk; if (nchunk > 64) nchunk = 64;
        int s = 0;
        float e0 = 0.f, e1 = 0.f, e2 = 0.f, e3 = 0.f;
        if (lane < nchunk) {
            s = csr[chunk + lane];
            float4 as4 = *(const float4*)(a_s + (size_t)s * 4);
            e0 = __expf(leaky(as4.x + ad4.x));
            e1 = __expf(leaky(as4.y + ad4.y));
            e2 = __expf(leaky(as4.z + ad4.z));
            e3 = __expf(leaky(as4.w + ad4.w));
            sum0 += e0; sum1 += e1; sum2 += e2; sum3 += e3;
        }
        int i = 0;
        for (; i + 4 <= nchunk; i += 4) {
            int sA = __shfl(s, i),     sB = __shfl(s, i + 1);
            int sC = __shfl(s, i + 2), sD = __shfl(s, i + 3);
            f16x2 hA = *(const f16x2*)(xb + (size_t)sA * 128);
            f16x2 hB = *(const f16x2*)(xb + (size_t)sB * 128);
            f16x2 hC = *(const f16x2*)(xb + (size_t)sC * 128);
            f16x2 hD = *(const f16x2*)(xb + (size_t)sD * 128);
            float w0A = __shfl(e0, i),     w1A = __shfl(e1, i),     w2A = __shfl(e2, i),     w3A = __shfl(e3, i);
            float w0B = __shfl(e0, i + 1), w1B = __shfl(e1, i + 1), w2B = __shfl(e2, i + 1), w3B = __shfl(e3, i + 1);
            float w0C = __shfl(e0, i + 2), w1C = __shfl(e1, i + 2), w2C = __shfl(e2, i + 2), w3C = __shfl(e3, i + 2);
            float w0D = __shfl(e0, i + 3), w1D = __shfl(e1, i + 3), w2D = __shfl(e2, i + 3), w3D = __shfl(e3, i + 3);
            float vxA = (float)hA.x, vyA = (float)hA.y;
            float vxB = (float)hB.x, vyB = (float)hB.y;
            float vxC = (float)hC.x, vyC = (float)hC.y;
            float vxD = (float)hD.x, vyD = (float)hD.y;
            a00 += w0A * vxA + w0B * vxB + w0C * vxC + w0D * vxD;
            a01 += w0A * vyA + w0B * vyB + w0C * vyC + w0D * vyD;
            a10 += w1A * vxA + w1B * vxB + w1C * vxC + w1D * vxD;
            a11 += w1A * vyA + w1B * vyB + w1C * vyC + w1D * vyD;
            a20 += w2A * vxA + w2B * vxB + w2C * vxC + w2D * vxD;
            a21 += w2A * vyA + w2B * vyB + w2C * vyC + w2D * vyD;
            a30 += w3A * vxA + w3B * vxB + w3C * vxC + w3D * vxD;
            a31 += w3A * vyA + w3B * vyB + w3C * vyC + w3D * vyD;
        }
        for (; i < nchunk; ++i) {
            int   si = __shfl(s,  i);
            float w0 = __shfl(e0, i);
            float w1 = __shfl(e1, i);
            float w2 = __shfl(e2, i);
            float w3 = __shfl(e3, i);
            f16x2 hv = *(const f16x2*)(xb + (size_t)si * 128);
            float vx = (float)hv.x, vy = (float)hv.y;
            a00 += w0 * vx; a01 += w0 * vy;
            a10 += w1 * vx; a11 += w1 * vy;
            a20 += w2 * vx; a21 += w2 * vy;
            a30 += w3 * vx; a31 += w3 * vy;
        }
    }
    #pragma unroll
    for (int o = 32; o; o >>= 1) {
        sum0 += __shfl_xor(sum0, o); sum1 += __shfl_xor(sum1, o);
        sum2 += __shfl_xor(sum2, o); sum3 += __shfl_xor(sum3, o);
    }
    float i0 = 1.f / (sum0 + 1e-16f), i1 = 1.f / (sum1 + 1e-16f);
    float i2 = 1.f / (sum2 + 1e-16f), i3 = 1.f / (sum3 + 1e-16f);
    _Float16* o = agg + (size_t)d * 512 + 2 * lane;
    f16x2 o0 = {(_Float16)(a00 * i0), (_Float16)(a01 * i0)};
    f16x2 o1 = {(_Float16)(a10 * i1), (_Float16)(a11 * i1)};
    f16x2 o2 = {(_Float16)(a20 * i2), (_Float16)(a21 * i2)};
    f16x2 o3 = {(_Float16)(a30 * i3), (_Float16)(a31 * i3)};
    *(f16x2*)(o)       = o0;
    *(f16x2*)(o + 128) = o1;
    *(f16x2*)(o + 256) = o2;
    *(f16x2*)(o + 384) = o3;
}

// ============ layer-2 gather (1 head) + bias + ELU -> h2 f32, 4-edge unrolled ============
__global__ __launch_bounds__(256) void k_gat2(const int* __restrict__ start,
                                              const int* __restrict__ csr,
                                              const float* __restrict__ a_s,
                                              const float* __restrict__ a_d,
                                              const _Float16* __restrict__ xh2,
                                              const float* __restrict__ b2,
                                              float* __restrict__ h2, int N)
{
    int d = blockIdx.x * 4 + (threadIdx.x >> 6);
    if (d >= N) return;
    int lane = threadIdx.x & 63;
    int beg = start[d], end = start[d + 1];
    float ad = a_d[d];

    float sum = 0.f, ax = 0.f, ay = 0.f;
    const _Float16* xb = xh2 + 2 * lane;

    for (int chunk = beg; chunk < end; chunk += 64) {
        int nchunk = end - chunk; if (nchunk > 64) nchunk = 64;
        int s = 0; float e = 0.f;
        if (lane < nchunk) {
            s = csr[chunk + lane];
            e = __expf(leaky(a_s[s] + ad));
            sum += e;
        }
        int i = 0;
        for (; i + 4 <= nchunk; i += 4) {
            int sA = __shfl(s, i),     sB = __shfl(s, i + 1);
            int sC = __shfl(s, i + 2), sD = __shfl(s, i + 3);
            f16x2 hA = *(const f16x2*)(xb + (size_t)sA * 128);
            f16x2 hB = *(const f16x2*)(xb + (size_t)sB * 128);
            f16x2 hC = *(const f16x2*)(xb + (size_t)sC * 128);
            f16x2 hD = *(const f16x2*)(xb + (size_t)sD * 128);
            float wA = __shfl(e, i),     wB = __shfl(e, i + 1);
            float wC = __shfl(e, i + 2), wD = __shfl(e, i + 3);
            ax += wA * (float)hA.x + wB * (float)hB.x + wC * (float)hC.x + wD * (float)hD.x;
            ay += wA * (float)hA.y + wB * (float)hB.y + wC * (float)hC.y + wD * (float)hD.y;
        }
        for (; i < nchunk; ++i) {
            int   si = __shfl(s, i);
            float w  = __shfl(e, i);
            f16x2 hv = *(const f16x2*)(xb + (size_t)si * 128);
            ax += w * (float)hv.x;
            ay += w * (float)hv.y;
        }
    }
    #pragma unroll
    for (int o = 32; o; o >>= 1) sum += __shfl_xor(sum, o);
    float inv = 1.f / (sum + 1e-16f);
    float2 bb = *(const float2*)(b2 + 2 * lane);
    float2 ov = make_float2(elu(ax * inv + bb.x), elu(ay * inv + bb.y));
    *(float2*)(h2 + (size_t)d * 128 + 2 * lane) = ov;
}

// ============ graph boundaries from SORTED batch ============
__global__ void k_gbound(const int* __restrict__ batch, int* __restrict__ gstart, int N, int G)
{
    int n = blockIdx.x * blockDim.x + threadIdx.x;
    if (n >= N) return;
    int b = batch[n];
    int prev = (n == 0) ? -1 : batch[n - 1];
    for (int g = prev + 1; g <= b; ++g) gstart[g] = n;
    if (n == N - 1)
        for (int g = b + 1; g <= G; ++g) gstart[g] = N;
}

// ============ pooling stage A: chunked partial sums ============
#define PCH 64
__global__ __launch_bounds__(128) void k_poolA(const float* __restrict__ h2,
                                               const int* __restrict__ batch,
                                               float* __restrict__ pooled, int N)
{
    int c = threadIdx.x;
    int n0 = blockIdx.x * PCH;
    int n1 = n0 + PCH < N ? n0 + PCH : N;
    if (n0 >= N) return;
    int g = batch[n0];
    float acc = 0.f;
    for (int n = n0; n < n1; ++n) {
        int bg = batch[n];
        if (bg != g) { atomicAdd(&pooled[(size_t)g * 128 + c], acc); acc = 0.f; g = bg; }
        acc += h2[(size_t)n * 128 + c];
    }
    atomicAdd(&pooled[(size_t)g * 128 + c], acc);
}

// ============ head: mean + relu(pooled@Wh1^T+bh1) @ Wh2^T + bh2 ============
__global__ __launch_bounds__(128) void k_head(const float* __restrict__ pooled,
                                              const int* __restrict__ gstart,
                                              const float* __restrict__ Wh1,
                                              const float* __restrict__ bh1,
                                              const float* __restrict__ Wh2,
                                              const float* __restrict__ bh2,
                                              float* __restrict__ out)
{
    int g = blockIdx.x, c = threadIdx.x;
    __shared__ float p[128];
    __shared__ float red[128];
    float cf = (float)(gstart[g + 1] - gstart[g]); cf = cf > 1.f ? cf : 1.f;
    p[c] = pooled[(size_t)g * 128 + c] / cf;
    __syncthreads();
    float z = bh1[c];
    for (int k = 0; k < 128; ++k) z += p[k] * Wh1[c * 128 + k];
    z = z > 0.f ? z : 0.f;
    red[c] = z * Wh2[c];
    __syncthreads();
    for (int st = 64; st > 0; st >>= 1) { if (c < st) red[c] += red[c + st]; __syncthreads(); }
    if (c == 0) out[g] = red[0] + bh2[0];
}

// ============ launch ============
extern "C" void kernel_launch(void* const* d_in, const int* in_sizes, int n_in,
                              void* d_out, int out_size, void* d_ws, size_t ws_size,
                              hipStream_t stream)
{
    const float* x   = (const float*)d_in[0];
    const int*   ei  = (const int*)d_in[1];
    const int*   bat = (const int*)d_in[2];
    const float* W1  = (const float*)d_in[3];
    const float* as1 = (const float*)d_in[4];
    const float* ad1 = (const float*)d_in[5];
    const float* b1  = (const float*)d_in[6];
    const float* W2  = (const float*)d_in[7];
    const float* as2 = (const float*)d_in[8];
    const float* ad2 = (const float*)d_in[9];
    const float* b2  = (const float*)d_in[10];
    const float* Wh1 = (const float*)d_in[11];
    const float* bh1 = (const float*)d_in[12];
    const float* Wh2 = (const float*)d_in[13];
    const float* bh2 = (const float*)d_in[14];
    float* out = (float*)d_out;

    const int N  = in_sizes[0] / 128;
    const int E  = in_sizes[1] / 2;
    const int Ep = E + N;
    const int G  = 128;

    char* w = (char*)d_ws;
    size_t off = 0;
    auto alloc = [&](size_t bytes) -> char* {
        char* p = w + off; off += (bytes + 511) & ~(size_t)511; return p;
    };
    _Float16* x_h  = (_Float16*)alloc((size_t)N * 128 * 2);
    _Float16* agg  = (_Float16*)alloc((size_t)N * 512 * 2);
    _Float16* h1   = (_Float16*)alloc((size_t)N * 512 * 2);
    _Float16* xh2h = (_Float16*)alloc((size_t)N * 128 * 2);
    float*    h2   = (float*)alloc((size_t)N * 128 * 4);
    float*    As1  = (float*)alloc((size_t)N * 4 * 4);
    float*    Ad1  = (float*)alloc((size_t)N * 4 * 4);
    float*    As2  = (float*)alloc((size_t)N * 4);
    float*    Ad2  = (float*)alloc((size_t)N * 4);
    float*    w_s1 = (float*)alloc(512 * 4);
    float*    w_d1 = (float*)alloc(512 * 4);
    _Float16* W1hi = (_Float16*)alloc(65536 * 2);
    _Float16* W1lo = (_Float16*)alloc(65536 * 2);
    _Float16* W2hi = (_Float16*)alloc(65536 * 2);
    _Float16* W2lo = (_Float16*)alloc(65536 * 2);
    int* startb = (int*)alloc((size_t)(N + 1) * 4);
    int* csr    = (int*)alloc((size_t)Ep * 4);
    int* sums   = (int*)alloc(4096);
    int* gstart = (int*)alloc((size_t)(G + 1) * 4);
    char* zbase = w + off;                                // zero-init group
    int*   deg    = (int*)alloc((size_t)N * 4);
    int*   cursor = (int*)alloc((size_t)N * 4);
    float* pooled = (float*)alloc((size_t)G * 128 * 4);
    size_t zbytes = (size_t)((w + off) - zbase);

    hipMemsetAsync(zbase, 0, zbytes, stream);

    // 1) fold attention vectors; logits + fp16 x
    k_wvec<<<4, 128, 0, stream>>>(W1, as1, ad1, w_s1, w_d1);
    k_attn_x<<<(N + 3) / 4, 256, 0, stream>>>(x, w_s1, w_d1, As1, Ad1, x_h, N);
    // 2) weights -> split fp16
    k_wcvt<<<256, 256, 0, stream>>>(W1, W1hi, W1lo, 65536);
    k_wcvt<<<256, 256, 0, stream>>>(W2, W2hi, W2lo, 65536);
    // 3) CSR by destination (self-loops appended)
    k_count<<<(Ep + 255) / 256, 256, 0, stream>>>(ei, deg, E, Ep);
    int nb = (N + 1 + 1023) / 1024;
    k_scanA<<<nb, 1024, 0, stream>>>(deg, startb, sums, N + 1, N);
    k_scanB<<<1, 64, 0, stream>>>(sums, nb);
    k_scanC<<<nb, 1024, 0, stream>>>(startb, sums, N + 1);
    k_fill<<<(Ep + 255) / 256, 256, 0, stream>>>(ei, startb, cursor, csr, E, Ep);
    // 4) graph boundaries
    k_gbound<<<(N + 255) / 256, 256, 0, stream>>>(bat, gstart, N, G);
    // 5) layer-1 gather (wave per dst, unrolled) -> agg fp16 [N, 4*128]
    k_gat1<<<(N + 3) / 4, 256, 0, stream>>>(startb, csr, As1, Ad1, x_h, agg, N);
    // 6) block-diag projection + bias + ELU (fp16 MFMA): h1_h = elu(agg_h @ W1_h^T + b1_h)
    k_gemm_h<true><<<dim3((N + 127) / 128, 1, 4), 256, 0, stream>>>(
        agg, W1hi, W1lo, b1, h1, N, 128, 512, 128, 512, 128L, 16384L, 128L, 128L);
    // 7) xh2 = h1 @ W2^T  [N,128]  (fp16 MFMA)
    k_gemm_h<false><<<dim3((N + 127) / 128, 1, 1), 256, 0, stream>>>(
        h1, W2hi, W2lo, nullptr, xh2h, N, 512, 512, 512, 128, 0L, 0L, 0L, 0L);
    // 8) layer-2 attention logits
    k_attn2<<<(N + 3) / 4, 256, 0, stream>>>(xh2h, as2, ad2, As2, Ad2, N);
    // 9) layer-2 gather + bias + ELU -> h2 f32 (wave per dst, unrolled)
    k_gat2<<<(N + 3) / 4, 256, 0, stream>>>(startb, csr, As2, Ad2, xh2h, b2, h2, N);
    // 10) two-stage pooling + MLP head
    k_poolA<<<(N + PCH - 1) / PCH, 128, 0, stream>>>(h2, bat, pooled, N);
    k_head<<<G, 128, 0, stream>>>(pooled, gstart, Wh1, bh1, Wh2, bh2, out);
}

// Round 12
// 420.371 us; speedup vs baseline: 1.1252x; 1.0386x over previous
//
#include <hip/hip_runtime.h>
#include <cstdint>
#include <cstddef>

#define NEG_SLOPE 0.2f

typedef _Float16 f16x8 __attribute__((ext_vector_type(8)));
typedef _Float16 f16x2 __attribute__((ext_vector_type(2)));
typedef float    f32x4 __attribute__((ext_vector_type(4)));

__device__ __forceinline__ float leaky(float x){ return x > 0.f ? x : NEG_SLOPE * x; }
__device__ __forceinline__ float elu(float x){ return x > 0.f ? x : __expf(x) - 1.f; }

// ============ split f32 -> fp16 hi + fp16 lo ============
__global__ void k_wcvt(const float* __restrict__ src, _Float16* __restrict__ hi,
                       _Float16* __restrict__ lo, int n)
{
    int i = blockIdx.x * 256 + threadIdx.x;
    if (i >= n) return;
    float v = src[i];
    _Float16 h = (_Float16)v;
    hi[i] = h;
    lo[i] = (_Float16)(v - (float)h);
}

// ============ fp16-A x split-fp16-B MFMA GEMM (tile 128x128, BK=32, z = heads) ============
template<bool FUSE_BIAS_ELU>
__global__ __launch_bounds__(256, 2) void k_gemm_h(
    const _Float16* __restrict__ A, const _Float16* __restrict__ Bh,
    const _Float16* __restrict__ Bl, const float* __restrict__ bias,
    _Float16* __restrict__ C,
    int M, int K, int lda, int ldb, int ldc,
    long aZ, long bZ, long cZ, long biasZ)
{
    constexpr int LS = 40;   // halfs per LDS row (32 + 8 pad)
    __shared__ __align__(16) _Float16 As [128 * LS];
    __shared__ __align__(16) _Float16 Bhs[128 * LS];
    __shared__ __align__(16) _Float16 Bls[128 * LS];

    const _Float16* Ab  = A  + (size_t)blockIdx.z * aZ;
    const _Float16* Bhb = Bh + (size_t)blockIdx.z * bZ;
    const _Float16* Blb = Bl + (size_t)blockIdx.z * bZ;
    _Float16* Cb = C + (size_t)blockIdx.z * cZ;

    const int tid = threadIdx.x;
    const int wave = tid >> 6, lane = tid & 63;
    const int wm = wave >> 1, wn = wave & 1;
    const int quad = lane >> 4, l16 = lane & 15;
    const int m0 = blockIdx.x * 128;

    f32x4 acc[4][4] = {};

    for (int k0 = 0; k0 < K; k0 += 32) {
        #pragma unroll
        for (int q = 0; q < 2; ++q) {
            int idx = tid + q * 256;            // 0..511: row 0..127, kq 0..3
            int row = idx >> 2, kq = idx & 3;
            int rg = m0 + row;
            f16x8 va = {};
            if (rg < M) va = *(const f16x8*)(Ab + (size_t)rg * lda + k0 + kq * 8);
            *(f16x8*)&As[row * LS + kq * 8] = va;
            *(f16x8*)&Bhs[row * LS + kq * 8] = *(const f16x8*)(Bhb + (size_t)row * ldb + k0 + kq * 8);
            *(f16x8*)&Bls[row * LS + kq * 8] = *(const f16x8*)(Blb + (size_t)row * ldb + k0 + kq * 8);
        }
        __syncthreads();

        f16x8 af[4], bhf[4], blf[4];
        #pragma unroll
        for (int i = 0; i < 4; ++i) {
            int mr = wm * 64 + i * 16 + l16;
            af[i] = *(const f16x8*)&As[mr * LS + quad * 8];
            int nr = wn * 64 + i * 16 + l16;
            bhf[i] = *(const f16x8*)&Bhs[nr * LS + quad * 8];
            blf[i] = *(const f16x8*)&Bls[nr * LS + quad * 8];
        }
        #pragma unroll
        for (int i = 0; i < 4; ++i)
            #pragma unroll
            for (int j = 0; j < 4; ++j) {
                acc[i][j] = __builtin_amdgcn_mfma_f32_16x16x32_f16(af[i], bhf[j], acc[i][j], 0, 0, 0);
                acc[i][j] = __builtin_amdgcn_mfma_f32_16x16x32_f16(af[i], blf[j], acc[i][j], 0, 0, 0);
            }
        __syncthreads();
    }

    #pragma unroll
    for (int j = 0; j < 4; ++j) {
        int n = wn * 64 + j * 16 + l16;
        float bb = 0.f;
        if (FUSE_BIAS_ELU) bb = bias[blockIdx.z * biasZ + n];
        #pragma unroll
        for (int i = 0; i < 4; ++i)
            #pragma unroll
            for (int r = 0; r < 4; ++r) {
                int m = m0 + wm * 64 + i * 16 + quad * 4 + r;
                if (m < M) {
                    float v = acc[i][j][r];
                    if (FUSE_BIAS_ELU) v = elu(v + bb);
                    Cb[(size_t)m * ldc + n] = (_Float16)v;
                }
            }
    }
}

// ============ fold attention vectors: w_s[h,k] = sum_c att_src[h,c] * W1[h*128+c, k] ============
__global__ __launch_bounds__(128) void k_wvec(const float* __restrict__ W1,
                                              const float* __restrict__ as1,
                                              const float* __restrict__ ad1,
                                              float* __restrict__ w_s,
                                              float* __restrict__ w_d)
{
    int h = blockIdx.x, k = threadIdx.x;
    float s = 0.f, d = 0.f;
    for (int c = 0; c < 128; ++c) {
        float w = W1[((size_t)(h * 128 + c)) * 128 + k];
        s += as1[h * 128 + c] * w;
        d += ad1[h * 128 + c] * w;
    }
    w_s[h * 128 + k] = s;
    w_d[h * 128 + k] = d;
}

// ============ layer-1 attention logits from raw x; also emit x as fp16 ============
__global__ __launch_bounds__(256) void k_attn_x(const float* __restrict__ x,
                                                const float* __restrict__ w_s,
                                                const float* __restrict__ w_d,
                                                float* __restrict__ a_s,
                                                float* __restrict__ a_d,
                                                _Float16* __restrict__ xh, int N)
{
    int n = blockIdx.x * 4 + (threadIdx.x >> 6);
    if (n >= N) return;
    int lane = threadIdx.x & 63;
    float2 xv = *(const float2*)(x + (size_t)n * 128 + lane * 2);
    f16x2 hv = { (_Float16)xv.x, (_Float16)xv.y };
    *(f16x2*)(xh + (size_t)n * 128 + lane * 2) = hv;
    float ps[4], pd[4];
    #pragma unroll
    for (int h = 0; h < 4; ++h) {
        float2 sv = *(const float2*)(w_s + h * 128 + lane * 2);
        float2 dv = *(const float2*)(w_d + h * 128 + lane * 2);
        ps[h] = xv.x * sv.x + xv.y * sv.y;
        pd[h] = xv.x * dv.x + xv.y * dv.y;
    }
    #pragma unroll
    for (int h = 0; h < 4; ++h)
        for (int off = 32; off; off >>= 1) {
            ps[h] += __shfl_xor(ps[h], off);
            pd[h] += __shfl_xor(pd[h], off);
        }
    if (lane == 0) {
        *(float4*)(a_s + (size_t)n * 4) = make_float4(ps[0], ps[1], ps[2], ps[3]);
        *(float4*)(a_d + (size_t)n * 4) = make_float4(pd[0], pd[1], pd[2], pd[3]);
    }
}

// ============ layer-2 attention logits from fp16 xh2 ============
__global__ __launch_bounds__(256) void k_attn2(const _Float16* __restrict__ xh,
                                               const float* __restrict__ as2,
                                               const float* __restrict__ ad2,
                                               float* __restrict__ a_s,
                                               float* __restrict__ a_d, int N)
{
    int n = blockIdx.x * 4 + (threadIdx.x >> 6);
    if (n >= N) return;
    int lane = threadIdx.x & 63;
    f16x2 xv = *(const f16x2*)(xh + (size_t)n * 128 + lane * 2);
    float vx = (float)xv.x, vy = (float)xv.y;
    float2 sv = *(const float2*)(as2 + lane * 2);
    float2 dv = *(const float2*)(ad2 + lane * 2);
    float ps = vx * sv.x + vy * sv.y;
    float pd = vx * dv.x + vy * dv.y;
    for (int off = 32; off; off >>= 1) { ps += __shfl_xor(ps, off); pd += __shfl_xor(pd, off); }
    if (lane == 0) { a_s[n] = ps; a_d[n] = pd; }
}

// ============ CSR construction ============
__global__ void k_count(const int* __restrict__ ei, int* __restrict__ deg, int E, int Ep)
{
    int e = blockIdx.x * blockDim.x + threadIdx.x;
    if (e >= Ep) return;
    int dst = (e < E) ? ei[E + e] : (e - E);
    atomicAdd(&deg[dst], 1);
}

__global__ __launch_bounds__(1024) void k_scanA(const int* __restrict__ deg,
                                                int* __restrict__ start,
                                                int* __restrict__ sums, int Ntot, int N)
{
    __shared__ int sm[1024];
    int tid = threadIdx.x;
    int i = blockIdx.x * 1024 + tid;
    int v = (i < N) ? deg[i] : 0;
    sm[tid] = v; __syncthreads();
    for (int off = 1; off < 1024; off <<= 1) {
        int t = (tid >= off) ? sm[tid - off] : 0;
        __syncthreads();
        sm[tid] += t;
        __syncthreads();
    }
    if (i < Ntot) start[i] = sm[tid] - v;
    if (tid == 1023) sums[blockIdx.x] = sm[1023];
}

__global__ void k_scanB(int* sums, int nb)
{
    int l = threadIdx.x;
    int v = (l < nb) ? sums[l] : 0;
    int orig = v;
    for (int off = 1; off < 64; off <<= 1) { int t = __shfl_up(v, off); if (l >= off) v += t; }
    if (l < nb) sums[l] = v - orig;
}

__global__ __launch_bounds__(1024) void k_scanC(int* __restrict__ start,
                                                const int* __restrict__ sums, int Ntot)
{
    int i = blockIdx.x * 1024 + threadIdx.x;
    if (i < Ntot) start[i] += sums[blockIdx.x];
}

__global__ void k_fill(const int* __restrict__ ei, const int* __restrict__ start,
                       int* __restrict__ cursor, int* __restrict__ csr_src, int E, int Ep)
{
    int e = blockIdx.x * blockDim.x + threadIdx.x;
    if (e >= Ep) return;
    int src, dst;
    if (e < E) { src = ei[e]; dst = ei[E + e]; } else { src = dst = e - E; }
    int pos = atomicAdd(&cursor[dst], 1);
    csr_src[start[dst] + pos] = src;
}

// ============ layer-1 gather: one 16-LANE GROUP per dst (4 dsts/wave) ============
// Lane covers 8 channels (f16x8 gather). __shfl width=16 broadcasts per-group:
// one shuffle serves 4 edges; per-dst serial chain runs 4-way concurrent per wave.
__global__ __launch_bounds__(256) void k_gat1(const int* __restrict__ start,
                                              const int* __restrict__ csr,
                                              const float* __restrict__ a_s,
                                              const float* __restrict__ a_d,
                                              const _Float16* __restrict__ x,
                                              _Float16* __restrict__ agg, int N)
{
    int d = blockIdx.x * 16 + (threadIdx.x >> 4);
    if (d >= N) return;
    int g16 = threadIdx.x & 15;
    int beg = start[d], end = start[d + 1];
    int deg = end - beg;
    float4 ad4 = *(const float4*)(a_d + (size_t)d * 4);

    float sum0 = 0.f, sum1 = 0.f, sum2 = 0.f, sum3 = 0.f;
    float acc[4][8] = {};
    const _Float16* xb = x + g16 * 8;

    for (int base = 0; base < deg; base += 16) {
        int nch = deg - base; if (nch > 16) nch = 16;
        int s = 0;
        float e0 = 0.f, e1 = 0.f, e2 = 0.f, e3 = 0.f;
        if (g16 < nch) {
            s = csr[beg + base + g16];
            float4 as4 = *(const float4*)(a_s + (size_t)s * 4);
            e0 = __expf(leaky(as4.x + ad4.x));
            e1 = __expf(leaky(as4.y + ad4.y));
            e2 = __expf(leaky(as4.z + ad4.z));
            e3 = __expf(leaky(as4.w + ad4.w));
            sum0 += e0; sum1 += e1; sum2 += e2; sum3 += e3;
        }
        for (int t = 0; t < nch; ++t) {
            int   si = __shfl(s,  t, 16);
            float w0 = __shfl(e0, t, 16);
            float w1 = __shfl(e1, t, 16);
            float w2 = __shfl(e2, t, 16);
            float w3 = __shfl(e3, t, 16);
            f16x8 hv = *(const f16x8*)(xb + (size_t)si * 128);
            #pragma unroll
            for (int c = 0; c < 8; ++c) {
                float v = (float)hv[c];
                acc[0][c] += w0 * v;
                acc[1][c] += w1 * v;
                acc[2][c] += w2 * v;
                acc[3][c] += w3 * v;
            }
        }
    }
    #pragma unroll
    for (int o = 1; o < 16; o <<= 1) {
        sum0 += __shfl_xor(sum0, o, 16); sum1 += __shfl_xor(sum1, o, 16);
        sum2 += __shfl_xor(sum2, o, 16); sum3 += __shfl_xor(sum3, o, 16);
    }
    float inv[4] = { 1.f / (sum0 + 1e-16f), 1.f / (sum1 + 1e-16f),
                     1.f / (sum2 + 1e-16f), 1.f / (sum3 + 1e-16f) };
    _Float16* o = agg + (size_t)d * 512 + g16 * 8;
    #pragma unroll
    for (int h = 0; h < 4; ++h) {
        f16x8 ov;
        #pragma unroll
        for (int c = 0; c < 8; ++c) ov[c] = (_Float16)(acc[h][c] * inv[h]);
        *(f16x8*)(o + h * 128) = ov;
    }
}

// ============ layer-2 gather (1 head) + bias + ELU -> h2 f32, 16-lane group per dst ============
__global__ __launch_bounds__(256) void k_gat2(const int* __restrict__ start,
                                              const int* __restrict__ csr,
                                              const float* __restrict__ a_s,
                                              const float* __restrict__ a_d,
                                              const _Float16* __restrict__ xh2,
                                              const float* __restrict__ b2,
                                              float* __restrict__ h2, int N)
{
    int d = blockIdx.x * 16 + (threadIdx.x >> 4);
    if (d >= N) return;
    int g16 = threadIdx.x & 15;
    int beg = start[d], end = start[d + 1];
    int deg = end - beg;
    float ad = a_d[d];

    float sum = 0.f;
    float acc[8] = {};
    const _Float16* xb = xh2 + g16 * 8;

    for (int base = 0; base < deg; base += 16) {
        int nch = deg - base; if (nch > 16) nch = 16;
        int s = 0; float e = 0.f;
        if (g16 < nch) {
            s = csr[beg + base + g16];
            e = __expf(leaky(a_s[s] + ad));
            sum += e;
        }
        for (int t = 0; t < nch; ++t) {
            int   si = __shfl(s, t, 16);
            float w  = __shfl(e, t, 16);
            f16x8 hv = *(const f16x8*)(xb + (size_t)si * 128);
            #pragma unroll
            for (int c = 0; c < 8; ++c) acc[c] += w * (float)hv[c];
        }
    }
    #pragma unroll
    for (int o = 1; o < 16; o <<= 1) sum += __shfl_xor(sum, o, 16);
    float inv = 1.f / (sum + 1e-16f);
    float ov[8];
    #pragma unroll
    for (int c = 0; c < 8; ++c) ov[c] = elu(acc[c] * inv + b2[g16 * 8 + c]);
    float* op = h2 + (size_t)d * 128 + g16 * 8;
    *(float4*)(op)     = *(float4*)&ov[0];
    *(float4*)(op + 4) = *(float4*)&ov[4];
}

// ============ graph boundaries from SORTED batch ============
__global__ void k_gbound(const int* __restrict__ batch, int* __restrict__ gstart, int N, int G)
{
    int n = blockIdx.x * blockDim.x + threadIdx.x;
    if (n >= N) return;
    int b = batch[n];
    int prev = (n == 0) ? -1 : batch[n - 1];
    for (int g = prev + 1; g <= b; ++g) gstart[g] = n;
    if (n == N - 1)
        for (int g = b + 1; g <= G; ++g) gstart[g] = N;
}

// ============ pooling stage A: chunked partial sums ============
#define PCH 64
__global__ __launch_bounds__(128) void k_poolA(const float* __restrict__ h2,
                                               const int* __restrict__ batch,
                                               float* __restrict__ pooled, int N)
{
    int c = threadIdx.x;
    int n0 = blockIdx.x * PCH;
    int n1 = n0 + PCH < N ? n0 + PCH : N;
    if (n0 >= N) return;
    int g = batch[n0];
    float acc = 0.f;
    for (int n = n0; n < n1; ++n) {
        int bg = batch[n];
        if (bg != g) { atomicAdd(&pooled[(size_t)g * 128 + c], acc); acc = 0.f; g = bg; }
        acc += h2[(size_t)n * 128 + c];
    }
    atomicAdd(&pooled[(size_t)g * 128 + c], acc);
}

// ============ head: mean + relu(pooled@Wh1^T+bh1) @ Wh2^T + bh2 ============
__global__ __launch_bounds__(128) void k_head(const float* __restrict__ pooled,
                                              const int* __restrict__ gstart,
                                              const float* __restrict__ Wh1,
                                              const float* __restrict__ bh1,
                                              const float* __restrict__ Wh2,
                                              const float* __restrict__ bh2,
                                              float* __restrict__ out)
{
    int g = blockIdx.x, c = threadIdx.x;
    __shared__ float p[128];
    __shared__ float red[128];
    float cf = (float)(gstart[g + 1] - gstart[g]); cf = cf > 1.f ? cf : 1.f;
    p[c] = pooled[(size_t)g * 128 + c] / cf;
    __syncthreads();
    float z = bh1[c];
    for (int k = 0; k < 128; ++k) z += p[k] * Wh1[c * 128 + k];
    z = z > 0.f ? z : 0.f;
    red[c] = z * Wh2[c];
    __syncthreads();
    for (int st = 64; st > 0; st >>= 1) { if (c < st) red[c] += red[c + st]; __syncthreads(); }
    if (c == 0) out[g] = red[0] + bh2[0];
}

// ============ launch ============
extern "C" void kernel_launch(void* const* d_in, const int* in_sizes, int n_in,
                              void* d_out, int out_size, void* d_ws, size_t ws_size,
                              hipStream_t stream)
{
    const float* x   = (const float*)d_in[0];
    const int*   ei  = (const int*)d_in[1];
    const int*   bat = (const int*)d_in[2];
    const float* W1  = (const float*)d_in[3];
    const float* as1 = (const float*)d_in[4];
    const float* ad1 = (const float*)d_in[5];
    const float* b1  = (const float*)d_in[6];
    const float* W2  = (const float*)d_in[7];
    const float* as2 = (const float*)d_in[8];
    const float* ad2 = (const float*)d_in[9];
    const float* b2  = (const float*)d_in[10];
    const float* Wh1 = (const float*)d_in[11];
    const float* bh1 = (const float*)d_in[12];
    const float* Wh2 = (const float*)d_in[13];
    const float* bh2 = (const float*)d_in[14];
    float* out = (float*)d_out;

    const int N  = in_sizes[0] / 128;
    const int E  = in_sizes[1] / 2;
    const int Ep = E + N;
    const int G  = 128;

    char* w = (char*)d_ws;
    size_t off = 0;
    auto alloc = [&](size_t bytes) -> char* {
        char* p = w + off; off += (bytes + 511) & ~(size_t)511; return p;
    };
    _Float16* x_h  = (_Float16*)alloc((size_t)N * 128 * 2);
    _Float16* agg  = (_Float16*)alloc((size_t)N * 512 * 2);
    _Float16* h1   = (_Float16*)alloc((size_t)N * 512 * 2);
    _Float16* xh2h = (_Float16*)alloc((size_t)N * 128 * 2);
    float*    h2   = (float*)alloc((size_t)N * 128 * 4);
    float*    As1  = (float*)alloc((size_t)N * 4 * 4);
    float*    Ad1  = (float*)alloc((size_t)N * 4 * 4);
    float*    As2  = (float*)alloc((size_t)N * 4);
    float*    Ad2  = (float*)alloc((size_t)N * 4);
    float*    w_s1 = (float*)alloc(512 * 4);
    float*    w_d1 = (float*)alloc(512 * 4);
    _Float16* W1hi = (_Float16*)alloc(65536 * 2);
    _Float16* W1lo = (_Float16*)alloc(65536 * 2);
    _Float16* W2hi = (_Float16*)alloc(65536 * 2);
    _Float16* W2lo = (_Float16*)alloc(65536 * 2);
    int* startb = (int*)alloc((size_t)(N + 1) * 4);
    int* csr    = (int*)alloc((size_t)Ep * 4);
    int* sums   = (int*)alloc(4096);
    int* gstart = (int*)alloc((size_t)(G + 1) * 4);
    char* zbase = w + off;                                // zero-init group
    int*   deg    = (int*)alloc((size_t)N * 4);
    int*   cursor = (int*)alloc((size_t)N * 4);
    float* pooled = (float*)alloc((size_t)G * 128 * 4);
    size_t zbytes = (size_t)((w + off) - zbase);

    hipMemsetAsync(zbase, 0, zbytes, stream);

    // 1) fold attention vectors; logits + fp16 x
    k_wvec<<<4, 128, 0, stream>>>(W1, as1, ad1, w_s1, w_d1);
    k_attn_x<<<(N + 3) / 4, 256, 0, stream>>>(x, w_s1, w_d1, As1, Ad1, x_h, N);
    // 2) weights -> split fp16
    k_wcvt<<<256, 256, 0, stream>>>(W1, W1hi, W1lo, 65536);
    k_wcvt<<<256, 256, 0, stream>>>(W2, W2hi, W2lo, 65536);
    // 3) CSR by destination (self-loops appended)
    k_count<<<(Ep + 255) / 256, 256, 0, stream>>>(ei, deg, E, Ep);
    int nb = (N + 1 + 1023) / 1024;
    k_scanA<<<nb, 1024, 0, stream>>>(deg, startb, sums, N + 1, N);
    k_scanB<<<1, 64, 0, stream>>>(sums, nb);
    k_scanC<<<nb, 1024, 0, stream>>>(startb, sums, N + 1);
    k_fill<<<(Ep + 255) / 256, 256, 0, stream>>>(ei, startb, cursor, csr, E, Ep);
    // 4) graph boundaries
    k_gbound<<<(N + 255) / 256, 256, 0, stream>>>(bat, gstart, N, G);
    // 5) layer-1 gather (16-lane group per dst) -> agg fp16 [N, 4*128]
    k_gat1<<<(N + 15) / 16, 256, 0, stream>>>(startb, csr, As1, Ad1, x_h, agg, N);
    // 6) block-diag projection + bias + ELU (fp16 MFMA): h1_h = elu(agg_h @ W1_h^T + b1_h)
    k_gemm_h<true><<<dim3((N + 127) / 128, 1, 4), 256, 0, stream>>>(
        agg, W1hi, W1lo, b1, h1, N, 128, 512, 128, 512, 128L, 16384L, 128L, 128L);
    // 7) xh2 = h1 @ W2^T  [N,128]  (fp16 MFMA)
    k_gemm_h<false><<<dim3((N + 127) / 128, 1, 1), 256, 0, stream>>>(
        h1, W2hi, W2lo, nullptr, xh2h, N, 512, 512, 512, 128, 0L, 0L, 0L, 0L);
    // 8) layer-2 attention logits
    k_attn2<<<(N + 3) / 4, 256, 0, stream>>>(xh2h, as2, ad2, As2, Ad2, N);
    // 9) layer-2 gather + bias + ELU -> h2 f32 (16-lane group per dst)
    k_gat2<<<(N + 15) / 16, 256, 0, stream>>>(startb, csr, As2, Ad2, xh2h, b2, h2, N);
    // 10) two-stage pooling + MLP head
    k_poolA<<<(N + PCH - 1) / PCH, 128, 0, stream>>>(h2, bat, pooled, N);
    k_head<<<G, 128, 0, stream>>>(pooled, gstart, Wh1, bh1, Wh2, bh2, out);
}

// Round 13
// 394.496 us; speedup vs baseline: 1.1990x; 1.0656x over previous
//
#include <hip/hip_runtime.h>
#include <cstdint>
#include <cstddef>

#define NEG_SLOPE 0.2f

typedef _Float16 f16x8 __attribute__((ext_vector_type(8)));
typedef _Float16 f16x2 __attribute__((ext_vector_type(2)));
typedef float    f32x4 __attribute__((ext_vector_type(4)));

__device__ __forceinline__ float leaky(float x){ return x > 0.f ? x : NEG_SLOPE * x; }
__device__ __forceinline__ float elu(float x){ return x > 0.f ? x : __expf(x) - 1.f; }

// ============ split f32 -> fp16 hi + fp16 lo ============
__global__ void k_wcvt(const float* __restrict__ src, _Float16* __restrict__ hi,
                       _Float16* __restrict__ lo, int n)
{
    int i = blockIdx.x * 256 + threadIdx.x;
    if (i >= n) return;
    float v = src[i];
    _Float16 h = (_Float16)v;
    hi[i] = h;
    lo[i] = (_Float16)(v - (float)h);
}

// ============ fp16-A x split-fp16-B MFMA GEMM (tile 128x128, BK=32, z = heads) ============
// Epilogue stages C through LDS (reusing the A/B tile space) -> f16x8 coalesced stores.
#define LSG 40    // halfs per staging row (32 + 8 pad, 80B: 16B-aligned, 2-way=free)
#define CP  136   // halfs per C-tile row (128 + 8 pad)
template<bool FUSE_BIAS_ELU>
__global__ __launch_bounds__(256, 2) void k_gemm_h(
    const _Float16* __restrict__ A, const _Float16* __restrict__ Bh,
    const _Float16* __restrict__ Bl, const float* __restrict__ bias,
    _Float16* __restrict__ C,
    int M, int K, int lda, int ldb, int ldc,
    long aZ, long bZ, long cZ, long biasZ)
{
    // union: staging (3 * 128*LSG = 15360 halfs) vs C-tile (128*CP = 17408 halfs)
    __shared__ __align__(16) _Float16 smem[128 * CP];
    _Float16* As  = smem;
    _Float16* Bhs = smem + 128 * LSG;
    _Float16* Bls = smem + 256 * LSG;

    const _Float16* Ab  = A  + (size_t)blockIdx.z * aZ;
    const _Float16* Bhb = Bh + (size_t)blockIdx.z * bZ;
    const _Float16* Blb = Bl + (size_t)blockIdx.z * bZ;
    _Float16* Cb = C + (size_t)blockIdx.z * cZ;

    const int tid = threadIdx.x;
    const int wave = tid >> 6, lane = tid & 63;
    const int wm = wave >> 1, wn = wave & 1;
    const int quad = lane >> 4, l16 = lane & 15;
    const int m0 = blockIdx.x * 128;

    f32x4 acc[4][4] = {};

    for (int k0 = 0; k0 < K; k0 += 32) {
        #pragma unroll
        for (int q = 0; q < 2; ++q) {
            int idx = tid + q * 256;            // 0..511: row 0..127, kq 0..3
            int row = idx >> 2, kq = idx & 3;
            int rg = m0 + row;
            f16x8 va = {};
            if (rg < M) va = *(const f16x8*)(Ab + (size_t)rg * lda + k0 + kq * 8);
            *(f16x8*)&As[row * LSG + kq * 8] = va;
            *(f16x8*)&Bhs[row * LSG + kq * 8] = *(const f16x8*)(Bhb + (size_t)row * ldb + k0 + kq * 8);
            *(f16x8*)&Bls[row * LSG + kq * 8] = *(const f16x8*)(Blb + (size_t)row * ldb + k0 + kq * 8);
        }
        __syncthreads();

        f16x8 af[4], bhf[4], blf[4];
        #pragma unroll
        for (int i = 0; i < 4; ++i) {
            int mr = wm * 64 + i * 16 + l16;
            af[i] = *(const f16x8*)&As[mr * LSG + quad * 8];
            int nr = wn * 64 + i * 16 + l16;
            bhf[i] = *(const f16x8*)&Bhs[nr * LSG + quad * 8];
            blf[i] = *(const f16x8*)&Bls[nr * LSG + quad * 8];
        }
        #pragma unroll
        for (int i = 0; i < 4; ++i)
            #pragma unroll
            for (int j = 0; j < 4; ++j) {
                acc[i][j] = __builtin_amdgcn_mfma_f32_16x16x32_f16(af[i], bhf[j], acc[i][j], 0, 0, 0);
                acc[i][j] = __builtin_amdgcn_mfma_f32_16x16x32_f16(af[i], blf[j], acc[i][j], 0, 0, 0);
            }
        __syncthreads();
    }

    // ---- epilogue: fragments -> LDS C-tile (A/B staging space is dead now) ----
    #pragma unroll
    for (int j = 0; j < 4; ++j) {
        int n = wn * 64 + j * 16 + l16;
        float bb = 0.f;
        if (FUSE_BIAS_ELU) bb = bias[blockIdx.z * biasZ + n];
        #pragma unroll
        for (int i = 0; i < 4; ++i)
            #pragma unroll
            for (int r = 0; r < 4; ++r) {
                float v = acc[i][j][r];
                if (FUSE_BIAS_ELU) v = elu(v + bb);
                smem[(wm * 64 + i * 16 + quad * 4 + r) * CP + n] = (_Float16)v;
            }
    }
    __syncthreads();
    // ---- coalesced f16x8 store: 2048 chunks, 8 per thread ----
    for (int c = tid; c < 2048; c += 256) {
        int row = c >> 4, col8 = (c & 15) * 8;
        int m = m0 + row;
        if (m < M)
            *(f16x8*)(Cb + (size_t)m * ldc + col8) = *(const f16x8*)&smem[row * CP + col8];
    }
}

// ============ fold attention vectors: w_s[h,k] = sum_c att_src[h,c] * W1[h*128+c, k] ============
__global__ __launch_bounds__(128) void k_wvec(const float* __restrict__ W1,
                                              const float* __restrict__ as1,
                                              const float* __restrict__ ad1,
                                              float* __restrict__ w_s,
                                              float* __restrict__ w_d)
{
    int h = blockIdx.x, k = threadIdx.x;
    float s = 0.f, d = 0.f;
    for (int c = 0; c < 128; ++c) {
        float w = W1[((size_t)(h * 128 + c)) * 128 + k];
        s += as1[h * 128 + c] * w;
        d += ad1[h * 128 + c] * w;
    }
    w_s[h * 128 + k] = s;
    w_d[h * 128 + k] = d;
}

// ============ layer-1 attention logits from raw x; also emit x as fp16 ============
__global__ __launch_bounds__(256) void k_attn_x(const float* __restrict__ x,
                                                const float* __restrict__ w_s,
                                                const float* __restrict__ w_d,
                                                float* __restrict__ a_s,
                                                float* __restrict__ a_d,
                                                _Float16* __restrict__ xh, int N)
{
    int n = blockIdx.x * 4 + (threadIdx.x >> 6);
    if (n >= N) return;
    int lane = threadIdx.x & 63;
    float2 xv = *(const float2*)(x + (size_t)n * 128 + lane * 2);
    f16x2 hv = { (_Float16)xv.x, (_Float16)xv.y };
    *(f16x2*)(xh + (size_t)n * 128 + lane * 2) = hv;
    float ps[4], pd[4];
    #pragma unroll
    for (int h = 0; h < 4; ++h) {
        float2 sv = *(const float2*)(w_s + h * 128 + lane * 2);
        float2 dv = *(const float2*)(w_d + h * 128 + lane * 2);
        ps[h] = xv.x * sv.x + xv.y * sv.y;
        pd[h] = xv.x * dv.x + xv.y * dv.y;
    }
    #pragma unroll
    for (int h = 0; h < 4; ++h)
        for (int off = 32; off; off >>= 1) {
            ps[h] += __shfl_xor(ps[h], off);
            pd[h] += __shfl_xor(pd[h], off);
        }
    if (lane == 0) {
        *(float4*)(a_s + (size_t)n * 4) = make_float4(ps[0], ps[1], ps[2], ps[3]);
        *(float4*)(a_d + (size_t)n * 4) = make_float4(pd[0], pd[1], pd[2], pd[3]);
    }
}

// ============ layer-2 attention logits from fp16 xh2 ============
__global__ __launch_bounds__(256) void k_attn2(const _Float16* __restrict__ xh,
                                               const float* __restrict__ as2,
                                               const float* __restrict__ ad2,
                                               float* __restrict__ a_s,
                                               float* __restrict__ a_d, int N)
{
    int n = blockIdx.x * 4 + (threadIdx.x >> 6);
    if (n >= N) return;
    int lane = threadIdx.x & 63;
    f16x2 xv = *(const f16x2*)(xh + (size_t)n * 128 + lane * 2);
    float vx = (float)xv.x, vy = (float)xv.y;
    float2 sv = *(const float2*)(as2 + lane * 2);
    float2 dv = *(const float2*)(ad2 + lane * 2);
    float ps = vx * sv.x + vy * sv.y;
    float pd = vx * dv.x + vy * dv.y;
    for (int off = 32; off; off >>= 1) { ps += __shfl_xor(ps, off); pd += __shfl_xor(pd, off); }
    if (lane == 0) { a_s[n] = ps; a_d[n] = pd; }
}

// ============ CSR construction ============
__global__ void k_count(const int* __restrict__ ei, int* __restrict__ deg, int E, int Ep)
{
    int e = blockIdx.x * blockDim.x + threadIdx.x;
    if (e >= Ep) return;
    int dst = (e < E) ? ei[E + e] : (e - E);
    atomicAdd(&deg[dst], 1);
}

__global__ __launch_bounds__(1024) void k_scanA(const int* __restrict__ deg,
                                                int* __restrict__ start,
                                                int* __restrict__ sums, int Ntot, int N)
{
    __shared__ int sm[1024];
    int tid = threadIdx.x;
    int i = blockIdx.x * 1024 + tid;
    int v = (i < N) ? deg[i] : 0;
    sm[tid] = v; __syncthreads();
    for (int off = 1; off < 1024; off <<= 1) {
        int t = (tid >= off) ? sm[tid - off] : 0;
        __syncthreads();
        sm[tid] += t;
        __syncthreads();
    }
    if (i < Ntot) start[i] = sm[tid] - v;
    if (tid == 1023) sums[blockIdx.x] = sm[1023];
}

__global__ void k_scanB(int* sums, int nb)
{
    int l = threadIdx.x;
    int v = (l < nb) ? sums[l] : 0;
    int orig = v;
    for (int off = 1; off < 64; off <<= 1) { int t = __shfl_up(v, off); if (l >= off) v += t; }
    if (l < nb) sums[l] = v - orig;
}

__global__ __launch_bounds__(1024) void k_scanC(int* __restrict__ start,
                                                const int* __restrict__ sums, int Ntot)
{
    int i = blockIdx.x * 1024 + threadIdx.x;
    if (i < Ntot) start[i] += sums[blockIdx.x];
}

__global__ void k_fill(const int* __restrict__ ei, const int* __restrict__ start,
                       int* __restrict__ cursor, int* __restrict__ csr_src, int E, int Ep)
{
    int e = blockIdx.x * blockDim.x + threadIdx.x;
    if (e >= Ep) return;
    int src, dst;
    if (e < E) { src = ei[e]; dst = ei[E + e]; } else { src = dst = e - E; }
    int pos = atomicAdd(&cursor[dst], 1);
    csr_src[start[dst] + pos] = src;
}

// ============ layer-1 gather: one 16-LANE GROUP per dst (4 dsts/wave) ============
__global__ __launch_bounds__(256) void k_gat1(const int* __restrict__ start,
                                              const int* __restrict__ csr,
                                              const float* __restrict__ a_s,
                                              const float* __restrict__ a_d,
                                              const _Float16* __restrict__ x,
                                              _Float16* __restrict__ agg, int N)
{
    int d = blockIdx.x * 16 + (threadIdx.x >> 4);
    if (d >= N) return;
    int g16 = threadIdx.x & 15;
    int beg = start[d], end = start[d + 1];
    int deg = end - beg;
    float4 ad4 = *(const float4*)(a_d + (size_t)d * 4);

    float sum0 = 0.f, sum1 = 0.f, sum2 = 0.f, sum3 = 0.f;
    float acc[4][8] = {};
    const _Float16* xb = x + g16 * 8;

    for (int base = 0; base < deg; base += 16) {
        int nch = deg - base; if (nch > 16) nch = 16;
        int s = 0;
        float e0 = 0.f, e1 = 0.f, e2 = 0.f, e3 = 0.f;
        if (g16 < nch) {
            s = csr[beg + base + g16];
            float4 as4 = *(const float4*)(a_s + (size_t)s * 4);
            e0 = __expf(leaky(as4.x + ad4.x));
            e1 = __expf(leaky(as4.y + ad4.y));
            e2 = __expf(leaky(as4.z + ad4.z));
            e3 = __expf(leaky(as4.w + ad4.w));
            sum0 += e0; sum1 += e1; sum2 += e2; sum3 += e3;
        }
        for (int t = 0; t < nch; ++t) {
            int   si = __shfl(s,  t, 16);
            float w0 = __shfl(e0, t, 16);
            float w1 = __shfl(e1, t, 16);
            float w2 = __shfl(e2, t, 16);
            float w3 = __shfl(e3, t, 16);
            f16x8 hv = *(const f16x8*)(xb + (size_t)si * 128);
            #pragma unroll
            for (int c = 0; c < 8; ++c) {
                float v = (float)hv[c];
                acc[0][c] += w0 * v;
                acc[1][c] += w1 * v;
                acc[2][c] += w2 * v;
                acc[3][c] += w3 * v;
            }
        }
    }
    #pragma unroll
    for (int o = 1; o < 16; o <<= 1) {
        sum0 += __shfl_xor(sum0, o, 16); sum1 += __shfl_xor(sum1, o, 16);
        sum2 += __shfl_xor(sum2, o, 16); sum3 += __shfl_xor(sum3, o, 16);
    }
    float inv[4] = { 1.f / (sum0 + 1e-16f), 1.f / (sum1 + 1e-16f),
                     1.f / (sum2 + 1e-16f), 1.f / (sum3 + 1e-16f) };
    _Float16* o = agg + (size_t)d * 512 + g16 * 8;
    #pragma unroll
    for (int h = 0; h < 4; ++h) {
        f16x8 ov;
        #pragma unroll
        for (int c = 0; c < 8; ++c) ov[c] = (_Float16)(acc[h][c] * inv[h]);
        *(f16x8*)(o + h * 128) = ov;
    }
}

// ============ layer-2 gather (1 head) + bias + ELU -> h2 f32, 16-lane group per dst ============
__global__ __launch_bounds__(256) void k_gat2(const int* __restrict__ start,
                                              const int* __restrict__ csr,
                                              const float* __restrict__ a_s,
                                              const float* __restrict__ a_d,
                                              const _Float16* __restrict__ xh2,
                                              const float* __restrict__ b2,
                                              float* __restrict__ h2, int N)
{
    int d = blockIdx.x * 16 + (threadIdx.x >> 4);
    if (d >= N) return;
    int g16 = threadIdx.x & 15;
    int beg = start[d], end = start[d + 1];
    int deg = end - beg;
    float ad = a_d[d];

    float sum = 0.f;
    float acc[8] = {};
    const _Float16* xb = xh2 + g16 * 8;

    for (int base = 0; base < deg; base += 16) {
        int nch = deg - base; if (nch > 16) nch = 16;
        int s = 0; float e = 0.f;
        if (g16 < nch) {
            s = csr[beg + base + g16];
            e = __expf(leaky(a_s[s] + ad));
            sum += e;
        }
        for (int t = 0; t < nch; ++t) {
            int   si = __shfl(s, t, 16);
            float w  = __shfl(e, t, 16);
            f16x8 hv = *(const f16x8*)(xb + (size_t)si * 128);
            #pragma unroll
            for (int c = 0; c < 8; ++c) acc[c] += w * (float)hv[c];
        }
    }
    #pragma unroll
    for (int o = 1; o < 16; o <<= 1) sum += __shfl_xor(sum, o, 16);
    float inv = 1.f / (sum + 1e-16f);
    float ov[8];
    #pragma unroll
    for (int c = 0; c < 8; ++c) ov[c] = elu(acc[c] * inv + b2[g16 * 8 + c]);
    float* op = h2 + (size_t)d * 128 + g16 * 8;
    *(float4*)(op)     = *(float4*)&ov[0];
    *(float4*)(op + 4) = *(float4*)&ov[4];
}

// ============ graph boundaries from SORTED batch ============
__global__ void k_gbound(const int* __restrict__ batch, int* __restrict__ gstart, int N, int G)
{
    int n = blockIdx.x * blockDim.x + threadIdx.x;
    if (n >= N) return;
    int b = batch[n];
    int prev = (n == 0) ? -1 : batch[n - 1];
    for (int g = prev + 1; g <= b; ++g) gstart[g] = n;
    if (n == N - 1)
        for (int g = b + 1; g <= G; ++g) gstart[g] = N;
}

// ============ pooling stage A: chunked partial sums ============
#define PCH 64
__global__ __launch_bounds__(128) void k_poolA(const float* __restrict__ h2,
                                               const int* __restrict__ batch,
                                               float* __restrict__ pooled, int N)
{
    int c = threadIdx.x;
    int n0 = blockIdx.x * PCH;
    int n1 = n0 + PCH < N ? n0 + PCH : N;
    if (n0 >= N) return;
    int g = batch[n0];
    float acc = 0.f;
    for (int n = n0; n < n1; ++n) {
        int bg = batch[n];
        if (bg != g) { atomicAdd(&pooled[(size_t)g * 128 + c], acc); acc = 0.f; g = bg; }
        acc += h2[(size_t)n * 128 + c];
    }
    atomicAdd(&pooled[(size_t)g * 128 + c], acc);
}

// ============ head: mean + relu(pooled@Wh1^T+bh1) @ Wh2^T + bh2 ============
__global__ __launch_bounds__(128) void k_head(const float* __restrict__ pooled,
                                              const int* __restrict__ gstart,
                                              const float* __restrict__ Wh1,
                                              const float* __restrict__ bh1,
                                              const float* __restrict__ Wh2,
                                              const float* __restrict__ bh2,
                                              float* __restrict__ out)
{
    int g = blockIdx.x, c = threadIdx.x;
    __shared__ float p[128];
    __shared__ float red[128];
    float cf = (float)(gstart[g + 1] - gstart[g]); cf = cf > 1.f ? cf : 1.f;
    p[c] = pooled[(size_t)g * 128 + c] / cf;
    __syncthreads();
    float z = bh1[c];
    for (int k = 0; k < 128; ++k) z += p[k] * Wh1[c * 128 + k];
    z = z > 0.f ? z : 0.f;
    red[c] = z * Wh2[c];
    __syncthreads();
    for (int st = 64; st > 0; st >>= 1) { if (c < st) red[c] += red[c + st]; __syncthreads(); }
    if (c == 0) out[g] = red[0] + bh2[0];
}

// ============ launch ============
extern "C" void kernel_launch(void* const* d_in, const int* in_sizes, int n_in,
                              void* d_out, int out_size, void* d_ws, size_t ws_size,
                              hipStream_t stream)
{
    const float* x   = (const float*)d_in[0];
    const int*   ei  = (const int*)d_in[1];
    const int*   bat = (const int*)d_in[2];
    const float* W1  = (const float*)d_in[3];
    const float* as1 = (const float*)d_in[4];
    const float* ad1 = (const float*)d_in[5];
    const float* b1  = (const float*)d_in[6];
    const float* W2  = (const float*)d_in[7];
    const float* as2 = (const float*)d_in[8];
    const float* ad2 = (const float*)d_in[9];
    const float* b2  = (const float*)d_in[10];
    const float* Wh1 = (const float*)d_in[11];
    const float* bh1 = (const float*)d_in[12];
    const float* Wh2 = (const float*)d_in[13];
    const float* bh2 = (const float*)d_in[14];
    float* out = (float*)d_out;

    const int N  = in_sizes[0] / 128;
    const int E  = in_sizes[1] / 2;
    const int Ep = E + N;
    const int G  = 128;

    char* w = (char*)d_ws;
    size_t off = 0;
    auto alloc = [&](size_t bytes) -> char* {
        char* p = w + off; off += (bytes + 511) & ~(size_t)511; return p;
    };
    _Float16* x_h  = (_Float16*)alloc((size_t)N * 128 * 2);
    _Float16* agg  = (_Float16*)alloc((size_t)N * 512 * 2);
    _Float16* h1   = (_Float16*)alloc((size_t)N * 512 * 2);
    _Float16* xh2h = (_Float16*)alloc((size_t)N * 128 * 2);
    float*    h2   = (float*)alloc((size_t)N * 128 * 4);
    float*    As1  = (float*)alloc((size_t)N * 4 * 4);
    float*    Ad1  = (float*)alloc((size_t)N * 4 * 4);
    float*    As2  = (float*)alloc((size_t)N * 4);
    float*    Ad2  = (float*)alloc((size_t)N * 4);
    float*    w_s1 = (float*)alloc(512 * 4);
    float*    w_d1 = (float*)alloc(512 * 4);
    _Float16* W1hi = (_Float16*)alloc(65536 * 2);
    _Float16* W1lo = (_Float16*)alloc(65536 * 2);
    _Float16* W2hi = (_Float16*)alloc(65536 * 2);
    _Float16* W2lo = (_Float16*)alloc(65536 * 2);
    int* startb = (int*)alloc((size_t)(N + 1) * 4);
    int* csr    = (int*)alloc((size_t)Ep * 4);
    int* sums   = (int*)alloc(4096);
    int* gstart = (int*)alloc((size_t)(G + 1) * 4);
    char* zbase = w + off;                                // zero-init group
    int*   deg    = (int*)alloc((size_t)N * 4);
    int*   cursor = (int*)alloc((size_t)N * 4);
    float* pooled = (float*)alloc((size_t)G * 128 * 4);
    size_t zbytes = (size_t)((w + off) - zbase);

    hipMemsetAsync(zbase, 0, zbytes, stream);

    // 1) fold attention vectors; logits + fp16 x
    k_wvec<<<4, 128, 0, stream>>>(W1, as1, ad1, w_s1, w_d1);
    k_attn_x<<<(N + 3) / 4, 256, 0, stream>>>(x, w_s1, w_d1, As1, Ad1, x_h, N);
    // 2) weights -> split fp16
    k_wcvt<<<256, 256, 0, stream>>>(W1, W1hi, W1lo, 65536);
    k_wcvt<<<256, 256, 0, stream>>>(W2, W2hi, W2lo, 65536);
    // 3) CSR by destination (self-loops appended)
    k_count<<<(Ep + 255) / 256, 256, 0, stream>>>(ei, deg, E, Ep);
    int nb = (N + 1 + 1023) / 1024;
    k_scanA<<<nb, 1024, 0, stream>>>(deg, startb, sums, N + 1, N);
    k_scanB<<<1, 64, 0, stream>>>(sums, nb);
    k_scanC<<<nb, 1024, 0, stream>>>(startb, sums, N + 1);
    k_fill<<<(Ep + 255) / 256, 256, 0, stream>>>(ei, startb, cursor, csr, E, Ep);
    // 4) graph boundaries
    k_gbound<<<(N + 255) / 256, 256, 0, stream>>>(bat, gstart, N, G);
    // 5) layer-1 gather (16-lane group per dst) -> agg fp16 [N, 4*128]
    k_gat1<<<(N + 15) / 16, 256, 0, stream>>>(startb, csr, As1, Ad1, x_h, agg, N);
    // 6) block-diag projection + bias + ELU (fp16 MFMA): h1_h = elu(agg_h @ W1_h^T + b1_h)
    k_gemm_h<true><<<dim3((N + 127) / 128, 1, 4), 256, 0, stream>>>(
        agg, W1hi, W1lo, b1, h1, N, 128, 512, 128, 512, 128L, 16384L, 128L, 128L);
    // 7) xh2 = h1 @ W2^T  [N,128]  (fp16 MFMA)
    k_gemm_h<false><<<dim3((N + 127) / 128, 1, 1), 256, 0, stream>>>(
        h1, W2hi, W2lo, nullptr, xh2h, N, 512, 512, 512, 128, 0L, 0L, 0L, 0L);
    // 8) layer-2 attention logits
    k_attn2<<<(N + 3) / 4, 256, 0, stream>>>(xh2h, as2, ad2, As2, Ad2, N);
    // 9) layer-2 gather + bias + ELU -> h2 f32 (16-lane group per dst)
    k_gat2<<<(N + 15) / 16, 256, 0, stream>>>(startb, csr, As2, Ad2, xh2h, b2, h2, N);
    // 10) two-stage pooling + MLP head
    k_poolA<<<(N + PCH - 1) / PCH, 128, 0, stream>>>(h2, bat, pooled, N);
    k_head<<<G, 128, 0, stream>>>(pooled, gstart, Wh1, bh1, Wh2, bh2, out);
}

// Round 14
// 362.153 us; speedup vs baseline: 1.3060x; 1.0893x over previous
//
#include <hip/hip_runtime.h>
#include <cstdint>
#include <cstddef>

#define NEG_SLOPE 0.2f

typedef _Float16 f16x8 __attribute__((ext_vector_type(8)));
typedef _Float16 f16x2 __attribute__((ext_vector_type(2)));
typedef float    f32x4 __attribute__((ext_vector_type(4)));

__device__ __forceinline__ float leaky(float x){ return x > 0.f ? x : NEG_SLOPE * x; }
__device__ __forceinline__ float elu(float x){ return x > 0.f ? x : __expf(x) - 1.f; }

// ============ split f32 -> fp16 hi + fp16 lo ============
__global__ void k_wcvt(const float* __restrict__ src, _Float16* __restrict__ hi,
                       _Float16* __restrict__ lo, int n)
{
    int i = blockIdx.x * 256 + threadIdx.x;
    if (i >= n) return;
    float v = src[i];
    _Float16 h = (_Float16)v;
    hi[i] = h;
    lo[i] = (_Float16)(v - (float)h);
}

// ============ fp16-A x split-fp16-B MFMA GEMM (tile 128x128, BK=32, z = heads) ============
// Epilogue stages C through LDS (reusing the A/B tile space) -> f16x8 coalesced stores.
#define LSG 40    // halfs per staging row (32 + 8 pad)
#define CP  136   // halfs per C-tile row (128 + 8 pad)
template<bool FUSE_BIAS_ELU>
__global__ __launch_bounds__(256, 2) void k_gemm_h(
    const _Float16* __restrict__ A, const _Float16* __restrict__ Bh,
    const _Float16* __restrict__ Bl, const float* __restrict__ bias,
    _Float16* __restrict__ C,
    int M, int K, int lda, int ldb, int ldc,
    long aZ, long bZ, long cZ, long biasZ)
{
    __shared__ __align__(16) _Float16 smem[128 * CP];
    _Float16* As  = smem;
    _Float16* Bhs = smem + 128 * LSG;
    _Float16* Bls = smem + 256 * LSG;

    const _Float16* Ab  = A  + (size_t)blockIdx.z * aZ;
    const _Float16* Bhb = Bh + (size_t)blockIdx.z * bZ;
    const _Float16* Blb = Bl + (size_t)blockIdx.z * bZ;
    _Float16* Cb = C + (size_t)blockIdx.z * cZ;

    const int tid = threadIdx.x;
    const int wave = tid >> 6, lane = tid & 63;
    const int wm = wave >> 1, wn = wave & 1;
    const int quad = lane >> 4, l16 = lane & 15;
    const int m0 = blockIdx.x * 128;

    f32x4 acc[4][4] = {};

    for (int k0 = 0; k0 < K; k0 += 32) {
        #pragma unroll
        for (int q = 0; q < 2; ++q) {
            int idx = tid + q * 256;
            int row = idx >> 2, kq = idx & 3;
            int rg = m0 + row;
            f16x8 va = {};
            if (rg < M) va = *(const f16x8*)(Ab + (size_t)rg * lda + k0 + kq * 8);
            *(f16x8*)&As[row * LSG + kq * 8] = va;
            *(f16x8*)&Bhs[row * LSG + kq * 8] = *(const f16x8*)(Bhb + (size_t)row * ldb + k0 + kq * 8);
            *(f16x8*)&Bls[row * LSG + kq * 8] = *(const f16x8*)(Blb + (size_t)row * ldb + k0 + kq * 8);
        }
        __syncthreads();

        f16x8 af[4], bhf[4], blf[4];
        #pragma unroll
        for (int i = 0; i < 4; ++i) {
            int mr = wm * 64 + i * 16 + l16;
            af[i] = *(const f16x8*)&As[mr * LSG + quad * 8];
            int nr = wn * 64 + i * 16 + l16;
            bhf[i] = *(const f16x8*)&Bhs[nr * LSG + quad * 8];
            blf[i] = *(const f16x8*)&Bls[nr * LSG + quad * 8];
        }
        #pragma unroll
        for (int i = 0; i < 4; ++i)
            #pragma unroll
            for (int j = 0; j < 4; ++j) {
                acc[i][j] = __builtin_amdgcn_mfma_f32_16x16x32_f16(af[i], bhf[j], acc[i][j], 0, 0, 0);
                acc[i][j] = __builtin_amdgcn_mfma_f32_16x16x32_f16(af[i], blf[j], acc[i][j], 0, 0, 0);
            }
        __syncthreads();
    }

    #pragma unroll
    for (int j = 0; j < 4; ++j) {
        int n = wn * 64 + j * 16 + l16;
        float bb = 0.f;
        if (FUSE_BIAS_ELU) bb = bias[blockIdx.z * biasZ + n];
        #pragma unroll
        for (int i = 0; i < 4; ++i)
            #pragma unroll
            for (int r = 0; r < 4; ++r) {
                float v = acc[i][j][r];
                if (FUSE_BIAS_ELU) v = elu(v + bb);
                smem[(wm * 64 + i * 16 + quad * 4 + r) * CP + n] = (_Float16)v;
            }
    }
    __syncthreads();
    for (int c = tid; c < 2048; c += 256) {
        int row = c >> 4, col8 = (c & 15) * 8;
        int m = m0 + row;
        if (m < M)
            *(f16x8*)(Cb + (size_t)m * ldc + col8) = *(const f16x8*)&smem[row * CP + col8];
    }
}

// ============ fold attention vectors: w_s[h,k] = sum_c att_src[h,c] * W1[h*128+c, k] ============
__global__ __launch_bounds__(128) void k_wvec(const float* __restrict__ W1,
                                              const float* __restrict__ as1,
                                              const float* __restrict__ ad1,
                                              float* __restrict__ w_s,
                                              float* __restrict__ w_d)
{
    int h = blockIdx.x, k = threadIdx.x;
    float s = 0.f, d = 0.f;
    for (int c = 0; c < 128; ++c) {
        float w = W1[((size_t)(h * 128 + c)) * 128 + k];
        s += as1[h * 128 + c] * w;
        d += ad1[h * 128 + c] * w;
    }
    w_s[h * 128 + k] = s;
    w_d[h * 128 + k] = d;
}

// ============ layer-1 attention logits from raw x; also emit x as fp16 ============
__global__ __launch_bounds__(256) void k_attn_x(const float* __restrict__ x,
                                                const float* __restrict__ w_s,
                                                const float* __restrict__ w_d,
                                                float* __restrict__ a_s,
                                                float* __restrict__ a_d,
                                                _Float16* __restrict__ xh, int N)
{
    int n = blockIdx.x * 4 + (threadIdx.x >> 6);
    if (n >= N) return;
    int lane = threadIdx.x & 63;
    float2 xv = *(const float2*)(x + (size_t)n * 128 + lane * 2);
    f16x2 hv = { (_Float16)xv.x, (_Float16)xv.y };
    *(f16x2*)(xh + (size_t)n * 128 + lane * 2) = hv;
    float ps[4], pd[4];
    #pragma unroll
    for (int h = 0; h < 4; ++h) {
        float2 sv = *(const float2*)(w_s + h * 128 + lane * 2);
        float2 dv = *(const float2*)(w_d + h * 128 + lane * 2);
        ps[h] = xv.x * sv.x + xv.y * sv.y;
        pd[h] = xv.x * dv.x + xv.y * dv.y;
    }
    #pragma unroll
    for (int h = 0; h < 4; ++h)
        for (int off = 32; off; off >>= 1) {
            ps[h] += __shfl_xor(ps[h], off);
            pd[h] += __shfl_xor(pd[h], off);
        }
    if (lane == 0) {
        *(float4*)(a_s + (size_t)n * 4) = make_float4(ps[0], ps[1], ps[2], ps[3]);
        *(float4*)(a_d + (size_t)n * 4) = make_float4(pd[0], pd[1], pd[2], pd[3]);
    }
}

// ============ layer-2 attention logits from fp16 xh2 ============
__global__ __launch_bounds__(256) void k_attn2(const _Float16* __restrict__ xh,
                                               const float* __restrict__ as2,
                                               const float* __restrict__ ad2,
                                               float* __restrict__ a_s,
                                               float* __restrict__ a_d, int N)
{
    int n = blockIdx.x * 4 + (threadIdx.x >> 6);
    if (n >= N) return;
    int lane = threadIdx.x & 63;
    f16x2 xv = *(const f16x2*)(xh + (size_t)n * 128 + lane * 2);
    float vx = (float)xv.x, vy = (float)xv.y;
    float2 sv = *(const float2*)(as2 + lane * 2);
    float2 dv = *(const float2*)(ad2 + lane * 2);
    float ps = vx * sv.x + vy * sv.y;
    float pd = vx * dv.x + vy * dv.y;
    for (int off = 32; off; off >>= 1) { ps += __shfl_xor(ps, off); pd += __shfl_xor(pd, off); }
    if (lane == 0) { a_s[n] = ps; a_d[n] = pd; }
}

// ============ CSR construction ============
// k_count stores each edge's RANK within its dst (atomicAdd return) -> k_fill needs no atomics.
__global__ void k_count(const int* __restrict__ ei, int* __restrict__ deg,
                        unsigned short* __restrict__ rank, int E, int Ep)
{
    int e = blockIdx.x * blockDim.x + threadIdx.x;
    if (e >= Ep) return;
    int dst = (e < E) ? ei[E + e] : (e - E);
    rank[e] = (unsigned short)atomicAdd(&deg[dst], 1);
}

__global__ __launch_bounds__(1024) void k_scanA(const int* __restrict__ deg,
                                                int* __restrict__ start,
                                                int* __restrict__ sums, int Ntot, int N)
{
    __shared__ int sm[1024];
    int tid = threadIdx.x;
    int i = blockIdx.x * 1024 + tid;
    int v = (i < N) ? deg[i] : 0;
    sm[tid] = v; __syncthreads();
    for (int off = 1; off < 1024; off <<= 1) {
        int t = (tid >= off) ? sm[tid - off] : 0;
        __syncthreads();
        sm[tid] += t;
        __syncthreads();
    }
    if (i < Ntot) start[i] = sm[tid] - v;
    if (tid == 1023) sums[blockIdx.x] = sm[1023];
}

__global__ void k_scanB(int* sums, int nb)
{
    int l = threadIdx.x;
    int v = (l < nb) ? sums[l] : 0;
    int orig = v;
    for (int off = 1; off < 64; off <<= 1) { int t = __shfl_up(v, off); if (l >= off) v += t; }
    if (l < nb) sums[l] = v - orig;
}

__global__ __launch_bounds__(1024) void k_scanC(int* __restrict__ start,
                                                const int* __restrict__ sums, int Ntot)
{
    int i = blockIdx.x * 1024 + threadIdx.x;
    if (i < Ntot) start[i] += sums[blockIdx.x];
}

__global__ void k_fill(const int* __restrict__ ei, const int* __restrict__ start,
                       const unsigned short* __restrict__ rank,
                       unsigned short* __restrict__ csr_src, int E, int Ep)
{
    int e = blockIdx.x * blockDim.x + threadIdx.x;
    if (e >= Ep) return;
    int src, dst;
    if (e < E) { src = ei[e]; dst = ei[E + e]; } else { src = dst = e - E; }
    csr_src[start[dst] + rank[e]] = (unsigned short)src;
}

// ============ layer-1 gather: one 16-LANE GROUP per dst (4 dsts/wave) ============
__global__ __launch_bounds__(256) void k_gat1(const int* __restrict__ start,
                                              const unsigned short* __restrict__ csr,
                                              const float* __restrict__ a_s,
                                              const float* __restrict__ a_d,
                                              const _Float16* __restrict__ x,
                                              _Float16* __restrict__ agg, int N)
{
    int d = blockIdx.x * 16 + (threadIdx.x >> 4);
    if (d >= N) return;
    int g16 = threadIdx.x & 15;
    int beg = start[d], end = start[d + 1];
    int deg = end - beg;
    float4 ad4 = *(const float4*)(a_d + (size_t)d * 4);

    float sum0 = 0.f, sum1 = 0.f, sum2 = 0.f, sum3 = 0.f;
    float acc[4][8] = {};
    const _Float16* xb = x + g16 * 8;

    for (int base = 0; base < deg; base += 16) {
        int nch = deg - base; if (nch > 16) nch = 16;
        int s = 0;
        float e0 = 0.f, e1 = 0.f, e2 = 0.f, e3 = 0.f;
        if (g16 < nch) {
            s = csr[beg + base + g16];
            float4 as4 = *(const float4*)(a_s + (size_t)s * 4);
            e0 = __expf(leaky(as4.x + ad4.x));
            e1 = __expf(leaky(as4.y + ad4.y));
            e2 = __expf(leaky(as4.z + ad4.z));
            e3 = __expf(leaky(as4.w + ad4.w));
            sum0 += e0; sum1 += e1; sum2 += e2; sum3 += e3;
        }
        for (int t = 0; t < nch; ++t) {
            int   si = __shfl(s,  t, 16);
            float w0 = __shfl(e0, t, 16);
            float w1 = __shfl(e1, t, 16);
            float w2 = __shfl(e2, t, 16);
            float w3 = __shfl(e3, t, 16);
            f16x8 hv = *(const f16x8*)(xb + (size_t)si * 128);
            #pragma unroll
            for (int c = 0; c < 8; ++c) {
                float v = (float)hv[c];
                acc[0][c] += w0 * v;
                acc[1][c] += w1 * v;
                acc[2][c] += w2 * v;
                acc[3][c] += w3 * v;
            }
        }
    }
    #pragma unroll
    for (int o = 1; o < 16; o <<= 1) {
        sum0 += __shfl_xor(sum0, o, 16); sum1 += __shfl_xor(sum1, o, 16);
        sum2 += __shfl_xor(sum2, o, 16); sum3 += __shfl_xor(sum3, o, 16);
    }
    float inv[4] = { 1.f / (sum0 + 1e-16f), 1.f / (sum1 + 1e-16f),
                     1.f / (sum2 + 1e-16f), 1.f / (sum3 + 1e-16f) };
    _Float16* o = agg + (size_t)d * 512 + g16 * 8;
    #pragma unroll
    for (int h = 0; h < 4; ++h) {
        f16x8 ov;
        #pragma unroll
        for (int c = 0; c < 8; ++c) ov[c] = (_Float16)(acc[h][c] * inv[h]);
        *(f16x8*)(o + h * 128) = ov;
    }
}

// ============ layer-2 gather (1 head) + bias + ELU -> h2 f32, 16-lane group per dst ============
__global__ __launch_bounds__(256) void k_gat2(const int* __restrict__ start,
                                              const unsigned short* __restrict__ csr,
                                              const float* __restrict__ a_s,
                                              const float* __restrict__ a_d,
                                              const _Float16* __restrict__ xh2,
                                              const float* __restrict__ b2,
                                              float* __restrict__ h2, int N)
{
    int d = blockIdx.x * 16 + (threadIdx.x >> 4);
    if (d >= N) return;
    int g16 = threadIdx.x & 15;
    int beg = start[d], end = start[d + 1];
    int deg = end - beg;
    float ad = a_d[d];

    float sum = 0.f;
    float acc[8] = {};
    const _Float16* xb = xh2 + g16 * 8;

    for (int base = 0; base < deg; base += 16) {
        int nch = deg - base; if (nch > 16) nch = 16;
        int s = 0; float e = 0.f;
        if (g16 < nch) {
            s = csr[beg + base + g16];
            e = __expf(leaky(a_s[s] + ad));
            sum += e;
        }
        for (int t = 0; t < nch; ++t) {
            int   si = __shfl(s, t, 16);
            float w  = __shfl(e, t, 16);
            f16x8 hv = *(const f16x8*)(xb + (size_t)si * 128);
            #pragma unroll
            for (int c = 0; c < 8; ++c) acc[c] += w * (float)hv[c];
        }
    }
    #pragma unroll
    for (int o = 1; o < 16; o <<= 1) sum += __shfl_xor(sum, o, 16);
    float inv = 1.f / (sum + 1e-16f);
    float ov[8];
    #pragma unroll
    for (int c = 0; c < 8; ++c) ov[c] = elu(acc[c] * inv + b2[g16 * 8 + c]);
    float* op = h2 + (size_t)d * 128 + g16 * 8;
    *(float4*)(op)     = *(float4*)&ov[0];
    *(float4*)(op + 4) = *(float4*)&ov[4];
}

// ============ graph boundaries from SORTED batch ============
__global__ void k_gbound(const int* __restrict__ batch, int* __restrict__ gstart, int N, int G)
{
    int n = blockIdx.x * blockDim.x + threadIdx.x;
    if (n >= N) return;
    int b = batch[n];
    int prev = (n == 0) ? -1 : batch[n - 1];
    for (int g = prev + 1; g <= b; ++g) gstart[g] = n;
    if (n == N - 1)
        for (int g = b + 1; g <= G; ++g) gstart[g] = N;
}

// ============ pooling stage A: chunked partial sums ============
#define PCH 64
__global__ __launch_bounds__(128) void k_poolA(const float* __restrict__ h2,
                                               const int* __restrict__ batch,
                                               float* __restrict__ pooled, int N)
{
    int c = threadIdx.x;
    int n0 = blockIdx.x * PCH;
    int n1 = n0 + PCH < N ? n0 + PCH : N;
    if (n0 >= N) return;
    int g = batch[n0];
    float acc = 0.f;
    for (int n = n0; n < n1; ++n) {
        int bg = batch[n];
        if (bg != g) { atomicAdd(&pooled[(size_t)g * 128 + c], acc); acc = 0.f; g = bg; }
        acc += h2[(size_t)n * 128 + c];
    }
    atomicAdd(&pooled[(size_t)g * 128 + c], acc);
}

// ============ head: mean + relu(pooled@Wh1^T+bh1) @ Wh2^T + bh2 ============
__global__ __launch_bounds__(128) void k_head(const float* __restrict__ pooled,
                                              const int* __restrict__ gstart,
                                              const float* __restrict__ Wh1,
                                              const float* __restrict__ bh1,
                                              const float* __restrict__ Wh2,
                                              const float* __restrict__ bh2,
                                              float* __restrict__ out)
{
    int g = blockIdx.x, c = threadIdx.x;
    __shared__ float p[128];
    __shared__ float red[128];
    float cf = (float)(gstart[g + 1] - gstart[g]); cf = cf > 1.f ? cf : 1.f;
    p[c] = pooled[(size_t)g * 128 + c] / cf;
    __syncthreads();
    float z = bh1[c];
    for (int k = 0; k < 128; ++k) z += p[k] * Wh1[c * 128 + k];
    z = z > 0.f ? z : 0.f;
    red[c] = z * Wh2[c];
    __syncthreads();
    for (int st = 64; st > 0; st >>= 1) { if (c < st) red[c] += red[c + st]; __syncthreads(); }
    if (c == 0) out[g] = red[0] + bh2[0];
}

// ============ launch ============
extern "C" void kernel_launch(void* const* d_in, const int* in_sizes, int n_in,
                              void* d_out, int out_size, void* d_ws, size_t ws_size,
                              hipStream_t stream)
{
    const float* x   = (const float*)d_in[0];
    const int*   ei  = (const int*)d_in[1];
    const int*   bat = (const int*)d_in[2];
    const float* W1  = (const float*)d_in[3];
    const float* as1 = (const float*)d_in[4];
    const float* ad1 = (const float*)d_in[5];
    const float* b1  = (const float*)d_in[6];
    const float* W2  = (const float*)d_in[7];
    const float* as2 = (const float*)d_in[8];
    const float* ad2 = (const float*)d_in[9];
    const float* b2  = (const float*)d_in[10];
    const float* Wh1 = (const float*)d_in[11];
    const float* bh1 = (const float*)d_in[12];
    const float* Wh2 = (const float*)d_in[13];
    const float* bh2 = (const float*)d_in[14];
    float* out = (float*)d_out;

    const int N  = in_sizes[0] / 128;
    const int E  = in_sizes[1] / 2;
    const int Ep = E + N;
    const int G  = 128;

    char* w = (char*)d_ws;
    size_t off = 0;
    auto alloc = [&](size_t bytes) -> char* {
        char* p = w + off; off += (bytes + 511) & ~(size_t)511; return p;
    };
    _Float16* x_h  = (_Float16*)alloc((size_t)N * 128 * 2);
    _Float16* agg  = (_Float16*)alloc((size_t)N * 512 * 2);
    _Float16* h1   = (_Float16*)alloc((size_t)N * 512 * 2);
    _Float16* xh2h = (_Float16*)alloc((size_t)N * 128 * 2);
    float*    h2   = (float*)alloc((size_t)N * 128 * 4);
    float*    As1  = (float*)alloc((size_t)N * 4 * 4);
    float*    Ad1  = (float*)alloc((size_t)N * 4 * 4);
    float*    As2  = (float*)alloc((size_t)N * 4);
    float*    Ad2  = (float*)alloc((size_t)N * 4);
    float*    w_s1 = (float*)alloc(512 * 4);
    float*    w_d1 = (float*)alloc(512 * 4);
    _Float16* W1hi = (_Float16*)alloc(65536 * 2);
    _Float16* W1lo = (_Float16*)alloc(65536 * 2);
    _Float16* W2hi = (_Float16*)alloc(65536 * 2);
    _Float16* W2lo = (_Float16*)alloc(65536 * 2);
    int* startb = (int*)alloc((size_t)(N + 1) * 4);
    unsigned short* csr  = (unsigned short*)alloc((size_t)Ep * 2);
    unsigned short* rank = (unsigned short*)alloc((size_t)Ep * 2);
    int* sums   = (int*)alloc(4096);
    int* gstart = (int*)alloc((size_t)(G + 1) * 4);
    char* zbase = w + off;                                // zero-init group
    int*   deg    = (int*)alloc((size_t)N * 4);
    float* pooled = (float*)alloc((size_t)G * 128 * 4);
    size_t zbytes = (size_t)((w + off) - zbase);

    hipMemsetAsync(zbase, 0, zbytes, stream);

    // 1) fold attention vectors; logits + fp16 x
    k_wvec<<<4, 128, 0, stream>>>(W1, as1, ad1, w_s1, w_d1);
    k_attn_x<<<(N + 3) / 4, 256, 0, stream>>>(x, w_s1, w_d1, As1, Ad1, x_h, N);
    // 2) weights -> split fp16
    k_wcvt<<<256, 256, 0, stream>>>(W1, W1hi, W1lo, 65536);
    k_wcvt<<<256, 256, 0, stream>>>(W2, W2hi, W2lo, 65536);
    // 3) CSR by destination (self-loops appended); rank trick -> atomic-free fill
    k_count<<<(Ep + 255) / 256, 256, 0, stream>>>(ei, deg, rank, E, Ep);
    int nb = (N + 1 + 1023) / 1024;
    k_scanA<<<nb, 1024, 0, stream>>>(deg, startb, sums, N + 1, N);
    k_scanB<<<1, 64, 0, stream>>>(sums, nb);
    k_scanC<<<nb, 1024, 0, stream>>>(startb, sums, N + 1);
    k_fill<<<(Ep + 255) / 256, 256, 0, stream>>>(ei, startb, rank, csr, E, Ep);
    // 4) graph boundaries
    k_gbound<<<(N + 255) / 256, 256, 0, stream>>>(bat, gstart, N, G);
    // 5) layer-1 gather (16-lane group per dst) -> agg fp16 [N, 4*128]
    k_gat1<<<(N + 15) / 16, 256, 0, stream>>>(startb, csr, As1, Ad1, x_h, agg, N);
    // 6) block-diag projection + bias + ELU (fp16 MFMA): h1_h = elu(agg_h @ W1_h^T + b1_h)
    k_gemm_h<true><<<dim3((N + 127) / 128, 1, 4), 256, 0, stream>>>(
        agg, W1hi, W1lo, b1, h1, N, 128, 512, 128, 512, 128L, 16384L, 128L, 128L);
    // 7) xh2 = h1 @ W2^T  [N,128]  (fp16 MFMA)
    k_gemm_h<false><<<dim3((N + 127) / 128, 1, 1), 256, 0, stream>>>(
        h1, W2hi, W2lo, nullptr, xh2h, N, 512, 512, 512, 128, 0L, 0L, 0L, 0L);
    // 8) layer-2 attention logits
    k_attn2<<<(N + 3) / 4, 256, 0, stream>>>(xh2h, as2, ad2, As2, Ad2, N);
    // 9) layer-2 gather + bias + ELU -> h2 f32 (16-lane group per dst)
    k_gat2<<<(N + 15) / 16, 256, 0, stream>>>(startb, csr, As2, Ad2, xh2h, b2, h2, N);
    // 10) two-stage pooling + MLP head
    k_poolA<<<(N + PCH - 1) / PCH, 128, 0, stream>>>(h2, bat, pooled, N);
    k_head<<<G, 128, 0, stream>>>(pooled, gstart, Wh1, bh1, Wh2, bh2, out);
}

// Round 15
// 352.073 us; speedup vs baseline: 1.3434x; 1.0286x over previous
//
#include <hip/hip_runtime.h>
#include <cstdint>
#include <cstddef>

#define NEG_SLOPE 0.2f

typedef _Float16 f16x8 __attribute__((ext_vector_type(8)));
typedef _Float16 f16x2 __attribute__((ext_vector_type(2)));
typedef float    f32x4 __attribute__((ext_vector_type(4)));
typedef float    f32x2 __attribute__((ext_vector_type(2)));

__device__ __forceinline__ float leaky(float x){ return x > 0.f ? x : NEG_SLOPE * x; }
__device__ __forceinline__ float elu(float x){ return x > 0.f ? x : __expf(x) - 1.f; }

// ============ prep: W1/W2 -> split fp16 hi/lo, + fold attention vectors through W1 ============
__global__ __launch_bounds__(256) void k_prep(const float* __restrict__ W1,
                                              const float* __restrict__ W2,
                                              const float* __restrict__ as1,
                                              const float* __restrict__ ad1,
                                              _Float16* __restrict__ W1hi, _Float16* __restrict__ W1lo,
                                              _Float16* __restrict__ W2hi, _Float16* __restrict__ W2lo,
                                              float* __restrict__ w_s, float* __restrict__ w_d)
{
    int b = blockIdx.x;
    if (b < 512) {
        const float* src = (b < 256) ? W1 : W2;
        _Float16* hi = (b < 256) ? W1hi : W2hi;
        _Float16* lo = (b < 256) ? W1lo : W2lo;
        int i = ((b & 255) << 8) + threadIdx.x;
        float v = src[i];
        _Float16 h = (_Float16)v;
        hi[i] = h;
        lo[i] = (_Float16)(v - (float)h);
    } else {
        int h = (b - 512) * 2 + (threadIdx.x >> 7);
        int k = threadIdx.x & 127;
        float s = 0.f, d = 0.f;
        for (int c = 0; c < 128; ++c) {
            float w = W1[((size_t)(h * 128 + c)) * 128 + k];
            s += as1[h * 128 + c] * w;
            d += ad1[h * 128 + c] * w;
        }
        w_s[h * 128 + k] = s;
        w_d[h * 128 + k] = d;
    }
}

// ============ fp16-A x split-fp16-B MFMA GEMM (tile 128x128, BK=32, z = heads) ============
// LDS-staged C epilogue -> f16x8 coalesced stores; optional fused layer-2 attn logits.
#define LSG 40    // halfs per staging row (32 + 8 pad)
#define CP  136   // halfs per C-tile row (128 + 8 pad)
template<bool FUSE_BIAS_ELU, bool FUSE_ATTN2>
__global__ __launch_bounds__(256, 2) void k_gemm_h(
    const _Float16* __restrict__ A, const _Float16* __restrict__ Bh,
    const _Float16* __restrict__ Bl, const float* __restrict__ bias,
    _Float16* __restrict__ C,
    const float* __restrict__ as2, const float* __restrict__ ad2,
    float* __restrict__ As2, float* __restrict__ Ad2,
    int M, int K, int lda, int ldb, int ldc,
    long aZ, long bZ, long cZ, long biasZ)
{
    __shared__ __align__(16) _Float16 smem[128 * CP];
    _Float16* As  = smem;
    _Float16* Bhs = smem + 128 * LSG;
    _Float16* Bls = smem + 256 * LSG;

    const _Float16* Ab  = A  + (size_t)blockIdx.z * aZ;
    const _Float16* Bhb = Bh + (size_t)blockIdx.z * bZ;
    const _Float16* Blb = Bl + (size_t)blockIdx.z * bZ;
    _Float16* Cb = C + (size_t)blockIdx.z * cZ;

    const int tid = threadIdx.x;
    const int wave = tid >> 6, lane = tid & 63;
    const int wm = wave >> 1, wn = wave & 1;
    const int quad = lane >> 4, l16 = lane & 15;
    const int m0 = blockIdx.x * 128;

    f32x4 acc[4][4] = {};

    for (int k0 = 0; k0 < K; k0 += 32) {
        #pragma unroll
        for (int q = 0; q < 2; ++q) {
            int idx = tid + q * 256;
            int row = idx >> 2, kq = idx & 3;
            int rg = m0 + row;
            f16x8 va = {};
            if (rg < M) va = *(const f16x8*)(Ab + (size_t)rg * lda + k0 + kq * 8);
            *(f16x8*)&As[row * LSG + kq * 8] = va;
            *(f16x8*)&Bhs[row * LSG + kq * 8] = *(const f16x8*)(Bhb + (size_t)row * ldb + k0 + kq * 8);
            *(f16x8*)&Bls[row * LSG + kq * 8] = *(const f16x8*)(Blb + (size_t)row * ldb + k0 + kq * 8);
        }
        __syncthreads();

        f16x8 af[4], bhf[4], blf[4];
        #pragma unroll
        for (int i = 0; i < 4; ++i) {
            int mr = wm * 64 + i * 16 + l16;
            af[i] = *(const f16x8*)&As[mr * LSG + quad * 8];
            int nr = wn * 64 + i * 16 + l16;
            bhf[i] = *(const f16x8*)&Bhs[nr * LSG + quad * 8];
            blf[i] = *(const f16x8*)&Bls[nr * LSG + quad * 8];
        }
        #pragma unroll
        for (int i = 0; i < 4; ++i)
            #pragma unroll
            for (int j = 0; j < 4; ++j) {
                acc[i][j] = __builtin_amdgcn_mfma_f32_16x16x32_f16(af[i], bhf[j], acc[i][j], 0, 0, 0);
                acc[i][j] = __builtin_amdgcn_mfma_f32_16x16x32_f16(af[i], blf[j], acc[i][j], 0, 0, 0);
            }
        __syncthreads();
    }

    #pragma unroll
    for (int j = 0; j < 4; ++j) {
        int n = wn * 64 + j * 16 + l16;
        float bb = 0.f;
        if (FUSE_BIAS_ELU) bb = bias[blockIdx.z * biasZ + n];
        #pragma unroll
        for (int i = 0; i < 4; ++i)
            #pragma unroll
            for (int r = 0; r < 4; ++r) {
                float v = acc[i][j][r];
                if (FUSE_BIAS_ELU) v = elu(v + bb);
                smem[(wm * 64 + i * 16 + quad * 4 + r) * CP + n] = (_Float16)v;
            }
    }
    __syncthreads();
    for (int c = tid; c < 2048; c += 256) {
        int row = c >> 4, col8 = (c & 15) * 8;
        int m = m0 + row;
        if (m < M)
            *(f16x8*)(Cb + (size_t)m * ldc + col8) = *(const f16x8*)&smem[row * CP + col8];
    }
    if (FUSE_ATTN2) {
        // layer-2 attn logits from the C-tile: 2 threads per row
        int row = tid >> 1, half = tid & 1;
        int d = m0 + row;
        float ss = 0.f, sd = 0.f;
        const _Float16* rp = &smem[row * CP + half * 64];
        #pragma unroll
        for (int c8 = 0; c8 < 8; ++c8) {
            f16x8 v = *(const f16x8*)(rp + c8 * 8);
            #pragma unroll
            for (int c = 0; c < 8; ++c) {
                float f = (float)v[c];
                int n = half * 64 + c8 * 8 + c;
                ss += f * as2[n];
                sd += f * ad2[n];
            }
        }
        ss += __shfl_xor(ss, 1);
        sd += __shfl_xor(sd, 1);
        if (half == 0 && d < M) { As2[d] = ss; Ad2[d] = sd; }
    }
}

// ============ layer-1 attention logits from raw x; also emit x as fp16 ============
__global__ __launch_bounds__(256) void k_attn_x(const float* __restrict__ x,
                                                const float* __restrict__ w_s,
                                                const float* __restrict__ w_d,
                                                float* __restrict__ a_s,
                                                float* __restrict__ a_d,
                                                _Float16* __restrict__ xh, int N)
{
    int n = blockIdx.x * 4 + (threadIdx.x >> 6);
    if (n >= N) return;
    int lane = threadIdx.x & 63;
    float2 xv = *(const float2*)(x + (size_t)n * 128 + lane * 2);
    f16x2 hv = { (_Float16)xv.x, (_Float16)xv.y };
    *(f16x2*)(xh + (size_t)n * 128 + lane * 2) = hv;
    float ps[4], pd[4];
    #pragma unroll
    for (int h = 0; h < 4; ++h) {
        float2 sv = *(const float2*)(w_s + h * 128 + lane * 2);
        float2 dv = *(const float2*)(w_d + h * 128 + lane * 2);
        ps[h] = xv.x * sv.x + xv.y * sv.y;
        pd[h] = xv.x * dv.x + xv.y * dv.y;
    }
    #pragma unroll
    for (int h = 0; h < 4; ++h)
        for (int off = 32; off; off >>= 1) {
            ps[h] += __shfl_xor(ps[h], off);
            pd[h] += __shfl_xor(pd[h], off);
        }
    if (lane == 0) {
        *(float4*)(a_s + (size_t)n * 4) = make_float4(ps[0], ps[1], ps[2], ps[3]);
        *(float4*)(a_d + (size_t)n * 4) = make_float4(pd[0], pd[1], pd[2], pd[3]);
    }
}

// ============ CSR construction (count+rank, fused graph boundaries) ============
__global__ void k_count(const int* __restrict__ ei, int* __restrict__ deg,
                        unsigned short* __restrict__ rank,
                        const int* __restrict__ batch, int* __restrict__ gstart,
                        int E, int Ep, int N, int G, int nbc)
{
    if ((int)blockIdx.x < nbc) {
        int e = blockIdx.x * 256 + threadIdx.x;
        if (e >= Ep) return;
        int dst = (e < E) ? ei[E + e] : (e - E);
        rank[e] = (unsigned short)atomicAdd(&deg[dst], 1);
    } else {
        int n = (blockIdx.x - nbc) * 256 + threadIdx.x;
        if (n >= N) return;
        int b = batch[n];
        int prev = (n == 0) ? -1 : batch[n - 1];
        for (int g = prev + 1; g <= b; ++g) gstart[g] = n;
        if (n == N - 1)
            for (int g = b + 1; g <= G; ++g) gstart[g] = N;
    }
}

__global__ __launch_bounds__(1024) void k_scanA(const int* __restrict__ deg,
                                                int* __restrict__ start,
                                                int* __restrict__ sums, int Ntot, int N)
{
    __shared__ int sm[1024];
    int tid = threadIdx.x;
    int i = blockIdx.x * 1024 + tid;
    int v = (i < N) ? deg[i] : 0;
    sm[tid] = v; __syncthreads();
    for (int off = 1; off < 1024; off <<= 1) {
        int t = (tid >= off) ? sm[tid - off] : 0;
        __syncthreads();
        sm[tid] += t;
        __syncthreads();
    }
    if (i < Ntot) start[i] = sm[tid] - v;
    if (tid == 1023) sums[blockIdx.x] = sm[1023];
}

__global__ void k_scanB(int* sums, int nb)
{
    int l = threadIdx.x;
    int v = (l < nb) ? sums[l] : 0;
    int orig = v;
    for (int off = 1; off < 64; off <<= 1) { int t = __shfl_up(v, off); if (l >= off) v += t; }
    if (l < nb) sums[l] = v - orig;
}

__global__ __launch_bounds__(1024) void k_scanC(int* __restrict__ start,
                                                const int* __restrict__ sums, int Ntot)
{
    int i = blockIdx.x * 1024 + threadIdx.x;
    if (i < Ntot) start[i] += sums[blockIdx.x];
}

__global__ void k_fill(const int* __restrict__ ei, const int* __restrict__ start,
                       const unsigned short* __restrict__ rank,
                       unsigned short* __restrict__ csr_src, int E, int Ep)
{
    int e = blockIdx.x * blockDim.x + threadIdx.x;
    if (e >= Ep) return;
    int src, dst;
    if (e < E) { src = ei[e]; dst = ei[E + e]; } else { src = dst = e - E; }
    csr_src[start[dst] + rank[e]] = (unsigned short)src;
}

// ============ layer-1 gather: 16-lane group per dst, f32x2 packed accumulation ============
__global__ __launch_bounds__(256) void k_gat1(const int* __restrict__ start,
                                              const unsigned short* __restrict__ csr,
                                              const float* __restrict__ a_s,
                                              const float* __restrict__ a_d,
                                              const _Float16* __restrict__ x,
                                              _Float16* __restrict__ agg, int N)
{
    int d = blockIdx.x * 16 + (threadIdx.x >> 4);
    if (d >= N) return;
    int g16 = threadIdx.x & 15;
    int beg = start[d], end = start[d + 1];
    int deg = end - beg;
    float4 ad4 = *(const float4*)(a_d + (size_t)d * 4);

    float sum0 = 0.f, sum1 = 0.f, sum2 = 0.f, sum3 = 0.f;
    f32x2 acc[4][4] = {};
    const _Float16* xb = x + g16 * 8;

    for (int base = 0; base < deg; base += 16) {
        int nch = deg - base; if (nch > 16) nch = 16;
        int s = 0;
        float e0 = 0.f, e1 = 0.f, e2 = 0.f, e3 = 0.f;
        if (g16 < nch) {
            s = csr[beg + base + g16];
            float4 as4 = *(const float4*)(a_s + (size_t)s * 4);
            e0 = __expf(leaky(as4.x + ad4.x));
            e1 = __expf(leaky(as4.y + ad4.y));
            e2 = __expf(leaky(as4.z + ad4.z));
            e3 = __expf(leaky(as4.w + ad4.w));
            sum0 += e0; sum1 += e1; sum2 += e2; sum3 += e3;
        }
        for (int t = 0; t < nch; ++t) {
            int   si = __shfl(s,  t, 16);
            float w0 = __shfl(e0, t, 16);
            float w1 = __shfl(e1, t, 16);
            float w2 = __shfl(e2, t, 16);
            float w3 = __shfl(e3, t, 16);
            f16x8 hv = *(const f16x8*)(xb + (size_t)si * 128);
            f32x2 v0 = { (float)hv[0], (float)hv[1] };
            f32x2 v1 = { (float)hv[2], (float)hv[3] };
            f32x2 v2 = { (float)hv[4], (float)hv[5] };
            f32x2 v3 = { (float)hv[6], (float)hv[7] };
            acc[0][0] += w0 * v0; acc[0][1] += w0 * v1; acc[0][2] += w0 * v2; acc[0][3] += w0 * v3;
            acc[1][0] += w1 * v0; acc[1][1] += w1 * v1; acc[1][2] += w1 * v2; acc[1][3] += w1 * v3;
            acc[2][0] += w2 * v0; acc[2][1] += w2 * v1; acc[2][2] += w2 * v2; acc[2][3] += w2 * v3;
            acc[3][0] += w3 * v0; acc[3][1] += w3 * v1; acc[3][2] += w3 * v2; acc[3][3] += w3 * v3;
        }
    }
    #pragma unroll
    for (int o = 1; o < 16; o <<= 1) {
        sum0 += __shfl_xor(sum0, o, 16); sum1 += __shfl_xor(sum1, o, 16);
        sum2 += __shfl_xor(sum2, o, 16); sum3 += __shfl_xor(sum3, o, 16);
    }
    float inv[4] = { 1.f / (sum0 + 1e-16f), 1.f / (sum1 + 1e-16f),
                     1.f / (sum2 + 1e-16f), 1.f / (sum3 + 1e-16f) };
    _Float16* o = agg + (size_t)d * 512 + g16 * 8;
    #pragma unroll
    for (int h = 0; h < 4; ++h) {
        f16x8 ov;
        #pragma unroll
        for (int p = 0; p < 4; ++p) {
            ov[2 * p]     = (_Float16)(acc[h][p].x * inv[h]);
            ov[2 * p + 1] = (_Float16)(acc[h][p].y * inv[h]);
        }
        *(f16x8*)(o + h * 128) = ov;
    }
}

// ============ layer-2 gather + bias + ELU -> h2 fp16, 16-lane group per dst ============
__global__ __launch_bounds__(256) void k_gat2(const int* __restrict__ start,
                                              const unsigned short* __restrict__ csr,
                                              const float* __restrict__ a_s,
                                              const float* __restrict__ a_d,
                                              const _Float16* __restrict__ xh2,
                                              const float* __restrict__ b2,
                                              _Float16* __restrict__ h2, int N)
{
    int d = blockIdx.x * 16 + (threadIdx.x >> 4);
    if (d >= N) return;
    int g16 = threadIdx.x & 15;
    int beg = start[d], end = start[d + 1];
    int deg = end - beg;
    float ad = a_d[d];

    float sum = 0.f;
    f32x2 acc[4] = {};
    const _Float16* xb = xh2 + g16 * 8;

    for (int base = 0; base < deg; base += 16) {
        int nch = deg - base; if (nch > 16) nch = 16;
        int s = 0; float e = 0.f;
        if (g16 < nch) {
            s = csr[beg + base + g16];
            e = __expf(leaky(a_s[s] + ad));
            sum += e;
        }
        for (int t = 0; t < nch; ++t) {
            int   si = __shfl(s, t, 16);
            float w  = __shfl(e, t, 16);
            f16x8 hv = *(const f16x8*)(xb + (size_t)si * 128);
            f32x2 v0 = { (float)hv[0], (float)hv[1] };
            f32x2 v1 = { (float)hv[2], (float)hv[3] };
            f32x2 v2 = { (float)hv[4], (float)hv[5] };
            f32x2 v3 = { (float)hv[6], (float)hv[7] };
            acc[0] += w * v0; acc[1] += w * v1; acc[2] += w * v2; acc[3] += w * v3;
        }
    }
    #pragma unroll
    for (int o = 1; o < 16; o <<= 1) sum += __shfl_xor(sum, o, 16);
    float inv = 1.f / (sum + 1e-16f);
    f16x8 ov;
    #pragma unroll
    for (int p = 0; p < 4; ++p) {
        ov[2 * p]     = (_Float16)elu(acc[p].x * inv + b2[g16 * 8 + 2 * p]);
        ov[2 * p + 1] = (_Float16)elu(acc[p].y * inv + b2[g16 * 8 + 2 * p + 1]);
    }
    *(f16x8*)(h2 + (size_t)d * 128 + g16 * 8) = ov;
}

// ============ pooling stage A: chunked partial sums (h2 fp16) ============
#define PCH 64
__global__ __launch_bounds__(128) void k_poolA(const _Float16* __restrict__ h2,
                                               const int* __restrict__ batch,
                                               float* __restrict__ pooled, int N)
{
    int c = threadIdx.x;
    int n0 = blockIdx.x * PCH;
    int n1 = n0 + PCH < N ? n0 + PCH : N;
    if (n0 >= N) return;
    int g = batch[n0];
    float acc = 0.f;
    for (int n = n0; n < n1; ++n) {
        int bg = batch[n];
        if (bg != g) { atomicAdd(&pooled[(size_t)g * 128 + c], acc); acc = 0.f; g = bg; }
        acc += (float)h2[(size_t)n * 128 + c];
    }
    atomicAdd(&pooled[(size_t)g * 128 + c], acc);
}

// ============ head: mean + relu(pooled@Wh1^T+bh1) @ Wh2^T + bh2 ============
__global__ __launch_bounds__(128) void k_head(const float* __restrict__ pooled,
                                              const int* __restrict__ gstart,
                                              const float* __restrict__ Wh1,
                                              const float* __restrict__ bh1,
                                              const float* __restrict__ Wh2,
                                              const float* __restrict__ bh2,
                                              float* __restrict__ out)
{
    int g = blockIdx.x, c = threadIdx.x;
    __shared__ float p[128];
    __shared__ float red[128];
    float cf = (float)(gstart[g + 1] - gstart[g]); cf = cf > 1.f ? cf : 1.f;
    p[c] = pooled[(size_t)g * 128 + c] / cf;
    __syncthreads();
    float z = bh1[c];
    for (int k = 0; k < 128; ++k) z += p[k] * Wh1[c * 128 + k];
    z = z > 0.f ? z : 0.f;
    red[c] = z * Wh2[c];
    __syncthreads();
    for (int st = 64; st > 0; st >>= 1) { if (c < st) red[c] += red[c + st]; __syncthreads(); }
    if (c == 0) out[g] = red[0] + bh2[0];
}

// ============ launch ============
extern "C" void kernel_launch(void* const* d_in, const int* in_sizes, int n_in,
                              void* d_out, int out_size, void* d_ws, size_t ws_size,
                              hipStream_t stream)
{
    const float* x   = (const float*)d_in[0];
    const int*   ei  = (const int*)d_in[1];
    const int*   bat = (const int*)d_in[2];
    const float* W1  = (const float*)d_in[3];
    const float* as1 = (const float*)d_in[4];
    const float* ad1 = (const float*)d_in[5];
    const float* b1  = (const float*)d_in[6];
    const float* W2  = (const float*)d_in[7];
    const float* as2 = (const float*)d_in[8];
    const float* ad2 = (const float*)d_in[9];
    const float* b2  = (const float*)d_in[10];
    const float* Wh1 = (const float*)d_in[11];
    const float* bh1 = (const float*)d_in[12];
    const float* Wh2 = (const float*)d_in[13];
    const float* bh2 = (const float*)d_in[14];
    float* out = (float*)d_out;

    const int N  = in_sizes[0] / 128;
    const int E  = in_sizes[1] / 2;
    const int Ep = E + N;
    const int G  = 128;

    char* w = (char*)d_ws;
    size_t off = 0;
    auto alloc = [&](size_t bytes) -> char* {
        char* p = w + off; off += (bytes + 511) & ~(size_t)511; return p;
    };
    _Float16* x_h  = (_Float16*)alloc((size_t)N * 128 * 2);
    _Float16* agg  = (_Float16*)alloc((size_t)N * 512 * 2);
    _Float16* h1   = (_Float16*)alloc((size_t)N * 512 * 2);
    _Float16* xh2h = (_Float16*)alloc((size_t)N * 128 * 2);
    _Float16* h2   = (_Float16*)alloc((size_t)N * 128 * 2);
    float*    As1  = (float*)alloc((size_t)N * 4 * 4);
    float*    Ad1  = (float*)alloc((size_t)N * 4 * 4);
    float*    As2  = (float*)alloc((size_t)N * 4);
    float*    Ad2  = (float*)alloc((size_t)N * 4);
    float*    w_s1 = (float*)alloc(512 * 4);
    float*    w_d1 = (float*)alloc(512 * 4);
    _Float16* W1hi = (_Float16*)alloc(65536 * 2);
    _Float16* W1lo = (_Float16*)alloc(65536 * 2);
    _Float16* W2hi = (_Float16*)alloc(65536 * 2);
    _Float16* W2lo = (_Float16*)alloc(65536 * 2);
    int* startb = (int*)alloc((size_t)(N + 1) * 4);
    unsigned short* csr  = (unsigned short*)alloc((size_t)Ep * 2);
    unsigned short* rank = (unsigned short*)alloc((size_t)Ep * 2);
    int* sums   = (int*)alloc(4096);
    int* gstart = (int*)alloc((size_t)(G + 1) * 4);
    char* zbase = w + off;                                // zero-init group
    int*   deg    = (int*)alloc((size_t)N * 4);
    float* pooled = (float*)alloc((size_t)G * 128 * 4);
    size_t zbytes = (size_t)((w + off) - zbase);

    hipMemsetAsync(zbase, 0, zbytes, stream);

    // 1) weights -> split fp16 + fold attention vectors (one kernel)
    k_prep<<<514, 256, 0, stream>>>(W1, W2, as1, ad1, W1hi, W1lo, W2hi, W2lo, w_s1, w_d1);
    // 2) layer-1 logits + fp16 x
    k_attn_x<<<(N + 3) / 4, 256, 0, stream>>>(x, w_s1, w_d1, As1, Ad1, x_h, N);
    // 3) CSR count+rank, fused graph boundaries
    int nbc = (Ep + 255) / 256, nbg = (N + 255) / 256;
    k_count<<<nbc + nbg, 256, 0, stream>>>(ei, deg, rank, bat, gstart, E, Ep, N, G, nbc);
    int nb = (N + 1 + 1023) / 1024;
    k_scanA<<<nb, 1024, 0, stream>>>(deg, startb, sums, N + 1, N);
    k_scanB<<<1, 64, 0, stream>>>(sums, nb);
    k_scanC<<<nb, 1024, 0, stream>>>(startb, sums, N + 1);
    k_fill<<<(Ep + 255) / 256, 256, 0, stream>>>(ei, startb, rank, csr, E, Ep);
    // 4) layer-1 gather -> agg fp16 [N, 4*128]
    k_gat1<<<(N + 15) / 16, 256, 0, stream>>>(startb, csr, As1, Ad1, x_h, agg, N);
    // 5) block-diag projection + bias + ELU (fp16 MFMA)
    k_gemm_h<true, false><<<dim3((N + 127) / 128, 1, 4), 256, 0, stream>>>(
        agg, W1hi, W1lo, b1, h1, nullptr, nullptr, nullptr, nullptr,
        N, 128, 512, 128, 512, 128L, 16384L, 128L, 128L);
    // 6) xh2 = h1 @ W2^T + fused layer-2 attn logits
    k_gemm_h<false, true><<<dim3((N + 127) / 128, 1, 1), 256, 0, stream>>>(
        h1, W2hi, W2lo, nullptr, xh2h, as2, ad2, As2, Ad2,
        N, 512, 512, 512, 128, 0L, 0L, 0L, 0L);
    // 7) layer-2 gather + bias + ELU -> h2 fp16
    k_gat2<<<(N + 15) / 16, 256, 0, stream>>>(startb, csr, As2, Ad2, xh2h, b2, h2, N);
    // 8) two-stage pooling + MLP head
    k_poolA<<<(N + PCH - 1) / PCH, 128, 0, stream>>>(h2, bat, pooled, N);
    k_head<<<G, 128, 0, stream>>>(pooled, gstart, Wh1, bh1, Wh2, bh2, out);
}

// Round 16
// 345.660 us; speedup vs baseline: 1.3684x; 1.0186x over previous
//
#include <hip/hip_runtime.h>
#include <cstdint>
#include <cstddef>

#define NEG_SLOPE 0.2f

typedef _Float16 f16x8 __attribute__((ext_vector_type(8)));
typedef _Float16 f16x2 __attribute__((ext_vector_type(2)));
typedef float    f32x4 __attribute__((ext_vector_type(4)));
typedef float    f32x2 __attribute__((ext_vector_type(2)));

__device__ __forceinline__ float leaky(float x){ return x > 0.f ? x : NEG_SLOPE * x; }
__device__ __forceinline__ float elu(float x){ return x > 0.f ? x : __expf(x) - 1.f; }

// ============ prep: W1/W2 -> split fp16 hi/lo, + fold attention vectors through W1 ============
__global__ __launch_bounds__(256) void k_prep(const float* __restrict__ W1,
                                              const float* __restrict__ W2,
                                              const float* __restrict__ as1,
                                              const float* __restrict__ ad1,
                                              _Float16* __restrict__ W1hi, _Float16* __restrict__ W1lo,
                                              _Float16* __restrict__ W2hi, _Float16* __restrict__ W2lo,
                                              float* __restrict__ w_s, float* __restrict__ w_d)
{
    int b = blockIdx.x;
    if (b < 512) {
        const float* src = (b < 256) ? W1 : W2;
        _Float16* hi = (b < 256) ? W1hi : W2hi;
        _Float16* lo = (b < 256) ? W1lo : W2lo;
        int i = ((b & 255) << 8) + threadIdx.x;
        float v = src[i];
        _Float16 h = (_Float16)v;
        hi[i] = h;
        lo[i] = (_Float16)(v - (float)h);
    } else {
        int h = (b - 512) * 2 + (threadIdx.x >> 7);
        int k = threadIdx.x & 127;
        float s = 0.f, d = 0.f;
        for (int c = 0; c < 128; ++c) {
            float w = W1[((size_t)(h * 128 + c)) * 128 + k];
            s += as1[h * 128 + c] * w;
            d += ad1[h * 128 + c] * w;
        }
        w_s[h * 128 + k] = s;
        w_d[h * 128 + k] = d;
    }
}

// ============ fp16-A x split-fp16-B MFMA GEMM (tile 128x128, BK=32, z = heads) ============
#define LSG 40    // halfs per staging row (32 + 8 pad)
#define CP  136   // halfs per C-tile row (128 + 8 pad)
template<bool FUSE_BIAS_ELU, bool FUSE_ATTN2>
__global__ __launch_bounds__(256, 2) void k_gemm_h(
    const _Float16* __restrict__ A, const _Float16* __restrict__ Bh,
    const _Float16* __restrict__ Bl, const float* __restrict__ bias,
    _Float16* __restrict__ C,
    const float* __restrict__ as2, const float* __restrict__ ad2,
    float* __restrict__ As2, float* __restrict__ Ad2,
    int M, int K, int lda, int ldb, int ldc,
    long aZ, long bZ, long cZ, long biasZ)
{
    __shared__ __align__(16) _Float16 smem[128 * CP];
    _Float16* As  = smem;
    _Float16* Bhs = smem + 128 * LSG;
    _Float16* Bls = smem + 256 * LSG;

    const _Float16* Ab  = A  + (size_t)blockIdx.z * aZ;
    const _Float16* Bhb = Bh + (size_t)blockIdx.z * bZ;
    const _Float16* Blb = Bl + (size_t)blockIdx.z * bZ;
    _Float16* Cb = C + (size_t)blockIdx.z * cZ;

    const int tid = threadIdx.x;
    const int wave = tid >> 6, lane = tid & 63;
    const int wm = wave >> 1, wn = wave & 1;
    const int quad = lane >> 4, l16 = lane & 15;
    const int m0 = blockIdx.x * 128;

    f32x4 acc[4][4] = {};

    for (int k0 = 0; k0 < K; k0 += 32) {
        #pragma unroll
        for (int q = 0; q < 2; ++q) {
            int idx = tid + q * 256;
            int row = idx >> 2, kq = idx & 3;
            int rg = m0 + row;
            f16x8 va = {};
            if (rg < M) va = *(const f16x8*)(Ab + (size_t)rg * lda + k0 + kq * 8);
            *(f16x8*)&As[row * LSG + kq * 8] = va;
            *(f16x8*)&Bhs[row * LSG + kq * 8] = *(const f16x8*)(Bhb + (size_t)row * ldb + k0 + kq * 8);
            *(f16x8*)&Bls[row * LSG + kq * 8] = *(const f16x8*)(Blb + (size_t)row * ldb + k0 + kq * 8);
        }
        __syncthreads();

        f16x8 af[4], bhf[4], blf[4];
        #pragma unroll
        for (int i = 0; i < 4; ++i) {
            int mr = wm * 64 + i * 16 + l16;
            af[i] = *(const f16x8*)&As[mr * LSG + quad * 8];
            int nr = wn * 64 + i * 16 + l16;
            bhf[i] = *(const f16x8*)&Bhs[nr * LSG + quad * 8];
            blf[i] = *(const f16x8*)&Bls[nr * LSG + quad * 8];
        }
        #pragma unroll
        for (int i = 0; i < 4; ++i)
            #pragma unroll
            for (int j = 0; j < 4; ++j) {
                acc[i][j] = __builtin_amdgcn_mfma_f32_16x16x32_f16(af[i], bhf[j], acc[i][j], 0, 0, 0);
                acc[i][j] = __builtin_amdgcn_mfma_f32_16x16x32_f16(af[i], blf[j], acc[i][j], 0, 0, 0);
            }
        __syncthreads();
    }

    #pragma unroll
    for (int j = 0; j < 4; ++j) {
        int n = wn * 64 + j * 16 + l16;
        float bb = 0.f;
        if (FUSE_BIAS_ELU) bb = bias[blockIdx.z * biasZ + n];
        #pragma unroll
        for (int i = 0; i < 4; ++i)
            #pragma unroll
            for (int r = 0; r < 4; ++r) {
                float v = acc[i][j][r];
                if (FUSE_BIAS_ELU) v = elu(v + bb);
                smem[(wm * 64 + i * 16 + quad * 4 + r) * CP + n] = (_Float16)v;
            }
    }
    __syncthreads();
    for (int c = tid; c < 2048; c += 256) {
        int row = c >> 4, col8 = (c & 15) * 8;
        int m = m0 + row;
        if (m < M)
            *(f16x8*)(Cb + (size_t)m * ldc + col8) = *(const f16x8*)&smem[row * CP + col8];
    }
    if (FUSE_ATTN2) {
        int row = tid >> 1, half = tid & 1;
        int d = m0 + row;
        float ss = 0.f, sd = 0.f;
        const _Float16* rp = &smem[row * CP + half * 64];
        #pragma unroll
        for (int c8 = 0; c8 < 8; ++c8) {
            f16x8 v = *(const f16x8*)(rp + c8 * 8);
            #pragma unroll
            for (int c = 0; c < 8; ++c) {
                float f = (float)v[c];
                int n = half * 64 + c8 * 8 + c;
                ss += f * as2[n];
                sd += f * ad2[n];
            }
        }
        ss += __shfl_xor(ss, 1);
        sd += __shfl_xor(sd, 1);
        if (half == 0 && d < M) { As2[d] = ss; Ad2[d] = sd; }
    }
}

// ============ layer-1 attention logits from raw x; also emit x as fp16 ============
__global__ __launch_bounds__(256) void k_attn_x(const float* __restrict__ x,
                                                const float* __restrict__ w_s,
                                                const float* __restrict__ w_d,
                                                float* __restrict__ a_s,
                                                float* __restrict__ a_d,
                                                _Float16* __restrict__ xh, int N)
{
    int n = blockIdx.x * 4 + (threadIdx.x >> 6);
    if (n >= N) return;
    int lane = threadIdx.x & 63;
    float2 xv = *(const float2*)(x + (size_t)n * 128 + lane * 2);
    f16x2 hv = { (_Float16)xv.x, (_Float16)xv.y };
    *(f16x2*)(xh + (size_t)n * 128 + lane * 2) = hv;
    float ps[4], pd[4];
    #pragma unroll
    for (int h = 0; h < 4; ++h) {
        float2 sv = *(const float2*)(w_s + h * 128 + lane * 2);
        float2 dv = *(const float2*)(w_d + h * 128 + lane * 2);
        ps[h] = xv.x * sv.x + xv.y * sv.y;
        pd[h] = xv.x * dv.x + xv.y * dv.y;
    }
    #pragma unroll
    for (int h = 0; h < 4; ++h)
        for (int off = 32; off; off >>= 1) {
            ps[h] += __shfl_xor(ps[h], off);
            pd[h] += __shfl_xor(pd[h], off);
        }
    if (lane == 0) {
        *(float4*)(a_s + (size_t)n * 4) = make_float4(ps[0], ps[1], ps[2], ps[3]);
        *(float4*)(a_d + (size_t)n * 4) = make_float4(pd[0], pd[1], pd[2], pd[3]);
    }
}

// ============ CSR construction (count+rank, fused graph boundaries) ============
__global__ void k_count(const int* __restrict__ ei, int* __restrict__ deg,
                        unsigned short* __restrict__ rank,
                        const int* __restrict__ batch, int* __restrict__ gstart,
                        int E, int Ep, int N, int G, int nbc)
{
    if ((int)blockIdx.x < nbc) {
        int e = blockIdx.x * 256 + threadIdx.x;
        if (e >= Ep) return;
        int dst = (e < E) ? ei[E + e] : (e - E);
        rank[e] = (unsigned short)atomicAdd(&deg[dst], 1);
    } else {
        int n = (blockIdx.x - nbc) * 256 + threadIdx.x;
        if (n >= N) return;
        int b = batch[n];
        int prev = (n == 0) ? -1 : batch[n - 1];
        for (int g = prev + 1; g <= b; ++g) gstart[g] = n;
        if (n == N - 1)
            for (int g = b + 1; g <= G; ++g) gstart[g] = N;
    }
}

__global__ __launch_bounds__(1024) void k_scanA(const int* __restrict__ deg,
                                                int* __restrict__ start,
                                                int* __restrict__ sums, int Ntot, int N)
{
    __shared__ int sm[1024];
    int tid = threadIdx.x;
    int i = blockIdx.x * 1024 + tid;
    int v = (i < N) ? deg[i] : 0;
    sm[tid] = v; __syncthreads();
    for (int off = 1; off < 1024; off <<= 1) {
        int t = (tid >= off) ? sm[tid - off] : 0;
        __syncthreads();
        sm[tid] += t;
        __syncthreads();
    }
    if (i < Ntot) start[i] = sm[tid] - v;
    if (tid == 1023) sums[blockIdx.x] = sm[1023];
}

__global__ void k_scanB(int* sums, int nb)
{
    int l = threadIdx.x;
    int v = (l < nb) ? sums[l] : 0;
    int orig = v;
    for (int off = 1; off < 64; off <<= 1) { int t = __shfl_up(v, off); if (l >= off) v += t; }
    if (l < nb) sums[l] = v - orig;
}

__global__ __launch_bounds__(1024) void k_scanC(int* __restrict__ start,
                                                const int* __restrict__ sums, int Ntot)
{
    int i = blockIdx.x * 1024 + threadIdx.x;
    if (i < Ntot) start[i] += sums[blockIdx.x];
}

__global__ void k_fill(const int* __restrict__ ei, const int* __restrict__ start,
                       const unsigned short* __restrict__ rank,
                       unsigned short* __restrict__ csr_src, int E, int Ep)
{
    int e = blockIdx.x * blockDim.x + threadIdx.x;
    if (e >= Ep) return;
    int src, dst;
    if (e < E) { src = ei[e]; dst = ei[E + e]; } else { src = dst = e - E; }
    csr_src[start[dst] + rank[e]] = (unsigned short)src;
}

// ============ layer-1 gather: 16-lane group per dst, 4-edge unrolled (4 gathers in flight) ====
__global__ __launch_bounds__(256) void k_gat1(const int* __restrict__ start,
                                              const unsigned short* __restrict__ csr,
                                              const float* __restrict__ a_s,
                                              const float* __restrict__ a_d,
                                              const _Float16* __restrict__ x,
                                              _Float16* __restrict__ agg, int N)
{
    int d = blockIdx.x * 16 + (threadIdx.x >> 4);
    if (d >= N) return;
    int g16 = threadIdx.x & 15;
    int beg = start[d], end = start[d + 1];
    int deg = end - beg;
    float4 ad4 = *(const float4*)(a_d + (size_t)d * 4);

    float sum0 = 0.f, sum1 = 0.f, sum2 = 0.f, sum3 = 0.f;
    f32x2 acc[4][4] = {};
    const _Float16* xb = x + g16 * 8;

    for (int base = 0; base < deg; base += 16) {
        int nch = deg - base; if (nch > 16) nch = 16;
        int s = 0;
        float e0 = 0.f, e1 = 0.f, e2 = 0.f, e3 = 0.f;
        if (g16 < nch) {
            s = csr[beg + base + g16];
            float4 as4 = *(const float4*)(a_s + (size_t)s * 4);
            e0 = __expf(leaky(as4.x + ad4.x));
            e1 = __expf(leaky(as4.y + ad4.y));
            e2 = __expf(leaky(as4.z + ad4.z));
            e3 = __expf(leaky(as4.w + ad4.w));
            sum0 += e0; sum1 += e1; sum2 += e2; sum3 += e3;
        }
        int t = 0;
        for (; t + 4 <= nch; t += 4) {
            int sA = __shfl(s, t, 16),     sB = __shfl(s, t + 1, 16);
            int sC = __shfl(s, t + 2, 16), sD = __shfl(s, t + 3, 16);
            f16x8 hA = *(const f16x8*)(xb + (size_t)sA * 128);
            f16x8 hB = *(const f16x8*)(xb + (size_t)sB * 128);
            f16x8 hC = *(const f16x8*)(xb + (size_t)sC * 128);
            f16x8 hD = *(const f16x8*)(xb + (size_t)sD * 128);
            float w0A = __shfl(e0, t, 16),     w1A = __shfl(e1, t, 16);
            float w2A = __shfl(e2, t, 16),     w3A = __shfl(e3, t, 16);
            float w0B = __shfl(e0, t + 1, 16), w1B = __shfl(e1, t + 1, 16);
            float w2B = __shfl(e2, t + 1, 16), w3B = __shfl(e3, t + 1, 16);
            float w0C = __shfl(e0, t + 2, 16), w1C = __shfl(e1, t + 2, 16);
            float w2C = __shfl(e2, t + 2, 16), w3C = __shfl(e3, t + 2, 16);
            float w0D = __shfl(e0, t + 3, 16), w1D = __shfl(e1, t + 3, 16);
            float w2D = __shfl(e2, t + 3, 16), w3D = __shfl(e3, t + 3, 16);
            #pragma unroll
            for (int p = 0; p < 4; ++p) {
                f32x2 vA = { (float)hA[2*p], (float)hA[2*p+1] };
                f32x2 vB = { (float)hB[2*p], (float)hB[2*p+1] };
                f32x2 vC = { (float)hC[2*p], (float)hC[2*p+1] };
                f32x2 vD = { (float)hD[2*p], (float)hD[2*p+1] };
                acc[0][p] += w0A * vA + w0B * vB + w0C * vC + w0D * vD;
                acc[1][p] += w1A * vA + w1B * vB + w1C * vC + w1D * vD;
                acc[2][p] += w2A * vA + w2B * vB + w2C * vC + w2D * vD;
                acc[3][p] += w3A * vA + w3B * vB + w3C * vC + w3D * vD;
            }
        }
        for (; t < nch; ++t) {
            int   si = __shfl(s,  t, 16);
            float w0 = __shfl(e0, t, 16);
            float w1 = __shfl(e1, t, 16);
            float w2 = __shfl(e2, t, 16);
            float w3 = __shfl(e3, t, 16);
            f16x8 hv = *(const f16x8*)(xb + (size_t)si * 128);
            #pragma unroll
            for (int p = 0; p < 4; ++p) {
                f32x2 v = { (float)hv[2*p], (float)hv[2*p+1] };
                acc[0][p] += w0 * v;
                acc[1][p] += w1 * v;
                acc[2][p] += w2 * v;
                acc[3][p] += w3 * v;
            }
        }
    }
    #pragma unroll
    for (int o = 1; o < 16; o <<= 1) {
        sum0 += __shfl_xor(sum0, o, 16); sum1 += __shfl_xor(sum1, o, 16);
        sum2 += __shfl_xor(sum2, o, 16); sum3 += __shfl_xor(sum3, o, 16);
    }
    float inv[4] = { 1.f / (sum0 + 1e-16f), 1.f / (sum1 + 1e-16f),
                     1.f / (sum2 + 1e-16f), 1.f / (sum3 + 1e-16f) };
    _Float16* o = agg + (size_t)d * 512 + g16 * 8;
    #pragma unroll
    for (int h = 0; h < 4; ++h) {
        f16x8 ov;
        #pragma unroll
        for (int p = 0; p < 4; ++p) {
            ov[2 * p]     = (_Float16)(acc[h][p].x * inv[h]);
            ov[2 * p + 1] = (_Float16)(acc[h][p].y * inv[h]);
        }
        *(f16x8*)(o + h * 128) = ov;
    }
}

// ============ layer-2 gather + bias + ELU -> h2 fp16, 16-lane group, 4-edge unrolled ============
__global__ __launch_bounds__(256) void k_gat2(const int* __restrict__ start,
                                              const unsigned short* __restrict__ csr,
                                              const float* __restrict__ a_s,
                                              const float* __restrict__ a_d,
                                              const _Float16* __restrict__ xh2,
                                              const float* __restrict__ b2,
                                              _Float16* __restrict__ h2, int N)
{
    int d = blockIdx.x * 16 + (threadIdx.x >> 4);
    if (d >= N) return;
    int g16 = threadIdx.x & 15;
    int beg = start[d], end = start[d + 1];
    int deg = end - beg;
    float ad = a_d[d];

    float sum = 0.f;
    f32x2 acc[4] = {};
    const _Float16* xb = xh2 + g16 * 8;

    for (int base = 0; base < deg; base += 16) {
        int nch = deg - base; if (nch > 16) nch = 16;
        int s = 0; float e = 0.f;
        if (g16 < nch) {
            s = csr[beg + base + g16];
            e = __expf(leaky(a_s[s] + ad));
            sum += e;
        }
        int t = 0;
        for (; t + 4 <= nch; t += 4) {
            int sA = __shfl(s, t, 16),     sB = __shfl(s, t + 1, 16);
            int sC = __shfl(s, t + 2, 16), sD = __shfl(s, t + 3, 16);
            f16x8 hA = *(const f16x8*)(xb + (size_t)sA * 128);
            f16x8 hB = *(const f16x8*)(xb + (size_t)sB * 128);
            f16x8 hC = *(const f16x8*)(xb + (size_t)sC * 128);
            f16x8 hD = *(const f16x8*)(xb + (size_t)sD * 128);
            float wA = __shfl(e, t, 16),     wB = __shfl(e, t + 1, 16);
            float wC = __shfl(e, t + 2, 16), wD = __shfl(e, t + 3, 16);
            #pragma unroll
            for (int p = 0; p < 4; ++p) {
                f32x2 vA = { (float)hA[2*p], (float)hA[2*p+1] };
                f32x2 vB = { (float)hB[2*p], (float)hB[2*p+1] };
                f32x2 vC = { (float)hC[2*p], (float)hC[2*p+1] };
                f32x2 vD = { (float)hD[2*p], (float)hD[2*p+1] };
                acc[p] += wA * vA + wB * vB + wC * vC + wD * vD;
            }
        }
        for (; t < nch; ++t) {
            int   si = __shfl(s, t, 16);
            float w  = __shfl(e, t, 16);
            f16x8 hv = *(const f16x8*)(xb + (size_t)si * 128);
            #pragma unroll
            for (int p = 0; p < 4; ++p) {
                f32x2 v = { (float)hv[2*p], (float)hv[2*p+1] };
                acc[p] += w * v;
            }
        }
    }
    #pragma unroll
    for (int o = 1; o < 16; o <<= 1) sum += __shfl_xor(sum, o, 16);
    float inv = 1.f / (sum + 1e-16f);
    f16x8 ov;
    #pragma unroll
    for (int p = 0; p < 4; ++p) {
        ov[2 * p]     = (_Float16)elu(acc[p].x * inv + b2[g16 * 8 + 2 * p]);
        ov[2 * p + 1] = (_Float16)elu(acc[p].y * inv + b2[g16 * 8 + 2 * p + 1]);
    }
    *(f16x8*)(h2 + (size_t)d * 128 + g16 * 8) = ov;
}

// ============ pooling stage A: chunked partial sums (h2 fp16) ============
#define PCH 64
__global__ __launch_bounds__(128) void k_poolA(const _Float16* __restrict__ h2,
                                               const int* __restrict__ batch,
                                               float* __restrict__ pooled, int N)
{
    int c = threadIdx.x;
    int n0 = blockIdx.x * PCH;
    int n1 = n0 + PCH < N ? n0 + PCH : N;
    if (n0 >= N) return;
    int g = batch[n0];
    float acc = 0.f;
    for (int n = n0; n < n1; ++n) {
        int bg = batch[n];
        if (bg != g) { atomicAdd(&pooled[(size_t)g * 128 + c], acc); acc = 0.f; g = bg; }
        acc += (float)h2[(size_t)n * 128 + c];
    }
    atomicAdd(&pooled[(size_t)g * 128 + c], acc);
}

// ============ head: mean + relu(pooled@Wh1^T+bh1) @ Wh2^T + bh2 ============
__global__ __launch_bounds__(128) void k_head(const float* __restrict__ pooled,
                                              const int* __restrict__ gstart,
                                              const float* __restrict__ Wh1,
                                              const float* __restrict__ bh1,
                                              const float* __restrict__ Wh2,
                                              const float* __restrict__ bh2,
                                              float* __restrict__ out)
{
    int g = blockIdx.x, c = threadIdx.x;
    __shared__ float p[128];
    __shared__ float red[128];
    float cf = (float)(gstart[g + 1] - gstart[g]); cf = cf > 1.f ? cf : 1.f;
    p[c] = pooled[(size_t)g * 128 + c] / cf;
    __syncthreads();
    float z = bh1[c];
    for (int k = 0; k < 128; ++k) z += p[k] * Wh1[c * 128 + k];
    z = z > 0.f ? z : 0.f;
    red[c] = z * Wh2[c];
    __syncthreads();
    for (int st = 64; st > 0; st >>= 1) { if (c < st) red[c] += red[c + st]; __syncthreads(); }
    if (c == 0) out[g] = red[0] + bh2[0];
}

// ============ launch ============
extern "C" void kernel_launch(void* const* d_in, const int* in_sizes, int n_in,
                              void* d_out, int out_size, void* d_ws, size_t ws_size,
                              hipStream_t stream)
{
    const float* x   = (const float*)d_in[0];
    const int*   ei  = (const int*)d_in[1];
    const int*   bat = (const int*)d_in[2];
    const float* W1  = (const float*)d_in[3];
    const float* as1 = (const float*)d_in[4];
    const float* ad1 = (const float*)d_in[5];
    const float* b1  = (const float*)d_in[6];
    const float* W2  = (const float*)d_in[7];
    const float* as2 = (const float*)d_in[8];
    const float* ad2 = (const float*)d_in[9];
    const float* b2  = (const float*)d_in[10];
    const float* Wh1 = (const float*)d_in[11];
    const float* bh1 = (const float*)d_in[12];
    const float* Wh2 = (const float*)d_in[13];
    const float* bh2 = (const float*)d_in[14];
    float* out = (float*)d_out;

    const int N  = in_sizes[0] / 128;
    const int E  = in_sizes[1] / 2;
    const int Ep = E + N;
    const int G  = 128;

    char* w = (char*)d_ws;
    size_t off = 0;
    auto alloc = [&](size_t bytes) -> char* {
        char* p = w + off; off += (bytes + 511) & ~(size_t)511; return p;
    };
    _Float16* x_h  = (_Float16*)alloc((size_t)N * 128 * 2);
    _Float16* agg  = (_Float16*)alloc((size_t)N * 512 * 2);
    _Float16* h1   = (_Float16*)alloc((size_t)N * 512 * 2);
    _Float16* xh2h = (_Float16*)alloc((size_t)N * 128 * 2);
    _Float16* h2   = (_Float16*)alloc((size_t)N * 128 * 2);
    float*    As1  = (float*)alloc((size_t)N * 4 * 4);
    float*    Ad1  = (float*)alloc((size_t)N * 4 * 4);
    float*    As2  = (float*)alloc((size_t)N * 4);
    float*    Ad2  = (float*)alloc((size_t)N * 4);
    float*    w_s1 = (float*)alloc(512 * 4);
    float*    w_d1 = (float*)alloc(512 * 4);
    _Float16* W1hi = (_Float16*)alloc(65536 * 2);
    _Float16* W1lo = (_Float16*)alloc(65536 * 2);
    _Float16* W2hi = (_Float16*)alloc(65536 * 2);
    _Float16* W2lo = (_Float16*)alloc(65536 * 2);
    int* startb = (int*)alloc((size_t)(N + 1) * 4);
    unsigned short* csr  = (unsigned short*)alloc((size_t)Ep * 2);
    unsigned short* rank = (unsigned short*)alloc((size_t)Ep * 2);
    int* sums   = (int*)alloc(4096);
    int* gstart = (int*)alloc((size_t)(G + 1) * 4);
    char* zbase = w + off;                                // zero-init group
    int*   deg    = (int*)alloc((size_t)N * 4);
    float* pooled = (float*)alloc((size_t)G * 128 * 4);
    size_t zbytes = (size_t)((w + off) - zbase);

    hipMemsetAsync(zbase, 0, zbytes, stream);

    // 1) weights -> split fp16 + fold attention vectors (one kernel)
    k_prep<<<514, 256, 0, stream>>>(W1, W2, as1, ad1, W1hi, W1lo, W2hi, W2lo, w_s1, w_d1);
    // 2) layer-1 logits + fp16 x
    k_attn_x<<<(N + 3) / 4, 256, 0, stream>>>(x, w_s1, w_d1, As1, Ad1, x_h, N);
    // 3) CSR count+rank, fused graph boundaries
    int nbc = (Ep + 255) / 256, nbg = (N + 255) / 256;
    k_count<<<nbc + nbg, 256, 0, stream>>>(ei, deg, rank, bat, gstart, E, Ep, N, G, nbc);
    int nb = (N + 1 + 1023) / 1024;
    k_scanA<<<nb, 1024, 0, stream>>>(deg, startb, sums, N + 1, N);
    k_scanB<<<1, 64, 0, stream>>>(sums, nb);
    k_scanC<<<nb, 1024, 0, stream>>>(startb, sums, N + 1);
    k_fill<<<(Ep + 255) / 256, 256, 0, stream>>>(ei, startb, rank, csr, E, Ep);
    // 4) layer-1 gather -> agg fp16 [N, 4*128]
    k_gat1<<<(N + 15) / 16, 256, 0, stream>>>(startb, csr, As1, Ad1, x_h, agg, N);
    // 5) block-diag projection + bias + ELU (fp16 MFMA)
    k_gemm_h<true, false><<<dim3((N + 127) / 128, 1, 4), 256, 0, stream>>>(
        agg, W1hi, W1lo, b1, h1, nullptr, nullptr, nullptr, nullptr,
        N, 128, 512, 128, 512, 128L, 16384L, 128L, 128L);
    // 6) xh2 = h1 @ W2^T + fused layer-2 attn logits
    k_gemm_h<false, true><<<dim3((N + 127) / 128, 1, 1), 256, 0, stream>>>(
        h1, W2hi, W2lo, nullptr, xh2h, as2, ad2, As2, Ad2,
        N, 512, 512, 512, 128, 0L, 0L, 0L, 0L);
    // 7) layer-2 gather + bias + ELU -> h2 fp16
    k_gat2<<<(N + 15) / 16, 256, 0, stream>>>(startb, csr, As2, Ad2, xh2h, b2, h2, N);
    // 8) two-stage pooling + MLP head
    k_poolA<<<(N + PCH - 1) / PCH, 128, 0, stream>>>(h2, bat, pooled, N);
    k_head<<<G, 128, 0, stream>>>(pooled, gstart, Wh1, bh1, Wh2, bh2, out);
}